// Round 1
// baseline (2160.325 us; speedup 1.0000x reference)
//
#include <hip/hip_runtime.h>
#include <cstddef>

constexpr int B = 8, L = 999, C = 768, C2 = 384, H = 8, HD = 48;
constexpr float ATT_SCALE = 0.14433756729740644f;   // 48^-0.5
constexpr float BN_EPS = 1e-5f;
constexpr float INV_N = 1.0f / (8.0f * 999.0f);     // 1/(B*L)

constexpr size_t SZ_XT   = (size_t)B * C * L;       // 6,137,856
constexpr size_t SZ_HALF = (size_t)B * C2 * L;      // 3,068,928
constexpr size_t OFF_XT   = 0;                      // xt, later t1
constexpr size_t OFF_XT2  = SZ_XT;                  // xt2 (concat branch outputs, transposed)
constexpr size_t OFF_KV   = 2 * SZ_XT;              // kv,   later y3
constexpr size_t OFF_KVIN = 3 * SZ_XT;              // kvin, later attnout
constexpr size_t OFF_Q    = 3 * SZ_XT + SZ_HALF;    // q,    later h2
constexpr size_t OFF_SM   = 3 * SZ_XT + 2 * SZ_HALF;

// small-region offsets (floats, relative to OFF_SM)
constexpr size_t SM_POOLED = 0;       // B*C2*3
constexpr size_t SM_XM     = 9216;    // B*C2
constexpr size_t SM_H1     = 12288;   // B*4*96
constexpr size_t SM_WDYN   = 15360;   // B*C2*3
constexpr size_t SM_BDYN   = 24576;   // B*C2
constexpr size_t SM_SUM1   = 27648;   // 768
constexpr size_t SM_SQ1    = 28416;
constexpr size_t SM_S1     = 29184;
constexpr size_t SM_D1     = 29952;
constexpr size_t SM_CB1    = 30720;   // 96
constexpr size_t SM_SUM2   = 30816;   // 96
constexpr size_t SM_SQ2    = 30912;
constexpr size_t SM_S2     = 31008;
constexpr size_t SM_D2     = 31104;
constexpr size_t SM_CB2    = 31200;   // 768
constexpr size_t SM_SUM3   = 31968;
constexpr size_t SM_SQ3    = 32736;
constexpr size_t SM_S3     = 33504;
constexpr size_t SM_D3     = 34272;
constexpr size_t SM_END    = 35040;

__device__ __forceinline__ float gelu_f(float x) {
  return 0.5f * x * (1.0f + erff(x * 0.70710678118654752f));
}

__device__ __forceinline__ float wave_sum(float v) {
  #pragma unroll
  for (int off = 32; off > 0; off >>= 1) v += __shfl_down(v, off, 64);
  return v;
}

__device__ __forceinline__ float wave_max(float v) {
  #pragma unroll
  for (int off = 32; off > 0; off >>= 1) v = fmaxf(v, __shfl_down(v, off, 64));
  return v;
}

// ---------------- transpose x (B,L,C) -> xt (B,C,L) ----------------
__global__ void k_transpose_in(const float* __restrict__ x, float* __restrict__ xt) {
  __shared__ float tile[32][33];
  int b = blockIdx.z;
  int l0 = blockIdx.x * 32, c0 = blockIdx.y * 32;
  int tx = threadIdx.x, ty = threadIdx.y;
  #pragma unroll
  for (int i = 0; i < 4; i++) {
    int l = l0 + ty + i * 8, c = c0 + tx;
    if (l < L) tile[ty + i * 8][tx] = x[((size_t)b * L + l) * C + c];
  }
  __syncthreads();
  #pragma unroll
  for (int i = 0; i < 4; i++) {
    int c = c0 + ty + i * 8, l = l0 + tx;
    if (l < L) xt[((size_t)b * C + c) * L + l] = tile[tx][ty + i * 8];
  }
}

// ---------------- pooled chunk means + row mean (dyn-conv branch) ----------------
__global__ __launch_bounds__(256) void k_pool(const float* __restrict__ xt,
                                              float* __restrict__ pooled,
                                              float* __restrict__ xm) {
  int c = blockIdx.x, b = blockIdx.y;       // c < 384
  const float* row = xt + ((size_t)b * C + c) * L;
  float s0 = 0.f, s1 = 0.f, s2 = 0.f;
  for (int l = threadIdx.x; l < L; l += 256) {
    float v = row[l];
    int ch = l / 333;
    if (ch == 0) s0 += v; else if (ch == 1) s1 += v; else s2 += v;
  }
  s0 = wave_sum(s0); s1 = wave_sum(s1); s2 = wave_sum(s2);
  __shared__ float r[3][4];
  int lane = threadIdx.x & 63, wid = threadIdx.x >> 6;
  if (lane == 0) { r[0][wid] = s0; r[1][wid] = s1; r[2][wid] = s2; }
  __syncthreads();
  if (threadIdx.x == 0) {
    float t0 = r[0][0] + r[0][1] + r[0][2] + r[0][3];
    float t1 = r[1][0] + r[1][1] + r[1][2] + r[1][3];
    float t2 = r[2][0] + r[2][1] + r[2][2] + r[2][3];
    size_t pb = (size_t)(b * C2 + c) * 3;
    pooled[pb + 0] = t0 / 333.f;
    pooled[pb + 1] = t1 / 333.f;
    pooled[pb + 2] = t2 / 333.f;
    xm[b * C2 + c] = (t0 + t1 + t2) / 999.f;
  }
}

// ---------------- tiny MLP layer 1: gelu(p1w @ in + p1b) ----------------
__global__ void k_mlp1(const float* __restrict__ pooled, const float* __restrict__ xm,
                       const float* __restrict__ p1w, const float* __restrict__ p1b,
                       float* __restrict__ h1) {
  int j = blockIdx.x, b = blockIdx.y;       // j in 0..3 (0..2 pooled cols, 3 = mean)
  __shared__ float vin[C2];
  for (int c = threadIdx.x; c < C2; c += 128)
    vin[c] = (j < 3) ? pooled[(size_t)(b * C2 + c) * 3 + j] : xm[b * C2 + c];
  __syncthreads();
  int o = threadIdx.x;
  if (o < 96) {
    float acc = p1b[o];
    const float* wr = p1w + (size_t)o * C2;
    for (int c = 0; c < C2; c++) acc += vin[c] * wr[c];
    h1[(b * 4 + j) * 96 + o] = gelu_f(acc);
  }
}

// ---------------- MLP layer 2 + softmax over G + weight/bias mix ----------------
__global__ void k_mix2(const float* __restrict__ h1,
                       const float* __restrict__ p2w, const float* __restrict__ p2b,
                       const float* __restrict__ dcw, const float* __restrict__ dcb,
                       float* __restrict__ wdyn, float* __restrict__ bdyn) {
  int j = blockIdx.x, b = blockIdx.y;
  __shared__ float hv[96];
  for (int i = threadIdx.x; i < 96; i += 384) hv[i] = h1[(b * 4 + j) * 96 + i];
  __syncthreads();
  int c = threadIdx.x;                       // < 384
  float a0 = p2b[c], a1 = p2b[C2 + c];
  const float* w0r = p2w + (size_t)c * 96;
  const float* w1r = p2w + (size_t)(C2 + c) * 96;
  for (int i = 0; i < 96; i++) { float h = hv[i]; a0 += h * w0r[i]; a1 += h * w1r[i]; }
  float m = fmaxf(a0, a1);
  float e0 = __expf(a0 - m), e1 = __expf(a1 - m);
  float inv = 1.f / (e0 + e1);
  float p0 = e0 * inv, p1 = e1 * inv;
  if (j < 3)
    wdyn[(size_t)(b * C2 + c) * 3 + j] = p0 * dcw[(size_t)c * 3 + j] + p1 * dcw[(size_t)(C2 + c) * 3 + j];
  else
    bdyn[b * C2 + c] = p0 * dcb[c] + p1 * dcb[C2 + c];
}

// ---------------- dynamic depthwise conv -> xt2 lower half ----------------
__global__ __launch_bounds__(256) void k_dynconv(const float* __restrict__ xt,
                                                 const float* __restrict__ wdyn,
                                                 const float* __restrict__ bdyn,
                                                 float* __restrict__ xt2) {
  int c = blockIdx.x, b = blockIdx.y;
  const float* row = xt + ((size_t)b * C + c) * L;
  size_t wb = (size_t)(b * C2 + c) * 3;
  float w0 = wdyn[wb], w1 = wdyn[wb + 1], w2 = wdyn[wb + 2], bb = bdyn[b * C2 + c];
  float* orow = xt2 + ((size_t)b * C + c) * L;
  for (int l = threadIdx.x; l < L; l += 256) {
    float xm1 = (l > 0) ? row[l - 1] : 0.f;
    float x0 = row[l];
    float xp1 = (l < L - 1) ? row[l + 1] : 0.f;
    orow[l] = xm1 * w0 + x0 * w1 + xp1 * w2 + bb;
  }
}

// ---------------- kv_in = dw3(x2t) + x2t ----------------
__global__ __launch_bounds__(256) void k_kvin(const float* __restrict__ xt,
                                              const float* __restrict__ lcw,
                                              const float* __restrict__ lcb,
                                              float* __restrict__ kvin) {
  int c = blockIdx.x, b = blockIdx.y;
  const float* row = xt + ((size_t)b * C + C2 + c) * L;
  float w0 = lcw[c * 3], w1 = lcw[c * 3 + 1] + 1.0f, w2 = lcw[c * 3 + 2], bb = lcb[c];
  float* orow = kvin + ((size_t)b * C2 + c) * L;
  for (int l = threadIdx.x; l < L; l += 256) {
    float xm1 = (l > 0) ? row[l - 1] : 0.f;
    float x0 = row[l];
    float xp1 = (l < L - 1) ? row[l + 1] : 0.f;
    orow[l] = xm1 * w0 + x0 * w1 + xp1 * w2 + bb;
  }
}

// ---------------- generic fp32 GEMM: Y[b,o,l] = sum_k (X[b,k,l]*scale[k]) * W[o,k] + bias[o] ----------------
__global__ __launch_bounds__(256) void k_gemm(const float* __restrict__ W,
                                              const float* __restrict__ X,
                                              float* __restrict__ Y,
                                              const float* __restrict__ scale,
                                              const float* __restrict__ bias,
                                              int O, int Kd, size_t xbs, size_t ybs,
                                              int do_gelu) {
  __shared__ float Ws[16][64];
  __shared__ float Xs[16][64];
  int b = blockIdx.z;
  int o0 = blockIdx.y * 64, l0 = blockIdx.x * 64;
  int t = threadIdx.x;
  int tx = t & 15, ty = t >> 4;
  const float* Xb = X + (size_t)b * xbs;
  float acc[4][4] = {{0.f}};
  for (int k0 = 0; k0 < Kd; k0 += 16) {
    {
      int o = t >> 2, ks = (t & 3) * 4;
      int oo = o0 + o;
      float4 w4 = make_float4(0.f, 0.f, 0.f, 0.f);
      if (oo < O) w4 = *reinterpret_cast<const float4*>(W + (size_t)oo * Kd + k0 + ks);
      Ws[ks + 0][o] = w4.x; Ws[ks + 1][o] = w4.y; Ws[ks + 2][o] = w4.z; Ws[ks + 3][o] = w4.w;
    }
    #pragma unroll
    for (int i = 0; i < 4; i++) {
      int f = t + i * 256;
      int kk = f >> 6, ll = f & 63;
      int l = l0 + ll;
      float v = (l < L) ? Xb[(size_t)(k0 + kk) * L + l] : 0.f;
      if (scale) v *= scale[k0 + kk];
      Xs[kk][ll] = v;
    }
    __syncthreads();
    #pragma unroll
    for (int k = 0; k < 16; k++) {
      float4 a4 = *reinterpret_cast<const float4*>(&Ws[k][ty * 4]);
      float4 x4 = *reinterpret_cast<const float4*>(&Xs[k][tx * 4]);
      acc[0][0] += a4.x * x4.x; acc[0][1] += a4.x * x4.y; acc[0][2] += a4.x * x4.z; acc[0][3] += a4.x * x4.w;
      acc[1][0] += a4.y * x4.x; acc[1][1] += a4.y * x4.y; acc[1][2] += a4.y * x4.z; acc[1][3] += a4.y * x4.w;
      acc[2][0] += a4.z * x4.x; acc[2][1] += a4.z * x4.y; acc[2][2] += a4.z * x4.z; acc[2][3] += a4.z * x4.w;
      acc[3][0] += a4.w * x4.x; acc[3][1] += a4.w * x4.y; acc[3][2] += a4.w * x4.z; acc[3][3] += a4.w * x4.w;
    }
    __syncthreads();
  }
  #pragma unroll
  for (int i = 0; i < 4; i++) {
    int o = o0 + ty * 4 + i;
    if (o >= O) break;
    float bo = bias ? bias[o] : 0.f;
    float* yrow = Y + (size_t)b * ybs + (size_t)o * L;
    #pragma unroll
    for (int j = 0; j < 4; j++) {
      int l = l0 + tx * 4 + j;
      if (l >= L) break;
      float v = acc[i][j] + bo;
      if (do_gelu) v = gelu_f(v);
      yrow[l] = v;
    }
  }
}

// ---------------- attention: one (b,h,l) row per block ----------------
__global__ __launch_bounds__(256) void k_attn(const float* __restrict__ q,
                                              const float* __restrict__ kv,
                                              float* __restrict__ out) {
  int l = blockIdx.x, h = blockIdx.y, b = blockIdx.z;
  __shared__ float qs[HD];
  __shared__ float sred[4];
  __shared__ float wred[4 * HD];
  int t = threadIdx.x, lane = t & 63, wid = t >> 6;
  const float* kvb = kv + (size_t)b * C * L;
  if (t < HD) qs[t] = q[((size_t)b * C2 + h * HD + t) * L + l];
  __syncthreads();
  const float* kb = kvb + (size_t)(h * HD) * L;
  float sv[4];
  float lmax = -1e30f;
  #pragma unroll
  for (int i = 0; i < 4; i++) {
    int m = t + i * 256;
    float s = -1e30f;
    if (m < L) {
      s = 0.f;
      #pragma unroll
      for (int d = 0; d < HD; d++) s += qs[d] * kb[(size_t)d * L + m];
      s *= ATT_SCALE;
    }
    sv[i] = s;
    lmax = fmaxf(lmax, s);
  }
  lmax = wave_max(lmax);
  if (lane == 0) sred[wid] = lmax;
  __syncthreads();
  float gmax = fmaxf(fmaxf(sred[0], sred[1]), fmaxf(sred[2], sred[3]));
  __syncthreads();
  float lsum = 0.f;
  #pragma unroll
  for (int i = 0; i < 4; i++) {
    float e = __expf(sv[i] - gmax);   // -1e30 rows -> 0
    sv[i] = e;
    lsum += e;
  }
  lsum = wave_sum(lsum);
  if (lane == 0) sred[wid] = lsum;
  __syncthreads();
  float inv = 1.f / (sred[0] + sred[1] + sred[2] + sred[3]);
  float acc[HD];
  #pragma unroll
  for (int d = 0; d < HD; d++) acc[d] = 0.f;
  const float* vb = kvb + (size_t)(C2 + h * HD) * L;
  #pragma unroll
  for (int i = 0; i < 4; i++) {
    int m = t + i * 256;
    if (m < L) {
      float p = sv[i];
      #pragma unroll
      for (int d = 0; d < HD; d++) acc[d] += p * vb[(size_t)d * L + m];
    }
  }
  #pragma unroll
  for (int d = 0; d < HD; d++) {
    float v = wave_sum(acc[d]);
    if (lane == 0) wred[wid * HD + d] = v;
  }
  __syncthreads();
  if (t < HD) {
    float v = (wred[t] + wred[HD + t] + wred[2 * HD + t] + wred[3 * HD + t]) * inv;
    out[((size_t)b * C2 + h * HD + t) * L + l] = v;
  }
}

// ---------------- scatter attention out (weird reshape) -> xt2 upper half ----------------
__global__ void k_fill_xt2(const float* __restrict__ ao, float* __restrict__ xt2) {
  __shared__ float tile[32][33];
  int b = blockIdx.z;
  int l0 = blockIdx.x * 32, c0 = blockIdx.y * 32;
  int tx = threadIdx.x, ty = threadIdx.y;
  #pragma unroll
  for (int i = 0; i < 4; i++) {
    int l = l0 + ty + i * 8, c = c0 + tx;
    if (l < L) tile[ty + i * 8][tx] = ao[(size_t)b * ((size_t)L * C2) + (size_t)l * C2 + c];
  }
  __syncthreads();
  #pragma unroll
  for (int i = 0; i < 4; i++) {
    int c = c0 + ty + i * 8, l = l0 + tx;
    if (l < L) xt2[((size_t)b * C + C2 + c) * L + l] = tile[tx][ty + i * 8];
  }
}

// ---------------- projection dw3 + gelu -> t1, accumulate bn1 stats ----------------
__global__ __launch_bounds__(256) void k_dwproj(const float* __restrict__ xt2,
                                                const float* __restrict__ dww,
                                                const float* __restrict__ dwb,
                                                float* __restrict__ t1,
                                                float* __restrict__ sum, float* __restrict__ sq) {
  int c = blockIdx.x, b = blockIdx.y;
  const float* row = xt2 + ((size_t)b * C + c) * L;
  float w0 = dww[c * 3], w1 = dww[c * 3 + 1], w2 = dww[c * 3 + 2], bb = dwb[c];
  float* orow = t1 + ((size_t)b * C + c) * L;
  float s = 0.f, s2 = 0.f;
  for (int l = threadIdx.x; l < L; l += 256) {
    float xm1 = (l > 0) ? row[l - 1] : 0.f;
    float x0 = row[l];
    float xp1 = (l < L - 1) ? row[l + 1] : 0.f;
    float v = gelu_f(xm1 * w0 + x0 * w1 + xp1 * w2 + bb);
    orow[l] = v;
    s += v; s2 += v * v;
  }
  s = wave_sum(s); s2 = wave_sum(s2);
  __shared__ float r1[4], r2[4];
  int lane = threadIdx.x & 63, wid = threadIdx.x >> 6;
  if (lane == 0) { r1[wid] = s; r2[wid] = s2; }
  __syncthreads();
  if (threadIdx.x == 0) {
    atomicAdd(&sum[c], r1[0] + r1[1] + r1[2] + r1[3]);
    atomicAdd(&sq[c], r2[0] + r2[1] + r2[2] + r2[3]);
  }
}

// ---------------- generic per-(b,c)-row stats ----------------
__global__ __launch_bounds__(256) void k_rowstats(const float* __restrict__ Y, int Cn,
                                                  float* __restrict__ sum, float* __restrict__ sq) {
  int c = blockIdx.x, b = blockIdx.y;
  const float* row = Y + ((size_t)b * Cn + c) * L;
  float s = 0.f, s2 = 0.f;
  for (int l = threadIdx.x; l < L; l += 256) { float v = row[l]; s += v; s2 += v * v; }
  s = wave_sum(s); s2 = wave_sum(s2);
  __shared__ float r1[4], r2[4];
  int lane = threadIdx.x & 63, wid = threadIdx.x >> 6;
  if (lane == 0) { r1[wid] = s; r2[wid] = s2; }
  __syncthreads();
  if (threadIdx.x == 0) {
    atomicAdd(&sum[c], r1[0] + r1[1] + r1[2] + r1[3]);
    atomicAdd(&sq[c], r2[0] + r2[1] + r2[2] + r2[3]);
  }
}

// ---------------- finalize bn1 (s1,d1) and folded c1 bias cb1 ----------------
__global__ void k_fin1(const float* __restrict__ sum, const float* __restrict__ sq,
                       const float* __restrict__ g, const float* __restrict__ be,
                       const float* __restrict__ c1w, const float* __restrict__ c1b,
                       float* __restrict__ s1, float* __restrict__ d1, float* __restrict__ cb1) {
  int t = threadIdx.x;
  if (t < C) {
    float m = sum[t] * INV_N;
    float v = sq[t] * INV_N - m * m;
    float r = rsqrtf(v + BN_EPS);
    float sc = g[t] * r;
    s1[t] = sc;
    d1[t] = be[t] - m * sc;
  }
  __syncthreads();
  if (t < 96) {
    float a = c1b[t];
    const float* wr = c1w + (size_t)t * C;
    for (int c = 0; c < C; c++) a += d1[c] * wr[c];
    cb1[t] = a;
  }
}

// ---------------- finalize bn2 (s2,d2) and folded c2 bias cb2 ----------------
__global__ void k_fin2(const float* __restrict__ sum, const float* __restrict__ sq,
                       const float* __restrict__ g, const float* __restrict__ be,
                       const float* __restrict__ c2w, const float* __restrict__ c2b,
                       float* __restrict__ s2, float* __restrict__ d2, float* __restrict__ cb2) {
  int t = threadIdx.x;
  if (t < 96) {
    float m = sum[t] * INV_N;
    float v = sq[t] * INV_N - m * m;
    float r = rsqrtf(v + BN_EPS);
    float sc = g[t] * r;
    s2[t] = sc;
    d2[t] = be[t] - m * sc;
  }
  __syncthreads();
  if (t < C) {
    float a = c2b[t];
    const float* wr = c2w + (size_t)t * 96;
    for (int i = 0; i < 96; i++) a += d2[i] * wr[i];
    cb2[t] = a;
  }
}

// ---------------- finalize bn3 ----------------
__global__ void k_fin3(const float* __restrict__ sum, const float* __restrict__ sq,
                       const float* __restrict__ g, const float* __restrict__ be,
                       float* __restrict__ s3, float* __restrict__ d3) {
  int t = threadIdx.x;
  if (t < C) {
    float m = sum[t] * INV_N;
    float v = sq[t] * INV_N - m * m;
    float r = rsqrtf(v + BN_EPS);
    float sc = g[t] * r;
    s3[t] = sc;
    d3[t] = be[t] - m * sc;
  }
}

// ---------------- final: out[b,l,c] = bn3(y3)[b,c,l] + xt2[b,c,l] ----------------
__global__ void k_final(const float* __restrict__ y3, const float* __restrict__ xt2,
                        const float* __restrict__ s3, const float* __restrict__ d3,
                        float* __restrict__ out) {
  __shared__ float tile[32][33];
  int b = blockIdx.z;
  int l0 = blockIdx.x * 32, c0 = blockIdx.y * 32;
  int tx = threadIdx.x, ty = threadIdx.y;
  #pragma unroll
  for (int i = 0; i < 4; i++) {
    int c = c0 + ty + i * 8, l = l0 + tx;
    if (l < L) {
      size_t idx = ((size_t)b * C + c) * L + l;
      tile[ty + i * 8][tx] = y3[idx] * s3[c] + d3[c] + xt2[idx];
    }
  }
  __syncthreads();
  #pragma unroll
  for (int i = 0; i < 4; i++) {
    int l = l0 + ty + i * 8, c = c0 + tx;
    if (l < L) out[((size_t)b * L + l) * C + c] = tile[tx][ty + i * 8];
  }
}

extern "C" void kernel_launch(void* const* d_in, const int* in_sizes, int n_in,
                              void* d_out, int out_size, void* d_ws, size_t ws_size,
                              hipStream_t stream) {
  const float* x    = (const float*)d_in[0];
  const float* dcw  = (const float*)d_in[1];
  const float* dcb  = (const float*)d_in[2];
  const float* p1w  = (const float*)d_in[3];
  const float* p1b  = (const float*)d_in[4];
  const float* p2w  = (const float*)d_in[5];
  const float* p2b  = (const float*)d_in[6];
  const float* qw   = (const float*)d_in[7];
  const float* qb   = (const float*)d_in[8];
  const float* kvw  = (const float*)d_in[9];
  const float* kvb  = (const float*)d_in[10];
  const float* lcw  = (const float*)d_in[11];
  const float* lcb  = (const float*)d_in[12];
  const float* dww  = (const float*)d_in[13];
  const float* dwb  = (const float*)d_in[14];
  const float* bn1g = (const float*)d_in[15];
  const float* bn1b = (const float*)d_in[16];
  const float* c1w  = (const float*)d_in[17];
  const float* c1b  = (const float*)d_in[18];
  const float* bn2g = (const float*)d_in[19];
  const float* bn2b = (const float*)d_in[20];
  const float* c2w  = (const float*)d_in[21];
  const float* c2b  = (const float*)d_in[22];
  const float* bn3g = (const float*)d_in[23];
  const float* bn3b = (const float*)d_in[24];
  float* out = (float*)d_out;
  float* ws  = (float*)d_ws;

  float* xt      = ws + OFF_XT;     // later reused as t1
  float* xt2     = ws + OFF_XT2;
  float* kvbuf   = ws + OFF_KV;     // later reused as y3
  float* kvin    = ws + OFF_KVIN;   // later reused as attnout
  float* qbuf    = ws + OFF_Q;      // later reused as h2
  float* sm      = ws + OFF_SM;

  float* pooled = sm + SM_POOLED;
  float* xm     = sm + SM_XM;
  float* h1     = sm + SM_H1;
  float* wdyn   = sm + SM_WDYN;
  float* bdyn   = sm + SM_BDYN;
  float* sum1 = sm + SM_SUM1; float* sq1 = sm + SM_SQ1;
  float* s1 = sm + SM_S1; float* d1 = sm + SM_D1; float* cb1 = sm + SM_CB1;
  float* sum2 = sm + SM_SUM2; float* sq2 = sm + SM_SQ2;
  float* s2 = sm + SM_S2; float* d2 = sm + SM_D2; float* cb2 = sm + SM_CB2;
  float* sum3 = sm + SM_SUM3; float* sq3 = sm + SM_SQ3;
  float* s3 = sm + SM_S3; float* d3 = sm + SM_D3;

  // zero the bn-stat accumulators (covers sum1..sq3 span; s/d/cb overwritten anyway)
  hipMemsetAsync((void*)(sm + SM_SUM1), 0, (SM_S3 - SM_SUM1) * sizeof(float), stream);

  dim3 tb32(32, 8);
  // 1. transpose input
  k_transpose_in<<<dim3(32, 24, B), tb32, 0, stream>>>(x, xt);
  // 2. pooled / mean
  k_pool<<<dim3(C2, B), 256, 0, stream>>>(xt, pooled, xm);
  // 3. tiny MLP
  k_mlp1<<<dim3(4, B), 128, 0, stream>>>(pooled, xm, p1w, p1b, h1);
  k_mix2<<<dim3(4, B), 384, 0, stream>>>(h1, p2w, p2b, dcw, dcb, wdyn, bdyn);
  // 4. dynamic conv -> xt2 lower
  k_dynconv<<<dim3(C2, B), 256, 0, stream>>>(xt, wdyn, bdyn, xt2);
  // 5. kv_in
  k_kvin<<<dim3(C2, B), 256, 0, stream>>>(xt, lcw, lcb, kvin);
  // 6. q = qw @ x2t  (O=384, K=384)
  k_gemm<<<dim3(16, 6, B), 256, 0, stream>>>(qw, xt + (size_t)C2 * L, qbuf, nullptr, qb,
                                             C2, C2, (size_t)C * L, (size_t)C2 * L, 0);
  // 7. kv = kvw @ kv_in (O=768, K=384)
  k_gemm<<<dim3(16, 12, B), 256, 0, stream>>>(kvw, kvin, kvbuf, nullptr, kvb,
                                              C, C2, (size_t)C2 * L, (size_t)C * L, 0);
  // 8. attention -> attnout (reuses kvin buffer)
  k_attn<<<dim3(L, H, B), 256, 0, stream>>>(qbuf, kvbuf, kvin);
  // 9. scatter (bug-compatible reshape) -> xt2 upper
  k_fill_xt2<<<dim3(32, 12, B), tb32, 0, stream>>>(kvin, xt2);
  // 10. projection dw3+gelu -> t1 (reuses xt), bn1 stats
  k_dwproj<<<dim3(C, B), 256, 0, stream>>>(xt2, dww, dwb, xt, sum1, sq1);
  k_fin1<<<1, 768, 0, stream>>>(sum1, sq1, bn1g, bn1b, c1w, c1b, s1, d1, cb1);
  // 11. c1 GEMM (bn1 folded) + gelu -> h2 (reuses qbuf), O=96, K=768
  k_gemm<<<dim3(16, 2, B), 256, 0, stream>>>(c1w, xt, qbuf, s1, cb1,
                                             96, C, (size_t)C * L, (size_t)96 * L, 1);
  k_rowstats<<<dim3(96, B), 256, 0, stream>>>(qbuf, 96, sum2, sq2);
  k_fin2<<<1, 768, 0, stream>>>(sum2, sq2, bn2g, bn2b, c2w, c2b, s2, d2, cb2);
  // 12. c2 GEMM (bn2 folded) -> y3 (reuses kvbuf), O=768, K=96
  k_gemm<<<dim3(16, 12, B), 256, 0, stream>>>(c2w, qbuf, kvbuf, s2, cb2,
                                              C, 96, (size_t)96 * L, (size_t)C * L, 0);
  k_rowstats<<<dim3(C, B), 256, 0, stream>>>(kvbuf, C, sum3, sq3);
  k_fin3<<<1, 768, 0, stream>>>(sum3, sq3, bn3g, bn3b, s3, d3);
  // 13. final bn3 + residual + transpose back
  k_final<<<dim3(32, 24, B), tb32, 0, stream>>>(kvbuf, xt2, s3, d3, out);
}

// Round 2
// 1364.715 us; speedup vs baseline: 1.5830x; 1.5830x over previous
//
#include <hip/hip_runtime.h>
#include <cstddef>

constexpr int B = 8, L = 999, C = 768, C2 = 384, H = 8, HD = 48;
constexpr float ATT_SCALE = 0.14433756729740644f;   // 48^-0.5
constexpr float BN_EPS = 1e-5f;
constexpr float INV_N = 1.0f / (8.0f * 999.0f);     // 1/(B*L)

constexpr size_t SZ_XT   = (size_t)B * C * L;       // 6,137,856
constexpr size_t SZ_HALF = (size_t)B * C2 * L;      // 3,068,928
constexpr size_t OFF_XT   = 0;                      // xt, later t1
constexpr size_t OFF_XT2  = SZ_XT;                  // xt2 (concat branch outputs, transposed)
constexpr size_t OFF_KV   = 2 * SZ_XT;              // kv,   later y3
constexpr size_t OFF_KVIN = 3 * SZ_XT;              // kvin, later attnout
constexpr size_t OFF_Q    = 3 * SZ_XT + SZ_HALF;    // q,    later h2
constexpr size_t OFF_SM   = 3 * SZ_XT + 2 * SZ_HALF;

// small-region offsets (floats, relative to OFF_SM)
constexpr size_t SM_POOLED = 0;       // B*C2*3
constexpr size_t SM_XM     = 9216;    // B*C2
constexpr size_t SM_H1     = 12288;   // B*4*96
constexpr size_t SM_WDYN   = 15360;   // B*C2*3
constexpr size_t SM_BDYN   = 24576;   // B*C2
constexpr size_t SM_SUM1   = 27648;   // 768
constexpr size_t SM_SQ1    = 28416;
constexpr size_t SM_S1     = 29184;
constexpr size_t SM_D1     = 29952;
constexpr size_t SM_CB1    = 30720;   // 96
constexpr size_t SM_SUM2   = 30816;   // 96
constexpr size_t SM_SQ2    = 30912;
constexpr size_t SM_S2     = 31008;
constexpr size_t SM_D2     = 31104;
constexpr size_t SM_CB2    = 31200;   // 768
constexpr size_t SM_SUM3   = 31968;
constexpr size_t SM_SQ3    = 32736;
constexpr size_t SM_S3     = 33504;
constexpr size_t SM_D3     = 34272;
constexpr size_t SM_END    = 35040;

__device__ __forceinline__ float gelu_f(float x) {
  return 0.5f * x * (1.0f + erff(x * 0.70710678118654752f));
}

__device__ __forceinline__ float wave_sum(float v) {
  #pragma unroll
  for (int off = 32; off > 0; off >>= 1) v += __shfl_down(v, off, 64);
  return v;
}

// ---------------- transpose x (B,L,C) -> xt (B,C,L) ----------------
__global__ void k_transpose_in(const float* __restrict__ x, float* __restrict__ xt) {
  __shared__ float tile[32][33];
  int b = blockIdx.z;
  int l0 = blockIdx.x * 32, c0 = blockIdx.y * 32;
  int tx = threadIdx.x, ty = threadIdx.y;
  #pragma unroll
  for (int i = 0; i < 4; i++) {
    int l = l0 + ty + i * 8, c = c0 + tx;
    if (l < L) tile[ty + i * 8][tx] = x[((size_t)b * L + l) * C + c];
  }
  __syncthreads();
  #pragma unroll
  for (int i = 0; i < 4; i++) {
    int c = c0 + ty + i * 8, l = l0 + tx;
    if (l < L) xt[((size_t)b * C + c) * L + l] = tile[tx][ty + i * 8];
  }
}

// ---------------- pooled chunk means + row mean (dyn-conv branch) ----------------
__global__ __launch_bounds__(256) void k_pool(const float* __restrict__ xt,
                                              float* __restrict__ pooled,
                                              float* __restrict__ xm) {
  int c = blockIdx.x, b = blockIdx.y;       // c < 384
  const float* row = xt + ((size_t)b * C + c) * L;
  float s0 = 0.f, s1 = 0.f, s2 = 0.f;
  for (int l = threadIdx.x; l < L; l += 256) {
    float v = row[l];
    int ch = l / 333;
    if (ch == 0) s0 += v; else if (ch == 1) s1 += v; else s2 += v;
  }
  s0 = wave_sum(s0); s1 = wave_sum(s1); s2 = wave_sum(s2);
  __shared__ float r[3][4];
  int lane = threadIdx.x & 63, wid = threadIdx.x >> 6;
  if (lane == 0) { r[0][wid] = s0; r[1][wid] = s1; r[2][wid] = s2; }
  __syncthreads();
  if (threadIdx.x == 0) {
    float t0 = r[0][0] + r[0][1] + r[0][2] + r[0][3];
    float t1 = r[1][0] + r[1][1] + r[1][2] + r[1][3];
    float t2 = r[2][0] + r[2][1] + r[2][2] + r[2][3];
    size_t pb = (size_t)(b * C2 + c) * 3;
    pooled[pb + 0] = t0 / 333.f;
    pooled[pb + 1] = t1 / 333.f;
    pooled[pb + 2] = t2 / 333.f;
    xm[b * C2 + c] = (t0 + t1 + t2) / 999.f;
  }
}

// ---------------- tiny MLP layer 1: gelu(p1w @ in + p1b) ----------------
__global__ void k_mlp1(const float* __restrict__ pooled, const float* __restrict__ xm,
                       const float* __restrict__ p1w, const float* __restrict__ p1b,
                       float* __restrict__ h1) {
  int j = blockIdx.x, b = blockIdx.y;       // j in 0..3 (0..2 pooled cols, 3 = mean)
  __shared__ float vin[C2];
  for (int c = threadIdx.x; c < C2; c += 128)
    vin[c] = (j < 3) ? pooled[(size_t)(b * C2 + c) * 3 + j] : xm[b * C2 + c];
  __syncthreads();
  int o = threadIdx.x;
  if (o < 96) {
    float acc = p1b[o];
    const float* wr = p1w + (size_t)o * C2;
    for (int c = 0; c < C2; c++) acc += vin[c] * wr[c];
    h1[(b * 4 + j) * 96 + o] = gelu_f(acc);
  }
}

// ---------------- MLP layer 2 + softmax over G + weight/bias mix ----------------
__global__ void k_mix2(const float* __restrict__ h1,
                       const float* __restrict__ p2w, const float* __restrict__ p2b,
                       const float* __restrict__ dcw, const float* __restrict__ dcb,
                       float* __restrict__ wdyn, float* __restrict__ bdyn) {
  int j = blockIdx.x, b = blockIdx.y;
  __shared__ float hv[96];
  for (int i = threadIdx.x; i < 96; i += 384) hv[i] = h1[(b * 4 + j) * 96 + i];
  __syncthreads();
  int c = threadIdx.x;                       // < 384
  float a0 = p2b[c], a1 = p2b[C2 + c];
  const float* w0r = p2w + (size_t)c * 96;
  const float* w1r = p2w + (size_t)(C2 + c) * 96;
  for (int i = 0; i < 96; i++) { float h = hv[i]; a0 += h * w0r[i]; a1 += h * w1r[i]; }
  float m = fmaxf(a0, a1);
  float e0 = __expf(a0 - m), e1 = __expf(a1 - m);
  float inv = 1.f / (e0 + e1);
  float p0 = e0 * inv, p1 = e1 * inv;
  if (j < 3)
    wdyn[(size_t)(b * C2 + c) * 3 + j] = p0 * dcw[(size_t)c * 3 + j] + p1 * dcw[(size_t)(C2 + c) * 3 + j];
  else
    bdyn[b * C2 + c] = p0 * dcb[c] + p1 * dcb[C2 + c];
}

// ---------------- dynamic depthwise conv -> xt2 lower half ----------------
__global__ __launch_bounds__(256) void k_dynconv(const float* __restrict__ xt,
                                                 const float* __restrict__ wdyn,
                                                 const float* __restrict__ bdyn,
                                                 float* __restrict__ xt2) {
  int c = blockIdx.x, b = blockIdx.y;
  const float* row = xt + ((size_t)b * C + c) * L;
  size_t wb = (size_t)(b * C2 + c) * 3;
  float w0 = wdyn[wb], w1 = wdyn[wb + 1], w2 = wdyn[wb + 2], bb = bdyn[b * C2 + c];
  float* orow = xt2 + ((size_t)b * C + c) * L;
  for (int l = threadIdx.x; l < L; l += 256) {
    float xm1 = (l > 0) ? row[l - 1] : 0.f;
    float x0 = row[l];
    float xp1 = (l < L - 1) ? row[l + 1] : 0.f;
    orow[l] = xm1 * w0 + x0 * w1 + xp1 * w2 + bb;
  }
}

// ---------------- kv_in = dw3(x2t) + x2t ----------------
__global__ __launch_bounds__(256) void k_kvin(const float* __restrict__ xt,
                                              const float* __restrict__ lcw,
                                              const float* __restrict__ lcb,
                                              float* __restrict__ kvin) {
  int c = blockIdx.x, b = blockIdx.y;
  const float* row = xt + ((size_t)b * C + C2 + c) * L;
  float w0 = lcw[c * 3], w1 = lcw[c * 3 + 1] + 1.0f, w2 = lcw[c * 3 + 2], bb = lcb[c];
  float* orow = kvin + ((size_t)b * C2 + c) * L;
  for (int l = threadIdx.x; l < L; l += 256) {
    float xm1 = (l > 0) ? row[l - 1] : 0.f;
    float x0 = row[l];
    float xp1 = (l < L - 1) ? row[l + 1] : 0.f;
    orow[l] = xm1 * w0 + x0 * w1 + xp1 * w2 + bb;
  }
}

// ---------------- generic fp32 GEMM: Y[b,o,l] = sum_k (X[b,k,l]*scale[k]) * W[o,k] + bias[o] ----------------
__global__ __launch_bounds__(256) void k_gemm(const float* __restrict__ W,
                                              const float* __restrict__ X,
                                              float* __restrict__ Y,
                                              const float* __restrict__ scale,
                                              const float* __restrict__ bias,
                                              int O, int Kd, size_t xbs, size_t ybs,
                                              int do_gelu) {
  __shared__ float Ws[16][64];
  __shared__ float Xs[16][64];
  int b = blockIdx.z;
  int o0 = blockIdx.y * 64, l0 = blockIdx.x * 64;
  int t = threadIdx.x;
  int tx = t & 15, ty = t >> 4;
  const float* Xb = X + (size_t)b * xbs;
  float acc[4][4] = {{0.f}};
  for (int k0 = 0; k0 < Kd; k0 += 16) {
    {
      int o = t >> 2, ks = (t & 3) * 4;
      int oo = o0 + o;
      float4 w4 = make_float4(0.f, 0.f, 0.f, 0.f);
      if (oo < O) w4 = *reinterpret_cast<const float4*>(W + (size_t)oo * Kd + k0 + ks);
      Ws[ks + 0][o] = w4.x; Ws[ks + 1][o] = w4.y; Ws[ks + 2][o] = w4.z; Ws[ks + 3][o] = w4.w;
    }
    #pragma unroll
    for (int i = 0; i < 4; i++) {
      int f = t + i * 256;
      int kk = f >> 6, ll = f & 63;
      int l = l0 + ll;
      float v = (l < L) ? Xb[(size_t)(k0 + kk) * L + l] : 0.f;
      if (scale) v *= scale[k0 + kk];
      Xs[kk][ll] = v;
    }
    __syncthreads();
    #pragma unroll
    for (int k = 0; k < 16; k++) {
      float4 a4 = *reinterpret_cast<const float4*>(&Ws[k][ty * 4]);
      float4 x4 = *reinterpret_cast<const float4*>(&Xs[k][tx * 4]);
      acc[0][0] += a4.x * x4.x; acc[0][1] += a4.x * x4.y; acc[0][2] += a4.x * x4.z; acc[0][3] += a4.x * x4.w;
      acc[1][0] += a4.y * x4.x; acc[1][1] += a4.y * x4.y; acc[1][2] += a4.y * x4.z; acc[1][3] += a4.y * x4.w;
      acc[2][0] += a4.z * x4.x; acc[2][1] += a4.z * x4.y; acc[2][2] += a4.z * x4.z; acc[2][3] += a4.z * x4.w;
      acc[3][0] += a4.w * x4.x; acc[3][1] += a4.w * x4.y; acc[3][2] += a4.w * x4.z; acc[3][3] += a4.w * x4.w;
    }
    __syncthreads();
  }
  #pragma unroll
  for (int i = 0; i < 4; i++) {
    int o = o0 + ty * 4 + i;
    if (o >= O) break;
    float bo = bias ? bias[o] : 0.f;
    float* yrow = Y + (size_t)b * ybs + (size_t)o * L;
    #pragma unroll
    for (int j = 0; j < 4; j++) {
      int l = l0 + tx * 4 + j;
      if (l >= L) break;
      float v = acc[i][j] + bo;
      if (do_gelu) v = gelu_f(v);
      yrow[l] = v;
    }
  }
}

// ---------------- flash attention: 64 q-rows per block, tiles of 64 m ----------------
// thread layout: wave w, lane; ty = w*4 + (lane>>4) -> l-quad, tx = lane&15 -> m-quad.
// All 16 threads sharing an l-row are in one wave -> row sums via shfl_xor over tx.
// Logits are tiny (|s|<~1, weights*0.02) -> unnormalized exp, divide by rowsum at end.
__global__ __launch_bounds__(256) void k_attn_flash(const float* __restrict__ q,
                                                    const float* __restrict__ kv,
                                                    float* __restrict__ out) {
  __shared__ __align__(16) float Qs[48 * 64];     // [d][l], Q pre-scaled by ATT_SCALE
  __shared__ __align__(16) float KVs[64 * 52];    // union: K as [d][64] (48*64) / V as [m][52]
  __shared__ __align__(16) float Ps[64 * 68];     // P as [m][l-padded]; epilogue: O as [d][64]
  int lt0 = blockIdx.x * 64;
  int h = blockIdx.y, b = blockIdx.z;
  int t = threadIdx.x;
  int w = t >> 6, lane = t & 63;
  int ty = w * 4 + (lane >> 4);   // l-quad 0..15
  int tx = lane & 15;             // m-quad 0..15
  const float* qb = q  + ((size_t)b * C2 + h * HD) * L;
  const float* kb = kv + ((size_t)b * C  + h * HD) * L;
  const float* vb = kv + ((size_t)b * C  + C2 + h * HD) * L;

  for (int idx = t; idx < 48 * 64; idx += 256) {
    int d = idx >> 6, ll = idx & 63;
    int l = lt0 + ll;
    Qs[idx] = (l < L) ? qb[(size_t)d * L + l] * ATT_SCALE : 0.f;
  }

  float o[4][3] = {{0.f, 0.f, 0.f}, {0.f, 0.f, 0.f}, {0.f, 0.f, 0.f}, {0.f, 0.f, 0.f}};
  float rs[4] = {0.f, 0.f, 0.f, 0.f};
  __syncthreads();

  for (int m0 = 0; m0 < L; m0 += 64) {
    // K tile -> KVs[d][m]
    for (int idx = t; idx < 48 * 64; idx += 256) {
      int d = idx >> 6, mm = idx & 63;
      int m = m0 + mm;
      KVs[idx] = (m < L) ? kb[(size_t)d * L + m] : 0.f;
    }
    __syncthreads();
    // S fragment 4l x 4m
    float s[4][4] = {{0.f}};
    #pragma unroll
    for (int d = 0; d < 48; d++) {
      float4 qv = *reinterpret_cast<const float4*>(&Qs[d * 64 + ty * 4]);
      float4 kx = *reinterpret_cast<const float4*>(&KVs[d * 64 + tx * 4]);
      s[0][0] += qv.x * kx.x; s[0][1] += qv.x * kx.y; s[0][2] += qv.x * kx.z; s[0][3] += qv.x * kx.w;
      s[1][0] += qv.y * kx.x; s[1][1] += qv.y * kx.y; s[1][2] += qv.y * kx.z; s[1][3] += qv.y * kx.w;
      s[2][0] += qv.z * kx.x; s[2][1] += qv.z * kx.y; s[2][2] += qv.z * kx.z; s[2][3] += qv.z * kx.w;
      s[3][0] += qv.w * kx.x; s[3][1] += qv.w * kx.y; s[3][2] += qv.w * kx.z; s[3][3] += qv.w * kx.w;
    }
    // P = exp(S) with m-mask; row sums via shfl over tx; write P to LDS [m][l]
    bool mv[4];
    #pragma unroll
    for (int j = 0; j < 4; j++) mv[j] = (m0 + tx * 4 + j) < L;
    #pragma unroll
    for (int i = 0; i < 4; i++) {
      float rt = 0.f;
      #pragma unroll
      for (int j = 0; j < 4; j++) {
        float p = mv[j] ? __expf(s[i][j]) : 0.f;
        s[i][j] = p;
        rt += p;
      }
      rt += __shfl_xor(rt, 1);
      rt += __shfl_xor(rt, 2);
      rt += __shfl_xor(rt, 4);
      rt += __shfl_xor(rt, 8);
      rs[i] += rt;
    }
    #pragma unroll
    for (int j = 0; j < 4; j++) {
      float4 pj = make_float4(s[0][j], s[1][j], s[2][j], s[3][j]);
      *reinterpret_cast<float4*>(&Ps[(tx * 4 + j) * 68 + ty * 4]) = pj;
    }
    __syncthreads();   // KVs reads (S) done, Ps visible
    // V tile -> KVs[m][d] (transposed, stride 52)
    for (int idx = t; idx < 48 * 64; idx += 256) {
      int d = idx >> 6, mm = idx & 63;
      int m = m0 + mm;
      KVs[mm * 52 + d] = (m < L) ? vb[(size_t)d * L + m] : 0.f;
    }
    __syncthreads();   // V visible
    // O += P * V : each thread 4l x 3d (d = 3*tx .. +2)
    #pragma unroll 8
    for (int m = 0; m < 64; m++) {
      float4 pv = *reinterpret_cast<const float4*>(&Ps[m * 68 + ty * 4]);
      float v0 = KVs[m * 52 + 3 * tx + 0];
      float v1 = KVs[m * 52 + 3 * tx + 1];
      float v2 = KVs[m * 52 + 3 * tx + 2];
      o[0][0] += pv.x * v0; o[0][1] += pv.x * v1; o[0][2] += pv.x * v2;
      o[1][0] += pv.y * v0; o[1][1] += pv.y * v1; o[1][2] += pv.y * v2;
      o[2][0] += pv.z * v0; o[2][1] += pv.z * v1; o[2][2] += pv.z * v2;
      o[3][0] += pv.w * v0; o[3][1] += pv.w * v1; o[3][2] += pv.w * v2;
    }
    __syncthreads();   // PV done reading Ps/KVs before next iter overwrites
  }
  // normalize, stage O in LDS as [d][l], store coalesced
  #pragma unroll
  for (int i = 0; i < 4; i++) {
    float inv = 1.f / rs[i];
    #pragma unroll
    for (int k = 0; k < 3; k++)
      Ps[(3 * tx + k) * 64 + ty * 4 + i] = o[i][k] * inv;
  }
  __syncthreads();
  for (int idx = t; idx < 48 * 64; idx += 256) {
    int d = idx >> 6, ll = idx & 63;
    int l = lt0 + ll;
    if (l < L) out[((size_t)b * C2 + h * HD + d) * L + l] = Ps[idx];
  }
}

// ---------------- scatter attention out (weird reshape) -> xt2 upper half ----------------
__global__ void k_fill_xt2(const float* __restrict__ ao, float* __restrict__ xt2) {
  __shared__ float tile[32][33];
  int b = blockIdx.z;
  int l0 = blockIdx.x * 32, c0 = blockIdx.y * 32;
  int tx = threadIdx.x, ty = threadIdx.y;
  #pragma unroll
  for (int i = 0; i < 4; i++) {
    int l = l0 + ty + i * 8, c = c0 + tx;
    if (l < L) tile[ty + i * 8][tx] = ao[(size_t)b * ((size_t)L * C2) + (size_t)l * C2 + c];
  }
  __syncthreads();
  #pragma unroll
  for (int i = 0; i < 4; i++) {
    int c = c0 + ty + i * 8, l = l0 + tx;
    if (l < L) xt2[((size_t)b * C + C2 + c) * L + l] = tile[tx][ty + i * 8];
  }
}

// ---------------- projection dw3 + gelu -> t1, accumulate bn1 stats ----------------
__global__ __launch_bounds__(256) void k_dwproj(const float* __restrict__ xt2,
                                                const float* __restrict__ dww,
                                                const float* __restrict__ dwb,
                                                float* __restrict__ t1,
                                                float* __restrict__ sum, float* __restrict__ sq) {
  int c = blockIdx.x, b = blockIdx.y;
  const float* row = xt2 + ((size_t)b * C + c) * L;
  float w0 = dww[c * 3], w1 = dww[c * 3 + 1], w2 = dww[c * 3 + 2], bb = dwb[c];
  float* orow = t1 + ((size_t)b * C + c) * L;
  float s = 0.f, s2 = 0.f;
  for (int l = threadIdx.x; l < L; l += 256) {
    float xm1 = (l > 0) ? row[l - 1] : 0.f;
    float x0 = row[l];
    float xp1 = (l < L - 1) ? row[l + 1] : 0.f;
    float v = gelu_f(xm1 * w0 + x0 * w1 + xp1 * w2 + bb);
    orow[l] = v;
    s += v; s2 += v * v;
  }
  s = wave_sum(s); s2 = wave_sum(s2);
  __shared__ float r1[4], r2[4];
  int lane = threadIdx.x & 63, wid = threadIdx.x >> 6;
  if (lane == 0) { r1[wid] = s; r2[wid] = s2; }
  __syncthreads();
  if (threadIdx.x == 0) {
    atomicAdd(&sum[c], r1[0] + r1[1] + r1[2] + r1[3]);
    atomicAdd(&sq[c], r2[0] + r2[1] + r2[2] + r2[3]);
  }
}

// ---------------- generic per-(b,c)-row stats ----------------
__global__ __launch_bounds__(256) void k_rowstats(const float* __restrict__ Y, int Cn,
                                                  float* __restrict__ sum, float* __restrict__ sq) {
  int c = blockIdx.x, b = blockIdx.y;
  const float* row = Y + ((size_t)b * Cn + c) * L;
  float s = 0.f, s2 = 0.f;
  for (int l = threadIdx.x; l < L; l += 256) { float v = row[l]; s += v; s2 += v * v; }
  s = wave_sum(s); s2 = wave_sum(s2);
  __shared__ float r1[4], r2[4];
  int lane = threadIdx.x & 63, wid = threadIdx.x >> 6;
  if (lane == 0) { r1[wid] = s; r2[wid] = s2; }
  __syncthreads();
  if (threadIdx.x == 0) {
    atomicAdd(&sum[c], r1[0] + r1[1] + r1[2] + r1[3]);
    atomicAdd(&sq[c], r2[0] + r2[1] + r2[2] + r2[3]);
  }
}

// ---------------- finalize bn1 (s1,d1) and folded c1 bias cb1 ----------------
__global__ void k_fin1(const float* __restrict__ sum, const float* __restrict__ sq,
                       const float* __restrict__ g, const float* __restrict__ be,
                       const float* __restrict__ c1w, const float* __restrict__ c1b,
                       float* __restrict__ s1, float* __restrict__ d1, float* __restrict__ cb1) {
  int t = threadIdx.x;
  if (t < C) {
    float m = sum[t] * INV_N;
    float v = sq[t] * INV_N - m * m;
    float r = rsqrtf(v + BN_EPS);
    float sc = g[t] * r;
    s1[t] = sc;
    d1[t] = be[t] - m * sc;
  }
  __syncthreads();
  if (t < 96) {
    float a = c1b[t];
    const float* wr = c1w + (size_t)t * C;
    for (int c = 0; c < C; c++) a += d1[c] * wr[c];
    cb1[t] = a;
  }
}

// ---------------- finalize bn2 (s2,d2) and folded c2 bias cb2 ----------------
__global__ void k_fin2(const float* __restrict__ sum, const float* __restrict__ sq,
                       const float* __restrict__ g, const float* __restrict__ be,
                       const float* __restrict__ c2w, const float* __restrict__ c2b,
                       float* __restrict__ s2, float* __restrict__ d2, float* __restrict__ cb2) {
  int t = threadIdx.x;
  if (t < 96) {
    float m = sum[t] * INV_N;
    float v = sq[t] * INV_N - m * m;
    float r = rsqrtf(v + BN_EPS);
    float sc = g[t] * r;
    s2[t] = sc;
    d2[t] = be[t] - m * sc;
  }
  __syncthreads();
  if (t < C) {
    float a = c2b[t];
    const float* wr = c2w + (size_t)t * 96;
    for (int i = 0; i < 96; i++) a += d2[i] * wr[i];
    cb2[t] = a;
  }
}

// ---------------- finalize bn3 ----------------
__global__ void k_fin3(const float* __restrict__ sum, const float* __restrict__ sq,
                       const float* __restrict__ g, const float* __restrict__ be,
                       float* __restrict__ s3, float* __restrict__ d3) {
  int t = threadIdx.x;
  if (t < C) {
    float m = sum[t] * INV_N;
    float v = sq[t] * INV_N - m * m;
    float r = rsqrtf(v + BN_EPS);
    float sc = g[t] * r;
    s3[t] = sc;
    d3[t] = be[t] - m * sc;
  }
}

// ---------------- final: out[b,l,c] = bn3(y3)[b,c,l] + xt2[b,c,l] ----------------
__global__ void k_final(const float* __restrict__ y3, const float* __restrict__ xt2,
                        const float* __restrict__ s3, const float* __restrict__ d3,
                        float* __restrict__ out) {
  __shared__ float tile[32][33];
  int b = blockIdx.z;
  int l0 = blockIdx.x * 32, c0 = blockIdx.y * 32;
  int tx = threadIdx.x, ty = threadIdx.y;
  #pragma unroll
  for (int i = 0; i < 4; i++) {
    int c = c0 + ty + i * 8, l = l0 + tx;
    if (l < L) {
      size_t idx = ((size_t)b * C + c) * L + l;
      tile[ty + i * 8][tx] = y3[idx] * s3[c] + d3[c] + xt2[idx];
    }
  }
  __syncthreads();
  #pragma unroll
  for (int i = 0; i < 4; i++) {
    int l = l0 + ty + i * 8, c = c0 + tx;
    if (l < L) out[((size_t)b * L + l) * C + c] = tile[tx][ty + i * 8];
  }
}

extern "C" void kernel_launch(void* const* d_in, const int* in_sizes, int n_in,
                              void* d_out, int out_size, void* d_ws, size_t ws_size,
                              hipStream_t stream) {
  const float* x    = (const float*)d_in[0];
  const float* dcw  = (const float*)d_in[1];
  const float* dcb  = (const float*)d_in[2];
  const float* p1w  = (const float*)d_in[3];
  const float* p1b  = (const float*)d_in[4];
  const float* p2w  = (const float*)d_in[5];
  const float* p2b  = (const float*)d_in[6];
  const float* qw   = (const float*)d_in[7];
  const float* qb   = (const float*)d_in[8];
  const float* kvw  = (const float*)d_in[9];
  const float* kvb  = (const float*)d_in[10];
  const float* lcw  = (const float*)d_in[11];
  const float* lcb  = (const float*)d_in[12];
  const float* dww  = (const float*)d_in[13];
  const float* dwb  = (const float*)d_in[14];
  const float* bn1g = (const float*)d_in[15];
  const float* bn1b = (const float*)d_in[16];
  const float* c1w  = (const float*)d_in[17];
  const float* c1b  = (const float*)d_in[18];
  const float* bn2g = (const float*)d_in[19];
  const float* bn2b = (const float*)d_in[20];
  const float* c2w  = (const float*)d_in[21];
  const float* c2b  = (const float*)d_in[22];
  const float* bn3g = (const float*)d_in[23];
  const float* bn3b = (const float*)d_in[24];
  float* out = (float*)d_out;
  float* ws  = (float*)d_ws;

  float* xt      = ws + OFF_XT;     // later reused as t1
  float* xt2     = ws + OFF_XT2;
  float* kvbuf   = ws + OFF_KV;     // later reused as y3
  float* kvin    = ws + OFF_KVIN;   // later reused as attnout
  float* qbuf    = ws + OFF_Q;      // later reused as h2
  float* sm      = ws + OFF_SM;

  float* pooled = sm + SM_POOLED;
  float* xm     = sm + SM_XM;
  float* h1     = sm + SM_H1;
  float* wdyn   = sm + SM_WDYN;
  float* bdyn   = sm + SM_BDYN;
  float* sum1 = sm + SM_SUM1; float* sq1 = sm + SM_SQ1;
  float* s1 = sm + SM_S1; float* d1 = sm + SM_D1; float* cb1 = sm + SM_CB1;
  float* sum2 = sm + SM_SUM2; float* sq2 = sm + SM_SQ2;
  float* s2 = sm + SM_S2; float* d2 = sm + SM_D2; float* cb2 = sm + SM_CB2;
  float* sum3 = sm + SM_SUM3; float* sq3 = sm + SM_SQ3;
  float* s3 = sm + SM_S3; float* d3 = sm + SM_D3;

  // zero the bn-stat accumulators (covers sum1..sq3 span; s/d/cb overwritten anyway)
  hipMemsetAsync((void*)(sm + SM_SUM1), 0, (SM_S3 - SM_SUM1) * sizeof(float), stream);

  dim3 tb32(32, 8);
  // 1. transpose input
  k_transpose_in<<<dim3(32, 24, B), tb32, 0, stream>>>(x, xt);
  // 2. pooled / mean
  k_pool<<<dim3(C2, B), 256, 0, stream>>>(xt, pooled, xm);
  // 3. tiny MLP
  k_mlp1<<<dim3(4, B), 128, 0, stream>>>(pooled, xm, p1w, p1b, h1);
  k_mix2<<<dim3(4, B), 384, 0, stream>>>(h1, p2w, p2b, dcw, dcb, wdyn, bdyn);
  // 4. dynamic conv -> xt2 lower
  k_dynconv<<<dim3(C2, B), 256, 0, stream>>>(xt, wdyn, bdyn, xt2);
  // 5. kv_in
  k_kvin<<<dim3(C2, B), 256, 0, stream>>>(xt, lcw, lcb, kvin);
  // 6. q = qw @ x2t  (O=384, K=384)
  k_gemm<<<dim3(16, 6, B), 256, 0, stream>>>(qw, xt + (size_t)C2 * L, qbuf, nullptr, qb,
                                             C2, C2, (size_t)C * L, (size_t)C2 * L, 0);
  // 7. kv = kvw @ kv_in (O=768, K=384)
  k_gemm<<<dim3(16, 12, B), 256, 0, stream>>>(kvw, kvin, kvbuf, nullptr, kvb,
                                              C, C2, (size_t)C2 * L, (size_t)C * L, 0);
  // 8. flash attention -> attnout (reuses kvin buffer)
  k_attn_flash<<<dim3(16, H, B), 256, 0, stream>>>(qbuf, kvbuf, kvin);
  // 9. scatter (bug-compatible reshape) -> xt2 upper
  k_fill_xt2<<<dim3(32, 12, B), tb32, 0, stream>>>(kvin, xt2);
  // 10. projection dw3+gelu -> t1 (reuses xt), bn1 stats
  k_dwproj<<<dim3(C, B), 256, 0, stream>>>(xt2, dww, dwb, xt, sum1, sq1);
  k_fin1<<<1, 768, 0, stream>>>(sum1, sq1, bn1g, bn1b, c1w, c1b, s1, d1, cb1);
  // 11. c1 GEMM (bn1 folded) + gelu -> h2 (reuses qbuf), O=96, K=768
  k_gemm<<<dim3(16, 2, B), 256, 0, stream>>>(c1w, xt, qbuf, s1, cb1,
                                             96, C, (size_t)C * L, (size_t)96 * L, 1);
  k_rowstats<<<dim3(96, B), 256, 0, stream>>>(qbuf, 96, sum2, sq2);
  k_fin2<<<1, 768, 0, stream>>>(sum2, sq2, bn2g, bn2b, c2w, c2b, s2, d2, cb2);
  // 12. c2 GEMM (bn2 folded) -> y3 (reuses kvbuf), O=768, K=96
  k_gemm<<<dim3(16, 12, B), 256, 0, stream>>>(c2w, qbuf, kvbuf, s2, cb2,
                                              C, 96, (size_t)96 * L, (size_t)C * L, 0);
  k_rowstats<<<dim3(C, B), 256, 0, stream>>>(kvbuf, C, sum3, sq3);
  k_fin3<<<1, 768, 0, stream>>>(sum3, sq3, bn3g, bn3b, s3, d3);
  // 13. final bn3 + residual + transpose back
  k_final<<<dim3(32, 24, B), tb32, 0, stream>>>(kvbuf, xt2, s3, d3, out);
}

// Round 3
// 662.879 us; speedup vs baseline: 3.2590x; 2.0588x over previous
//
#include <hip/hip_runtime.h>
#include <cstddef>

constexpr int B = 8, L = 999, C = 768, C2 = 384, H = 8, HD = 48;
constexpr float ATT_SCALE = 0.14433756729740644f;   // 48^-0.5
constexpr float BN_EPS = 1e-5f;
constexpr float INV_N = 1.0f / (8.0f * 999.0f);     // 1/(B*L)

constexpr size_t SZ_XT   = (size_t)B * C * L;       // 6,137,856
constexpr size_t SZ_HALF = (size_t)B * C2 * L;      // 3,068,928
constexpr size_t OFF_XT   = 0;                      // xt, later t1
constexpr size_t OFF_XT2  = SZ_XT;                  // xt2 (concat branch outputs, transposed)
constexpr size_t OFF_KV   = 2 * SZ_XT;              // kv,   later y3
constexpr size_t OFF_KVIN = 3 * SZ_XT;              // kvin, later attnout
constexpr size_t OFF_Q    = 3 * SZ_XT + SZ_HALF;    // q,    later h2
constexpr size_t OFF_SM   = 3 * SZ_XT + 2 * SZ_HALF;

// small-region offsets (floats, relative to OFF_SM)
constexpr size_t SM_POOLED = 0;       // B*C2*3
constexpr size_t SM_XM     = 9216;    // B*C2
constexpr size_t SM_H1     = 12288;   // B*4*96
constexpr size_t SM_WDYN   = 15360;   // B*C2*3
constexpr size_t SM_BDYN   = 24576;   // B*C2
constexpr size_t SM_SUM1   = 27648;   // 768
constexpr size_t SM_SQ1    = 28416;
constexpr size_t SM_S1     = 29184;
constexpr size_t SM_D1     = 29952;
constexpr size_t SM_CB1    = 30720;   // 96
constexpr size_t SM_SUM2   = 30816;   // 96
constexpr size_t SM_SQ2    = 30912;
constexpr size_t SM_S2     = 31008;
constexpr size_t SM_D2     = 31104;
constexpr size_t SM_CB2    = 31200;   // 768
constexpr size_t SM_SUM3   = 31968;
constexpr size_t SM_SQ3    = 32736;
constexpr size_t SM_S3     = 33504;
constexpr size_t SM_D3     = 34272;
constexpr size_t SM_END    = 35040;

typedef __attribute__((ext_vector_type(8))) short bf16x8;
typedef __attribute__((ext_vector_type(4))) float floatx4;

__device__ __forceinline__ float gelu_f(float x) {
  return 0.5f * x * (1.0f + erff(x * 0.70710678118654752f));
}

__device__ __forceinline__ float wave_sum(float v) {
  #pragma unroll
  for (int off = 32; off > 0; off >>= 1) v += __shfl_down(v, off, 64);
  return v;
}

__device__ __forceinline__ short f2bf(float f) {
  union { float f; unsigned u; } x; x.f = f;
  unsigned r = x.u + 0x7FFFu + ((x.u >> 16) & 1u);
  return (short)(r >> 16);
}

// ---------------- transpose x (B,L,C) -> xt (B,C,L) ----------------
__global__ void k_transpose_in(const float* __restrict__ x, float* __restrict__ xt) {
  __shared__ float tile[32][33];
  int b = blockIdx.z;
  int l0 = blockIdx.x * 32, c0 = blockIdx.y * 32;
  int tx = threadIdx.x, ty = threadIdx.y;
  #pragma unroll
  for (int i = 0; i < 4; i++) {
    int l = l0 + ty + i * 8, c = c0 + tx;
    if (l < L) tile[ty + i * 8][tx] = x[((size_t)b * L + l) * C + c];
  }
  __syncthreads();
  #pragma unroll
  for (int i = 0; i < 4; i++) {
    int c = c0 + ty + i * 8, l = l0 + tx;
    if (l < L) xt[((size_t)b * C + c) * L + l] = tile[tx][ty + i * 8];
  }
}

// ---------------- pooled chunk means + row mean (dyn-conv branch) ----------------
__global__ __launch_bounds__(256) void k_pool(const float* __restrict__ xt,
                                              float* __restrict__ pooled,
                                              float* __restrict__ xm) {
  int c = blockIdx.x, b = blockIdx.y;       // c < 384
  const float* row = xt + ((size_t)b * C + c) * L;
  float s0 = 0.f, s1 = 0.f, s2 = 0.f;
  for (int l = threadIdx.x; l < L; l += 256) {
    float v = row[l];
    int ch = l / 333;
    if (ch == 0) s0 += v; else if (ch == 1) s1 += v; else s2 += v;
  }
  s0 = wave_sum(s0); s1 = wave_sum(s1); s2 = wave_sum(s2);
  __shared__ float r[3][4];
  int lane = threadIdx.x & 63, wid = threadIdx.x >> 6;
  if (lane == 0) { r[0][wid] = s0; r[1][wid] = s1; r[2][wid] = s2; }
  __syncthreads();
  if (threadIdx.x == 0) {
    float t0 = r[0][0] + r[0][1] + r[0][2] + r[0][3];
    float t1 = r[1][0] + r[1][1] + r[1][2] + r[1][3];
    float t2 = r[2][0] + r[2][1] + r[2][2] + r[2][3];
    size_t pb = (size_t)(b * C2 + c) * 3;
    pooled[pb + 0] = t0 / 333.f;
    pooled[pb + 1] = t1 / 333.f;
    pooled[pb + 2] = t2 / 333.f;
    xm[b * C2 + c] = (t0 + t1 + t2) / 999.f;
  }
}

// ---------------- tiny MLP layer 1: gelu(p1w @ in + p1b) ----------------
__global__ void k_mlp1(const float* __restrict__ pooled, const float* __restrict__ xm,
                       const float* __restrict__ p1w, const float* __restrict__ p1b,
                       float* __restrict__ h1) {
  int j = blockIdx.x, b = blockIdx.y;       // j in 0..3 (0..2 pooled cols, 3 = mean)
  __shared__ float vin[C2];
  for (int c = threadIdx.x; c < C2; c += 128)
    vin[c] = (j < 3) ? pooled[(size_t)(b * C2 + c) * 3 + j] : xm[b * C2 + c];
  __syncthreads();
  int o = threadIdx.x;
  if (o < 96) {
    float acc = p1b[o];
    const float* wr = p1w + (size_t)o * C2;
    for (int c = 0; c < C2; c++) acc += vin[c] * wr[c];
    h1[(b * 4 + j) * 96 + o] = gelu_f(acc);
  }
}

// ---------------- MLP layer 2 + softmax over G + weight/bias mix ----------------
__global__ void k_mix2(const float* __restrict__ h1,
                       const float* __restrict__ p2w, const float* __restrict__ p2b,
                       const float* __restrict__ dcw, const float* __restrict__ dcb,
                       float* __restrict__ wdyn, float* __restrict__ bdyn) {
  int j = blockIdx.x, b = blockIdx.y;
  __shared__ float hv[96];
  for (int i = threadIdx.x; i < 96; i += 384) hv[i] = h1[(b * 4 + j) * 96 + i];
  __syncthreads();
  int c = threadIdx.x;                       // < 384
  float a0 = p2b[c], a1 = p2b[C2 + c];
  const float* w0r = p2w + (size_t)c * 96;
  const float* w1r = p2w + (size_t)(C2 + c) * 96;
  for (int i = 0; i < 96; i++) { float h = hv[i]; a0 += h * w0r[i]; a1 += h * w1r[i]; }
  float m = fmaxf(a0, a1);
  float e0 = __expf(a0 - m), e1 = __expf(a1 - m);
  float inv = 1.f / (e0 + e1);
  float p0 = e0 * inv, p1 = e1 * inv;
  if (j < 3)
    wdyn[(size_t)(b * C2 + c) * 3 + j] = p0 * dcw[(size_t)c * 3 + j] + p1 * dcw[(size_t)(C2 + c) * 3 + j];
  else
    bdyn[b * C2 + c] = p0 * dcb[c] + p1 * dcb[C2 + c];
}

// ---------------- dynamic depthwise conv -> xt2 lower half ----------------
__global__ __launch_bounds__(256) void k_dynconv(const float* __restrict__ xt,
                                                 const float* __restrict__ wdyn,
                                                 const float* __restrict__ bdyn,
                                                 float* __restrict__ xt2) {
  int c = blockIdx.x, b = blockIdx.y;
  const float* row = xt + ((size_t)b * C + c) * L;
  size_t wb = (size_t)(b * C2 + c) * 3;
  float w0 = wdyn[wb], w1 = wdyn[wb + 1], w2 = wdyn[wb + 2], bb = bdyn[b * C2 + c];
  float* orow = xt2 + ((size_t)b * C + c) * L;
  for (int l = threadIdx.x; l < L; l += 256) {
    float xm1 = (l > 0) ? row[l - 1] : 0.f;
    float x0 = row[l];
    float xp1 = (l < L - 1) ? row[l + 1] : 0.f;
    orow[l] = xm1 * w0 + x0 * w1 + xp1 * w2 + bb;
  }
}

// ---------------- kv_in = dw3(x2t) + x2t ----------------
__global__ __launch_bounds__(256) void k_kvin(const float* __restrict__ xt,
                                              const float* __restrict__ lcw,
                                              const float* __restrict__ lcb,
                                              float* __restrict__ kvin) {
  int c = blockIdx.x, b = blockIdx.y;
  const float* row = xt + ((size_t)b * C + C2 + c) * L;
  float w0 = lcw[c * 3], w1 = lcw[c * 3 + 1] + 1.0f, w2 = lcw[c * 3 + 2], bb = lcb[c];
  float* orow = kvin + ((size_t)b * C2 + c) * L;
  for (int l = threadIdx.x; l < L; l += 256) {
    float xm1 = (l > 0) ? row[l - 1] : 0.f;
    float x0 = row[l];
    float xp1 = (l < L - 1) ? row[l + 1] : 0.f;
    orow[l] = xm1 * w0 + x0 * w1 + xp1 * w2 + bb;
  }
}

// ---------------- generic fp32 GEMM: Y[b,o,l] = sum_k (X[b,k,l]*scale[k]) * W[o,k] + bias[o] ----------------
__global__ __launch_bounds__(256) void k_gemm(const float* __restrict__ W,
                                              const float* __restrict__ X,
                                              float* __restrict__ Y,
                                              const float* __restrict__ scale,
                                              const float* __restrict__ bias,
                                              int O, int Kd, size_t xbs, size_t ybs,
                                              int do_gelu) {
  __shared__ float Ws[16][64];
  __shared__ float Xs[16][64];
  int b = blockIdx.z;
  int o0 = blockIdx.y * 64, l0 = blockIdx.x * 64;
  int t = threadIdx.x;
  int tx = t & 15, ty = t >> 4;
  const float* Xb = X + (size_t)b * xbs;
  float acc[4][4] = {{0.f}};
  for (int k0 = 0; k0 < Kd; k0 += 16) {
    {
      int o = t >> 2, ks = (t & 3) * 4;
      int oo = o0 + o;
      float4 w4 = make_float4(0.f, 0.f, 0.f, 0.f);
      if (oo < O) w4 = *reinterpret_cast<const float4*>(W + (size_t)oo * Kd + k0 + ks);
      Ws[ks + 0][o] = w4.x; Ws[ks + 1][o] = w4.y; Ws[ks + 2][o] = w4.z; Ws[ks + 3][o] = w4.w;
    }
    #pragma unroll
    for (int i = 0; i < 4; i++) {
      int f = t + i * 256;
      int kk = f >> 6, ll = f & 63;
      int l = l0 + ll;
      float v = (l < L) ? Xb[(size_t)(k0 + kk) * L + l] : 0.f;
      if (scale) v *= scale[k0 + kk];
      Xs[kk][ll] = v;
    }
    __syncthreads();
    #pragma unroll
    for (int k = 0; k < 16; k++) {
      float4 a4 = *reinterpret_cast<const float4*>(&Ws[k][ty * 4]);
      float4 x4 = *reinterpret_cast<const float4*>(&Xs[k][tx * 4]);
      acc[0][0] += a4.x * x4.x; acc[0][1] += a4.x * x4.y; acc[0][2] += a4.x * x4.z; acc[0][3] += a4.x * x4.w;
      acc[1][0] += a4.y * x4.x; acc[1][1] += a4.y * x4.y; acc[1][2] += a4.y * x4.z; acc[1][3] += a4.y * x4.w;
      acc[2][0] += a4.z * x4.x; acc[2][1] += a4.z * x4.y; acc[2][2] += a4.z * x4.z; acc[2][3] += a4.z * x4.w;
      acc[3][0] += a4.w * x4.x; acc[3][1] += a4.w * x4.y; acc[3][2] += a4.w * x4.z; acc[3][3] += a4.w * x4.w;
    }
    __syncthreads();
  }
  #pragma unroll
  for (int i = 0; i < 4; i++) {
    int o = o0 + ty * 4 + i;
    if (o >= O) break;
    float bo = bias ? bias[o] : 0.f;
    float* yrow = Y + (size_t)b * ybs + (size_t)o * L;
    #pragma unroll
    for (int j = 0; j < 4; j++) {
      int l = l0 + tx * 4 + j;
      if (l >= L) break;
      float v = acc[i][j] + bo;
      if (do_gelu) v = gelu_f(v);
      yrow[l] = v;
    }
  }
}

// ---------------- MFMA flash attention: 64 q-rows per block, one (b,h) ----------------
// mfma_f32_16x16x32_bf16. C/D: col=lane&15, row=quad*4+reg. A: A[m=lane&15][k=quad*8+j].
// Qs/Ks/Ps: bf16 [row][64+pad], stride 72 bf16 (144B, 16B-aligned rows, 2-way b128 reads).
// Vf: pre-packed B-fragment order, one b128 read per fragment.
// Unnormalized exp (|s| small): rowsum accumulated fp32, divide at end.
__global__ __launch_bounds__(256) void k_attn_mfma(const float* __restrict__ q,
                                                   const float* __restrict__ kv,
                                                   float* __restrict__ out) {
  __shared__ __align__(16) char smem[9216 * 3 + 6144];
  short* Qs = (short*)smem;              // [64 l][72] bf16
  short* Ks = (short*)(smem + 9216);     // [64 m][72] bf16
  short* Ps = (short*)(smem + 18432);    // [64 l][72] bf16
  short* Vf = (short*)(smem + 27648);    // [chunk2][dsub3][lane64][8] bf16
  float* Os = (float*)smem;              // epilogue overlay over Qs+Ks: [48 d][66 l] fp32

  int lt0 = blockIdx.x * 64;
  int h = blockIdx.y, b = blockIdx.z;
  int t = threadIdx.x;
  int w = t >> 6, lane = t & 63;
  int col = lane & 15, quad = lane >> 4;
  const float* qb = q  + ((size_t)b * C2 + h * HD) * L;
  const float* kb = kv + ((size_t)b * C  + h * HD) * L;
  const float* vb = kv + ((size_t)b * C + C2 + h * HD) * L;

  // zero the d=48..63 pad of Qs and Ks (never rewritten)
  for (int i = t; i < 64 * 16; i += 256) {
    int row = i >> 4, d = 48 + (i & 15);
    Qs[row * 72 + d] = 0;
    Ks[row * 72 + d] = 0;
  }
  // stage Q (scaled), d-pairs -> b32 writes
  for (int i = t; i < 64 * 24; i += 256) {
    int d2 = i >> 6, ll = i & 63;
    int l = lt0 + ll;
    float f0 = 0.f, f1 = 0.f;
    if (l < L) {
      f0 = qb[(size_t)(2 * d2) * L + l] * ATT_SCALE;
      f1 = qb[(size_t)(2 * d2 + 1) * L + l] * ATT_SCALE;
    }
    unsigned pk = (unsigned)(unsigned short)f2bf(f0) | ((unsigned)(unsigned short)f2bf(f1) << 16);
    *(unsigned*)&Qs[ll * 72 + 2 * d2] = pk;
  }

  floatx4 of[3];
  #pragma unroll
  for (int i = 0; i < 3; i++) of[i] = floatx4{0.f, 0.f, 0.f, 0.f};
  float rs[4] = {0.f, 0.f, 0.f, 0.f};
  __syncthreads();

  for (int m0 = 0; m0 < L; m0 += 64) {
    // ---- stage K [mm][d] ----
    for (int i = t; i < 64 * 24; i += 256) {
      int d2 = i >> 6, mm = i & 63;
      int m = m0 + mm;
      float f0 = 0.f, f1 = 0.f;
      if (m < L) {
        f0 = kb[(size_t)(2 * d2) * L + m];
        f1 = kb[(size_t)(2 * d2 + 1) * L + m];
      }
      unsigned pk = (unsigned)(unsigned short)f2bf(f0) | ((unsigned)(unsigned short)f2bf(f1) << 16);
      *(unsigned*)&Ks[mm * 72 + 2 * d2] = pk;
    }
    // ---- stage V pre-packed: value V[m0+o*8+j][d] -> Vf[((chunk*3+dsub)*64 + ((o&3)<<4 | (d&15)))*8 + j]
    for (int a = t; a < 384; a += 256) {
      int d = (a & 7) | ((a >> 6) << 3);   // 0..47 (d%8 spans lanes -> spread b128 banks)
      int o = (a >> 3) & 7;                // m-octet 0..7
      int mb = m0 + o * 8;
      const float* src = vb + (size_t)d * L + mb;
      bf16x8 v8;
      #pragma unroll
      for (int j = 0; j < 8; j++) v8[j] = (mb + j < L) ? f2bf(src[j]) : (short)0;
      int chunk = o >> 2, dsub = d >> 4;
      int lanep = ((o & 3) << 4) | (d & 15);
      *(bf16x8*)&Vf[((chunk * 3 + dsub) * 64 + lanep) * 8] = v8;
    }
    __syncthreads();

    // ---- S = Q K^T for this wave's 16-l strip ----
    bf16x8 aq0 = *(bf16x8*)&Qs[(w * 16 + col) * 72 + quad * 8];
    bf16x8 aq1 = *(bf16x8*)&Qs[(w * 16 + col) * 72 + 32 + quad * 8];
    floatx4 sf[4];
    #pragma unroll
    for (int ms = 0; ms < 4; ms++) {
      bf16x8 bk0 = *(bf16x8*)&Ks[(ms * 16 + col) * 72 + quad * 8];
      bf16x8 bk1 = *(bf16x8*)&Ks[(ms * 16 + col) * 72 + 32 + quad * 8];
      floatx4 acc = floatx4{0.f, 0.f, 0.f, 0.f};
      acc = __builtin_amdgcn_mfma_f32_16x16x32_bf16(aq0, bk0, acc, 0, 0, 0);
      acc = __builtin_amdgcn_mfma_f32_16x16x32_bf16(aq1, bk1, acc, 0, 0, 0);
      sf[ms] = acc;
    }
    // ---- P = exp(S) (masked), rowsums, write P to LDS [l][m] ----
    float rloc[4] = {0.f, 0.f, 0.f, 0.f};
    #pragma unroll
    for (int ms = 0; ms < 4; ms++) {
      int m = m0 + ms * 16 + col;
      bool ok = m < L;
      #pragma unroll
      for (int r = 0; r < 4; r++) {
        float e = ok ? __expf(sf[ms][r]) : 0.f;
        rloc[r] += e;
        Ps[(w * 16 + quad * 4 + r) * 72 + ms * 16 + col] = f2bf(e);
      }
    }
    #pragma unroll
    for (int r = 0; r < 4; r++) {
      float v = rloc[r];
      v += __shfl_xor(v, 1); v += __shfl_xor(v, 2);
      v += __shfl_xor(v, 4); v += __shfl_xor(v, 8);
      rs[r] += v;
    }
    __syncthreads();

    // ---- O += P V ----
    bf16x8 ap0 = *(bf16x8*)&Ps[(w * 16 + col) * 72 + quad * 8];
    bf16x8 ap1 = *(bf16x8*)&Ps[(w * 16 + col) * 72 + 32 + quad * 8];
    #pragma unroll
    for (int ds = 0; ds < 3; ds++) {
      bf16x8 bv0 = *(bf16x8*)&Vf[((0 * 3 + ds) * 64 + lane) * 8];
      bf16x8 bv1 = *(bf16x8*)&Vf[((1 * 3 + ds) * 64 + lane) * 8];
      of[ds] = __builtin_amdgcn_mfma_f32_16x16x32_bf16(ap0, bv0, of[ds], 0, 0, 0);
      of[ds] = __builtin_amdgcn_mfma_f32_16x16x32_bf16(ap1, bv1, of[ds], 0, 0, 0);
    }
    __syncthreads();
  }

  // ---- normalize, stage O to LDS [d][l] fp32 (overlay), coalesced store ----
  #pragma unroll
  for (int r = 0; r < 4; r++) {
    float inv = 1.f / rs[r];
    #pragma unroll
    for (int ds = 0; ds < 3; ds++)
      Os[(ds * 16 + col) * 66 + w * 16 + quad * 4 + r] = of[ds][r] * inv;
  }
  __syncthreads();
  for (int i = t; i < 48 * 64; i += 256) {
    int d = i >> 6, ll = i & 63;
    int l = lt0 + ll;
    if (l < L) out[((size_t)b * C2 + h * HD + d) * L + l] = Os[d * 66 + ll];
  }
}

// ---------------- scatter attention out (weird reshape) -> xt2 upper half ----------------
__global__ void k_fill_xt2(const float* __restrict__ ao, float* __restrict__ xt2) {
  __shared__ float tile[32][33];
  int b = blockIdx.z;
  int l0 = blockIdx.x * 32, c0 = blockIdx.y * 32;
  int tx = threadIdx.x, ty = threadIdx.y;
  #pragma unroll
  for (int i = 0; i < 4; i++) {
    int l = l0 + ty + i * 8, c = c0 + tx;
    if (l < L) tile[ty + i * 8][tx] = ao[(size_t)b * ((size_t)L * C2) + (size_t)l * C2 + c];
  }
  __syncthreads();
  #pragma unroll
  for (int i = 0; i < 4; i++) {
    int c = c0 + ty + i * 8, l = l0 + tx;
    if (l < L) xt2[((size_t)b * C + C2 + c) * L + l] = tile[tx][ty + i * 8];
  }
}

// ---------------- projection dw3 + gelu -> t1, accumulate bn1 stats ----------------
__global__ __launch_bounds__(256) void k_dwproj(const float* __restrict__ xt2,
                                                const float* __restrict__ dww,
                                                const float* __restrict__ dwb,
                                                float* __restrict__ t1,
                                                float* __restrict__ sum, float* __restrict__ sq) {
  int c = blockIdx.x, b = blockIdx.y;
  const float* row = xt2 + ((size_t)b * C + c) * L;
  float w0 = dww[c * 3], w1 = dww[c * 3 + 1], w2 = dww[c * 3 + 2], bb = dwb[c];
  float* orow = t1 + ((size_t)b * C + c) * L;
  float s = 0.f, s2 = 0.f;
  for (int l = threadIdx.x; l < L; l += 256) {
    float xm1 = (l > 0) ? row[l - 1] : 0.f;
    float x0 = row[l];
    float xp1 = (l < L - 1) ? row[l + 1] : 0.f;
    float v = gelu_f(xm1 * w0 + x0 * w1 + xp1 * w2 + bb);
    orow[l] = v;
    s += v; s2 += v * v;
  }
  s = wave_sum(s); s2 = wave_sum(s2);
  __shared__ float r1[4], r2[4];
  int lane = threadIdx.x & 63, wid = threadIdx.x >> 6;
  if (lane == 0) { r1[wid] = s; r2[wid] = s2; }
  __syncthreads();
  if (threadIdx.x == 0) {
    atomicAdd(&sum[c], r1[0] + r1[1] + r1[2] + r1[3]);
    atomicAdd(&sq[c], r2[0] + r2[1] + r2[2] + r2[3]);
  }
}

// ---------------- generic per-(b,c)-row stats ----------------
__global__ __launch_bounds__(256) void k_rowstats(const float* __restrict__ Y, int Cn,
                                                  float* __restrict__ sum, float* __restrict__ sq) {
  int c = blockIdx.x, b = blockIdx.y;
  const float* row = Y + ((size_t)b * Cn + c) * L;
  float s = 0.f, s2 = 0.f;
  for (int l = threadIdx.x; l < L; l += 256) { float v = row[l]; s += v; s2 += v * v; }
  s = wave_sum(s); s2 = wave_sum(s2);
  __shared__ float r1[4], r2[4];
  int lane = threadIdx.x & 63, wid = threadIdx.x >> 6;
  if (lane == 0) { r1[wid] = s; r2[wid] = s2; }
  __syncthreads();
  if (threadIdx.x == 0) {
    atomicAdd(&sum[c], r1[0] + r1[1] + r1[2] + r1[3]);
    atomicAdd(&sq[c], r2[0] + r2[1] + r2[2] + r2[3]);
  }
}

// ---------------- finalize bn1 (s1,d1) and folded c1 bias cb1 ----------------
__global__ void k_fin1(const float* __restrict__ sum, const float* __restrict__ sq,
                       const float* __restrict__ g, const float* __restrict__ be,
                       const float* __restrict__ c1w, const float* __restrict__ c1b,
                       float* __restrict__ s1, float* __restrict__ d1, float* __restrict__ cb1) {
  int t = threadIdx.x;
  if (t < C) {
    float m = sum[t] * INV_N;
    float v = sq[t] * INV_N - m * m;
    float r = rsqrtf(v + BN_EPS);
    float sc = g[t] * r;
    s1[t] = sc;
    d1[t] = be[t] - m * sc;
  }
  __syncthreads();
  if (t < 96) {
    float a = c1b[t];
    const float* wr = c1w + (size_t)t * C;
    for (int c = 0; c < C; c++) a += d1[c] * wr[c];
    cb1[t] = a;
  }
}

// ---------------- finalize bn2 (s2,d2) and folded c2 bias cb2 ----------------
__global__ void k_fin2(const float* __restrict__ sum, const float* __restrict__ sq,
                       const float* __restrict__ g, const float* __restrict__ be,
                       const float* __restrict__ c2w, const float* __restrict__ c2b,
                       float* __restrict__ s2, float* __restrict__ d2, float* __restrict__ cb2) {
  int t = threadIdx.x;
  if (t < 96) {
    float m = sum[t] * INV_N;
    float v = sq[t] * INV_N - m * m;
    float r = rsqrtf(v + BN_EPS);
    float sc = g[t] * r;
    s2[t] = sc;
    d2[t] = be[t] - m * sc;
  }
  __syncthreads();
  if (t < C) {
    float a = c2b[t];
    const float* wr = c2w + (size_t)t * 96;
    for (int i = 0; i < 96; i++) a += d2[i] * wr[i];
    cb2[t] = a;
  }
}

// ---------------- finalize bn3 ----------------
__global__ void k_fin3(const float* __restrict__ sum, const float* __restrict__ sq,
                       const float* __restrict__ g, const float* __restrict__ be,
                       float* __restrict__ s3, float* __restrict__ d3) {
  int t = threadIdx.x;
  if (t < C) {
    float m = sum[t] * INV_N;
    float v = sq[t] * INV_N - m * m;
    float r = rsqrtf(v + BN_EPS);
    float sc = g[t] * r;
    s3[t] = sc;
    d3[t] = be[t] - m * sc;
  }
}

// ---------------- final: out[b,l,c] = bn3(y3)[b,c,l] + xt2[b,c,l] ----------------
__global__ void k_final(const float* __restrict__ y3, const float* __restrict__ xt2,
                        const float* __restrict__ s3, const float* __restrict__ d3,
                        float* __restrict__ out) {
  __shared__ float tile[32][33];
  int b = blockIdx.z;
  int l0 = blockIdx.x * 32, c0 = blockIdx.y * 32;
  int tx = threadIdx.x, ty = threadIdx.y;
  #pragma unroll
  for (int i = 0; i < 4; i++) {
    int c = c0 + ty + i * 8, l = l0 + tx;
    if (l < L) {
      size_t idx = ((size_t)b * C + c) * L + l;
      tile[ty + i * 8][tx] = y3[idx] * s3[c] + d3[c] + xt2[idx];
    }
  }
  __syncthreads();
  #pragma unroll
  for (int i = 0; i < 4; i++) {
    int l = l0 + ty + i * 8, c = c0 + tx;
    if (l < L) out[((size_t)b * L + l) * C + c] = tile[tx][ty + i * 8];
  }
}

extern "C" void kernel_launch(void* const* d_in, const int* in_sizes, int n_in,
                              void* d_out, int out_size, void* d_ws, size_t ws_size,
                              hipStream_t stream) {
  const float* x    = (const float*)d_in[0];
  const float* dcw  = (const float*)d_in[1];
  const float* dcb  = (const float*)d_in[2];
  const float* p1w  = (const float*)d_in[3];
  const float* p1b  = (const float*)d_in[4];
  const float* p2w  = (const float*)d_in[5];
  const float* p2b  = (const float*)d_in[6];
  const float* qw   = (const float*)d_in[7];
  const float* qb   = (const float*)d_in[8];
  const float* kvw  = (const float*)d_in[9];
  const float* kvb  = (const float*)d_in[10];
  const float* lcw  = (const float*)d_in[11];
  const float* lcb  = (const float*)d_in[12];
  const float* dww  = (const float*)d_in[13];
  const float* dwb  = (const float*)d_in[14];
  const float* bn1g = (const float*)d_in[15];
  const float* bn1b = (const float*)d_in[16];
  const float* c1w  = (const float*)d_in[17];
  const float* c1b  = (const float*)d_in[18];
  const float* bn2g = (const float*)d_in[19];
  const float* bn2b = (const float*)d_in[20];
  const float* c2w  = (const float*)d_in[21];
  const float* c2b  = (const float*)d_in[22];
  const float* bn3g = (const float*)d_in[23];
  const float* bn3b = (const float*)d_in[24];
  float* out = (float*)d_out;
  float* ws  = (float*)d_ws;

  float* xt      = ws + OFF_XT;     // later reused as t1
  float* xt2     = ws + OFF_XT2;
  float* kvbuf   = ws + OFF_KV;     // later reused as y3
  float* kvin    = ws + OFF_KVIN;   // later reused as attnout
  float* qbuf    = ws + OFF_Q;      // later reused as h2
  float* sm      = ws + OFF_SM;

  float* pooled = sm + SM_POOLED;
  float* xm     = sm + SM_XM;
  float* h1     = sm + SM_H1;
  float* wdyn   = sm + SM_WDYN;
  float* bdyn   = sm + SM_BDYN;
  float* sum1 = sm + SM_SUM1; float* sq1 = sm + SM_SQ1;
  float* s1 = sm + SM_S1; float* d1 = sm + SM_D1; float* cb1 = sm + SM_CB1;
  float* sum2 = sm + SM_SUM2; float* sq2 = sm + SM_SQ2;
  float* s2 = sm + SM_S2; float* d2 = sm + SM_D2; float* cb2 = sm + SM_CB2;
  float* sum3 = sm + SM_SUM3; float* sq3 = sm + SM_SQ3;
  float* s3 = sm + SM_S3; float* d3 = sm + SM_D3;

  // zero the bn-stat accumulators (covers sum1..sq3 span; s/d/cb overwritten anyway)
  hipMemsetAsync((void*)(sm + SM_SUM1), 0, (SM_S3 - SM_SUM1) * sizeof(float), stream);

  dim3 tb32(32, 8);
  // 1. transpose input
  k_transpose_in<<<dim3(32, 24, B), tb32, 0, stream>>>(x, xt);
  // 2. pooled / mean
  k_pool<<<dim3(C2, B), 256, 0, stream>>>(xt, pooled, xm);
  // 3. tiny MLP
  k_mlp1<<<dim3(4, B), 128, 0, stream>>>(pooled, xm, p1w, p1b, h1);
  k_mix2<<<dim3(4, B), 384, 0, stream>>>(h1, p2w, p2b, dcw, dcb, wdyn, bdyn);
  // 4. dynamic conv -> xt2 lower
  k_dynconv<<<dim3(C2, B), 256, 0, stream>>>(xt, wdyn, bdyn, xt2);
  // 5. kv_in
  k_kvin<<<dim3(C2, B), 256, 0, stream>>>(xt, lcw, lcb, kvin);
  // 6. q = qw @ x2t  (O=384, K=384)
  k_gemm<<<dim3(16, 6, B), 256, 0, stream>>>(qw, xt + (size_t)C2 * L, qbuf, nullptr, qb,
                                             C2, C2, (size_t)C * L, (size_t)C2 * L, 0);
  // 7. kv = kvw @ kv_in (O=768, K=384)
  k_gemm<<<dim3(16, 12, B), 256, 0, stream>>>(kvw, kvin, kvbuf, nullptr, kvb,
                                              C, C2, (size_t)C2 * L, (size_t)C * L, 0);
  // 8. MFMA flash attention -> attnout (reuses kvin buffer)
  k_attn_mfma<<<dim3(16, H, B), 256, 0, stream>>>(qbuf, kvbuf, kvin);
  // 9. scatter (bug-compatible reshape) -> xt2 upper
  k_fill_xt2<<<dim3(32, 12, B), tb32, 0, stream>>>(kvin, xt2);
  // 10. projection dw3+gelu -> t1 (reuses xt), bn1 stats
  k_dwproj<<<dim3(C, B), 256, 0, stream>>>(xt2, dww, dwb, xt, sum1, sq1);
  k_fin1<<<1, 768, 0, stream>>>(sum1, sq1, bn1g, bn1b, c1w, c1b, s1, d1, cb1);
  // 11. c1 GEMM (bn1 folded) + gelu -> h2 (reuses qbuf), O=96, K=768
  k_gemm<<<dim3(16, 2, B), 256, 0, stream>>>(c1w, xt, qbuf, s1, cb1,
                                             96, C, (size_t)C * L, (size_t)96 * L, 1);
  k_rowstats<<<dim3(96, B), 256, 0, stream>>>(qbuf, 96, sum2, sq2);
  k_fin2<<<1, 768, 0, stream>>>(sum2, sq2, bn2g, bn2b, c2w, c2b, s2, d2, cb2);
  // 12. c2 GEMM (bn2 folded) -> y3 (reuses kvbuf), O=768, K=96
  k_gemm<<<dim3(16, 12, B), 256, 0, stream>>>(c2w, qbuf, kvbuf, s2, cb2,
                                              C, 96, (size_t)96 * L, (size_t)C * L, 0);
  k_rowstats<<<dim3(C, B), 256, 0, stream>>>(kvbuf, C, sum3, sq3);
  k_fin3<<<1, 768, 0, stream>>>(sum3, sq3, bn3g, bn3b, s3, d3);
  // 13. final bn3 + residual + transpose back
  k_final<<<dim3(32, 24, B), tb32, 0, stream>>>(kvbuf, xt2, s3, d3, out);
}

// Round 6
// 634.289 us; speedup vs baseline: 3.4059x; 1.0451x over previous
//
#include <hip/hip_runtime.h>
#include <cstddef>

constexpr int B = 8, L = 999, C = 768, C2 = 384, H = 8, HD = 48;
constexpr float ATT_SCALE = 0.14433756729740644f;   // 48^-0.5
constexpr float BN_EPS = 1e-5f;
constexpr float INV_N = 1.0f / (8.0f * 999.0f);     // 1/(B*L)

constexpr size_t SZ_XT   = (size_t)B * C * L;       // 6,137,856
constexpr size_t SZ_HALF = (size_t)B * C2 * L;      // 3,068,928
constexpr size_t OFF_XT   = 0;                      // xt, later t1
constexpr size_t OFF_XT2  = SZ_XT;                  // xt2 (concat branch outputs, transposed)
constexpr size_t OFF_KV   = 2 * SZ_XT;              // kv (bf16), later y3 (fp32)
constexpr size_t OFF_KVIN = 3 * SZ_XT;              // kvin, later attnout
constexpr size_t OFF_Q    = 3 * SZ_XT + SZ_HALF;    // q (bf16), later h2 (fp32)
constexpr size_t OFF_SM   = 3 * SZ_XT + 2 * SZ_HALF;

// small-region offsets (floats, relative to OFF_SM)
constexpr size_t SM_POOLED = 0;       // B*C2*3
constexpr size_t SM_XM     = 9216;    // B*C2
constexpr size_t SM_H1     = 12288;   // B*4*96
constexpr size_t SM_WDYN   = 15360;   // B*C2*3
constexpr size_t SM_BDYN   = 24576;   // B*C2
constexpr size_t SM_SUM1   = 27648;   // 768
constexpr size_t SM_SQ1    = 28416;
constexpr size_t SM_S1     = 29184;   // bn1 scale g/sigma
constexpr size_t SM_M1     = 29952;   // bn1 mean
constexpr size_t SM_CB1    = 30720;   // 96: c1b + c1w . bn1b
constexpr size_t SM_SUM2   = 30816;   // 96
constexpr size_t SM_SQ2    = 30912;
constexpr size_t SM_S2     = 31008;
constexpr size_t SM_M2     = 31104;
constexpr size_t SM_CB2    = 31200;   // 768
constexpr size_t SM_SUM3   = 31968;
constexpr size_t SM_SQ3    = 32736;
constexpr size_t SM_S3     = 33504;
constexpr size_t SM_D3     = 34272;
constexpr size_t SM_END    = 35040;

typedef __attribute__((ext_vector_type(8))) short bf16x8;
typedef __attribute__((ext_vector_type(4))) float floatx4;

__device__ __forceinline__ float gelu_f(float x) {
  return 0.5f * x * (1.0f + erff(x * 0.70710678118654752f));
}

__device__ __forceinline__ float wave_sum(float v) {
  #pragma unroll
  for (int off = 32; off > 0; off >>= 1) v += __shfl_down(v, off, 64);
  return v;
}

__device__ __forceinline__ short f2bf(float f) {
  union { float f; unsigned u; } x; x.f = f;
  unsigned r = x.u + 0x7FFFu + ((x.u >> 16) & 1u);
  return (short)(r >> 16);
}

// ---------------- transpose x (B,L,C) -> xt (B,C,L) ----------------
__global__ void k_transpose_in(const float* __restrict__ x, float* __restrict__ xt) {
  __shared__ float tile[32][33];
  int b = blockIdx.z;
  int l0 = blockIdx.x * 32, c0 = blockIdx.y * 32;
  int tx = threadIdx.x, ty = threadIdx.y;
  #pragma unroll
  for (int i = 0; i < 4; i++) {
    int l = l0 + ty + i * 8, c = c0 + tx;
    if (l < L) tile[ty + i * 8][tx] = x[((size_t)b * L + l) * C + c];
  }
  __syncthreads();
  #pragma unroll
  for (int i = 0; i < 4; i++) {
    int c = c0 + ty + i * 8, l = l0 + tx;
    if (l < L) xt[((size_t)b * C + c) * L + l] = tile[tx][ty + i * 8];
  }
}

// ---------------- pooled chunk means + row mean (dyn-conv branch) ----------------
__global__ __launch_bounds__(256) void k_pool(const float* __restrict__ xt,
                                              float* __restrict__ pooled,
                                              float* __restrict__ xm) {
  int c = blockIdx.x, b = blockIdx.y;       // c < 384
  const float* row = xt + ((size_t)b * C + c) * L;
  float s0 = 0.f, s1 = 0.f, s2 = 0.f;
  for (int l = threadIdx.x; l < L; l += 256) {
    float v = row[l];
    int ch = l / 333;
    if (ch == 0) s0 += v; else if (ch == 1) s1 += v; else s2 += v;
  }
  s0 = wave_sum(s0); s1 = wave_sum(s1); s2 = wave_sum(s2);
  __shared__ float r[3][4];
  int lane = threadIdx.x & 63, wid = threadIdx.x >> 6;
  if (lane == 0) { r[0][wid] = s0; r[1][wid] = s1; r[2][wid] = s2; }
  __syncthreads();
  if (threadIdx.x == 0) {
    float t0 = r[0][0] + r[0][1] + r[0][2] + r[0][3];
    float t1 = r[1][0] + r[1][1] + r[1][2] + r[1][3];
    float t2 = r[2][0] + r[2][1] + r[2][2] + r[2][3];
    size_t pb = (size_t)(b * C2 + c) * 3;
    pooled[pb + 0] = t0 / 333.f;
    pooled[pb + 1] = t1 / 333.f;
    pooled[pb + 2] = t2 / 333.f;
    xm[b * C2 + c] = (t0 + t1 + t2) / 999.f;
  }
}

// ---------------- tiny MLP layer 1: gelu(p1w @ in + p1b) ----------------
__global__ void k_mlp1(const float* __restrict__ pooled, const float* __restrict__ xm,
                       const float* __restrict__ p1w, const float* __restrict__ p1b,
                       float* __restrict__ h1) {
  int j = blockIdx.x, b = blockIdx.y;       // j in 0..3 (0..2 pooled cols, 3 = mean)
  __shared__ float vin[C2];
  for (int c = threadIdx.x; c < C2; c += 128)
    vin[c] = (j < 3) ? pooled[(size_t)(b * C2 + c) * 3 + j] : xm[b * C2 + c];
  __syncthreads();
  int o = threadIdx.x;
  if (o < 96) {
    float acc = p1b[o];
    const float* wr = p1w + (size_t)o * C2;
    for (int c = 0; c < C2; c++) acc += vin[c] * wr[c];
    h1[(b * 4 + j) * 96 + o] = gelu_f(acc);
  }
}

// ---------------- MLP layer 2 + softmax over G + weight/bias mix ----------------
__global__ void k_mix2(const float* __restrict__ h1,
                       const float* __restrict__ p2w, const float* __restrict__ p2b,
                       const float* __restrict__ dcw, const float* __restrict__ dcb,
                       float* __restrict__ wdyn, float* __restrict__ bdyn) {
  int j = blockIdx.x, b = blockIdx.y;
  __shared__ float hv[96];
  for (int i = threadIdx.x; i < 96; i += 384) hv[i] = h1[(b * 4 + j) * 96 + i];
  __syncthreads();
  int c = threadIdx.x;                       // < 384
  float a0 = p2b[c], a1 = p2b[C2 + c];
  const float* w0r = p2w + (size_t)c * 96;
  const float* w1r = p2w + (size_t)(C2 + c) * 96;
  for (int i = 0; i < 96; i++) { float h = hv[i]; a0 += h * w0r[i]; a1 += h * w1r[i]; }
  float m = fmaxf(a0, a1);
  float e0 = __expf(a0 - m), e1 = __expf(a1 - m);
  float inv = 1.f / (e0 + e1);
  float p0 = e0 * inv, p1 = e1 * inv;
  if (j < 3)
    wdyn[(size_t)(b * C2 + c) * 3 + j] = p0 * dcw[(size_t)c * 3 + j] + p1 * dcw[(size_t)(C2 + c) * 3 + j];
  else
    bdyn[b * C2 + c] = p0 * dcb[c] + p1 * dcb[C2 + c];
}

// ---------------- fused: dynamic depthwise conv (lower half) + kv_in (upper half) ----------------
__global__ __launch_bounds__(256) void k_dwpair(const float* __restrict__ xt,
                                                const float* __restrict__ wdyn,
                                                const float* __restrict__ bdyn,
                                                const float* __restrict__ lcw,
                                                const float* __restrict__ lcb,
                                                float* __restrict__ xt2,
                                                float* __restrict__ kvin) {
  int c = blockIdx.x, b = blockIdx.y;
  const float* rowA = xt + ((size_t)b * C + c) * L;
  size_t wb = (size_t)(b * C2 + c) * 3;
  float a0 = wdyn[wb], a1 = wdyn[wb + 1], a2 = wdyn[wb + 2], ab = bdyn[b * C2 + c];
  float* oA = xt2 + ((size_t)b * C + c) * L;
  const float* rowB = xt + ((size_t)b * C + C2 + c) * L;
  float w0 = lcw[c * 3], w1 = lcw[c * 3 + 1] + 1.0f, w2 = lcw[c * 3 + 2], bb = lcb[c];
  float* oB = kvin + ((size_t)b * C2 + c) * L;
  for (int l = threadIdx.x; l < L; l += 256) {
    {
      float xm1 = (l > 0) ? rowA[l - 1] : 0.f;
      float x0 = rowA[l];
      float xp1 = (l < L - 1) ? rowA[l + 1] : 0.f;
      oA[l] = xm1 * a0 + x0 * a1 + xp1 * a2 + ab;
    }
    {
      float xm1 = (l > 0) ? rowB[l - 1] : 0.f;
      float x0 = rowB[l];
      float xp1 = (l < L - 1) ? rowB[l + 1] : 0.f;
      oB[l] = xm1 * w0 + x0 * w1 + xp1 * w2 + bb;
    }
  }
}

// ---------------- MFMA GEMM: Y[b,o,l] = act(sum_k ((X[b,k,l]-mu[k])s[k])W[o,k] + bias[o])*outmul ----
// flags: 1 = gelu, 2 = bf16 output. 64o x 64l per block, K-tiles of 64, bf16 MFMA.
// shift/scale center+normalize the staged input so bf16 error stays relative (no cancellation).
__global__ __launch_bounds__(256) void k_gemm_mfma(const float* __restrict__ W,
                                                   const float* __restrict__ X,
                                                   void* __restrict__ Yv,
                                                   const float* __restrict__ shift,
                                                   const float* __restrict__ scale,
                                                   const float* __restrict__ bias,
                                                   int O, int Kd, size_t xbs, size_t ybs,
                                                   int flags, float outmul) {
  __shared__ __align__(16) short Wt[64 * 72];
  __shared__ __align__(16) short Xt[64 * 72];
  int b = blockIdx.z;
  int o0 = blockIdx.y * 64, l0 = blockIdx.x * 64;
  int t = threadIdx.x, w = t >> 6, lane = t & 63;
  int col = lane & 15, quad = lane >> 4;
  const float* Xb = X + (size_t)b * xbs;
  floatx4 acc[4];
  #pragma unroll
  for (int i = 0; i < 4; i++) acc[i] = floatx4{0.f, 0.f, 0.f, 0.f};

  for (int k0 = 0; k0 < Kd; k0 += 64) {
    // W tile -> Wt[o][k], bf16, zero-padded
    {
      int o = t >> 2, ks = (t & 3) * 16;
      int oo = o0 + o;
      short tmp[16];
      #pragma unroll
      for (int j = 0; j < 16; j++) {
        int k = k0 + ks + j;
        float v = (oo < O && k < Kd) ? W[(size_t)oo * Kd + k] : 0.f;
        tmp[j] = f2bf(v);
      }
      *(bf16x8*)&Wt[o * 72 + ks] = *(bf16x8*)&tmp[0];
      *(bf16x8*)&Wt[o * 72 + ks + 8] = *(bf16x8*)&tmp[8];
    }
    // X tile transposed -> Xt[l][k], bf16, shift/scale folded
    #pragma unroll
    for (int rep = 0; rep < 8; rep++) {
      int u = t + rep * 256;
      int kk2 = u >> 6, ll = u & 63;
      int k = k0 + 2 * kk2;
      int l = l0 + ll;
      float x0 = 0.f, x1 = 0.f;
      if (l < L && k < Kd) {
        x0 = Xb[(size_t)k * L + l];
        if (shift) x0 -= shift[k];
        if (scale) x0 *= scale[k];
        if (k + 1 < Kd) {
          x1 = Xb[(size_t)(k + 1) * L + l];
          if (shift) x1 -= shift[k + 1];
          if (scale) x1 *= scale[k + 1];
        }
      }
      unsigned pk = (unsigned)(unsigned short)f2bf(x0) | ((unsigned)(unsigned short)f2bf(x1) << 16);
      *(unsigned*)&Xt[ll * 72 + 2 * kk2] = pk;
    }
    __syncthreads();
    #pragma unroll
    for (int half = 0; half < 2; half++) {
      bf16x8 aw = *(bf16x8*)&Wt[(w * 16 + col) * 72 + half * 32 + quad * 8];
      #pragma unroll
      for (int nt = 0; nt < 4; nt++) {
        bf16x8 bx = *(bf16x8*)&Xt[(nt * 16 + col) * 72 + half * 32 + quad * 8];
        acc[nt] = __builtin_amdgcn_mfma_f32_16x16x32_bf16(aw, bx, acc[nt], 0, 0, 0);
      }
    }
    __syncthreads();
  }
  // epilogue: D row = o (quad*4+r within wave strip), col = l
  int o_base = o0 + w * 16 + quad * 4;
  #pragma unroll
  for (int r = 0; r < 4; r++) {
    int o = o_base + r;
    if (o >= O) continue;
    float bo = bias ? bias[o] : 0.f;
    #pragma unroll
    for (int nt = 0; nt < 4; nt++) {
      int l = l0 + nt * 16 + col;
      if (l >= L) continue;
      float v = acc[nt][r] + bo;
      if (flags & 1) v = gelu_f(v);
      v *= outmul;
      if (flags & 2) ((short*)Yv)[(size_t)b * ybs + (size_t)o * L + l] = f2bf(v);
      else           ((float*)Yv)[(size_t)b * ybs + (size_t)o * L + l] = v;
    }
  }
}

// ---------------- MFMA flash attention: 64 q-rows per block, one (b,h) ----------------
// q, kv are bf16; q pre-scaled by ATT_SCALE in the q GEMM.
__global__ __launch_bounds__(256) void k_attn_mfma(const short* __restrict__ q,
                                                   const short* __restrict__ kv,
                                                   float* __restrict__ out) {
  __shared__ __align__(16) char smem[9216 * 3 + 6144];
  short* Qs = (short*)smem;              // [64 l][72] bf16
  short* Ks = (short*)(smem + 9216);     // [64 m][72] bf16
  short* Ps = (short*)(smem + 18432);    // [64 l][72] bf16
  short* Vf = (short*)(smem + 27648);    // [chunk2][dsub3][lane64][8] bf16
  float* Os = (float*)smem;              // epilogue overlay: [48 d][66 l] fp32

  int lt0 = blockIdx.x * 64;
  int h = blockIdx.y, b = blockIdx.z;
  int t = threadIdx.x;
  int w = t >> 6, lane = t & 63;
  int col = lane & 15, quad = lane >> 4;
  const short* qb = q  + ((size_t)b * C2 + h * HD) * L;
  const short* kb = kv + ((size_t)b * C  + h * HD) * L;
  const short* vb = kv + ((size_t)b * C + C2 + h * HD) * L;

  for (int i = t; i < 64 * 16; i += 256) {
    int row = i >> 4, d = 48 + (i & 15);
    Qs[row * 72 + d] = 0;
    Ks[row * 72 + d] = 0;
  }
  for (int i = t; i < 64 * 24; i += 256) {
    int d2 = i >> 6, ll = i & 63;
    int l = lt0 + ll;
    unsigned pk = 0;
    if (l < L) {
      unsigned s0_ = (unsigned short)qb[(size_t)(2 * d2) * L + l];
      unsigned s1_ = (unsigned short)qb[(size_t)(2 * d2 + 1) * L + l];
      pk = s0_ | (s1_ << 16);
    }
    *(unsigned*)&Qs[ll * 72 + 2 * d2] = pk;
  }

  floatx4 of[3];
  #pragma unroll
  for (int i = 0; i < 3; i++) of[i] = floatx4{0.f, 0.f, 0.f, 0.f};
  float rs[4] = {0.f, 0.f, 0.f, 0.f};
  __syncthreads();

  for (int m0 = 0; m0 < L; m0 += 64) {
    for (int i = t; i < 64 * 24; i += 256) {
      int d2 = i >> 6, mm = i & 63;
      int m = m0 + mm;
      unsigned pk = 0;
      if (m < L) {
        unsigned s0_ = (unsigned short)kb[(size_t)(2 * d2) * L + m];
        unsigned s1_ = (unsigned short)kb[(size_t)(2 * d2 + 1) * L + m];
        pk = s0_ | (s1_ << 16);
      }
      *(unsigned*)&Ks[mm * 72 + 2 * d2] = pk;
    }
    for (int a = t; a < 384; a += 256) {
      int d = (a & 7) | ((a >> 6) << 3);   // 0..47
      int o = (a >> 3) & 7;                // m-octet 0..7
      int mb = m0 + o * 8;
      const short* src = vb + (size_t)d * L + mb;
      short v8a[8];
      #pragma unroll
      for (int j = 0; j < 8; j++) v8a[j] = (mb + j < L) ? src[j] : (short)0;
      int chunk = o >> 2, dsub = d >> 4;
      int lanep = ((o & 3) << 4) | (d & 15);
      *(bf16x8*)&Vf[((chunk * 3 + dsub) * 64 + lanep) * 8] = *(bf16x8*)&v8a[0];
    }
    __syncthreads();

    bf16x8 aq0 = *(bf16x8*)&Qs[(w * 16 + col) * 72 + quad * 8];
    bf16x8 aq1 = *(bf16x8*)&Qs[(w * 16 + col) * 72 + 32 + quad * 8];
    floatx4 sf[4];
    #pragma unroll
    for (int ms = 0; ms < 4; ms++) {
      bf16x8 bk0 = *(bf16x8*)&Ks[(ms * 16 + col) * 72 + quad * 8];
      bf16x8 bk1 = *(bf16x8*)&Ks[(ms * 16 + col) * 72 + 32 + quad * 8];
      floatx4 acc = floatx4{0.f, 0.f, 0.f, 0.f};
      acc = __builtin_amdgcn_mfma_f32_16x16x32_bf16(aq0, bk0, acc, 0, 0, 0);
      acc = __builtin_amdgcn_mfma_f32_16x16x32_bf16(aq1, bk1, acc, 0, 0, 0);
      sf[ms] = acc;
    }
    float rloc[4] = {0.f, 0.f, 0.f, 0.f};
    #pragma unroll
    for (int ms = 0; ms < 4; ms++) {
      int m = m0 + ms * 16 + col;
      bool ok = m < L;
      #pragma unroll
      for (int r = 0; r < 4; r++) {
        float e = ok ? __expf(sf[ms][r]) : 0.f;
        rloc[r] += e;
        Ps[(w * 16 + quad * 4 + r) * 72 + ms * 16 + col] = f2bf(e);
      }
    }
    #pragma unroll
    for (int r = 0; r < 4; r++) {
      float v = rloc[r];
      v += __shfl_xor(v, 1); v += __shfl_xor(v, 2);
      v += __shfl_xor(v, 4); v += __shfl_xor(v, 8);
      rs[r] += v;
    }
    __syncthreads();

    bf16x8 ap0 = *(bf16x8*)&Ps[(w * 16 + col) * 72 + quad * 8];
    bf16x8 ap1 = *(bf16x8*)&Ps[(w * 16 + col) * 72 + 32 + quad * 8];
    #pragma unroll
    for (int ds = 0; ds < 3; ds++) {
      bf16x8 bv0 = *(bf16x8*)&Vf[((0 * 3 + ds) * 64 + lane) * 8];
      bf16x8 bv1 = *(bf16x8*)&Vf[((1 * 3 + ds) * 64 + lane) * 8];
      of[ds] = __builtin_amdgcn_mfma_f32_16x16x32_bf16(ap0, bv0, of[ds], 0, 0, 0);
      of[ds] = __builtin_amdgcn_mfma_f32_16x16x32_bf16(ap1, bv1, of[ds], 0, 0, 0);
    }
    __syncthreads();
  }

  #pragma unroll
  for (int r = 0; r < 4; r++) {
    float inv = 1.f / rs[r];
    #pragma unroll
    for (int ds = 0; ds < 3; ds++)
      Os[(ds * 16 + col) * 66 + w * 16 + quad * 4 + r] = of[ds][r] * inv;
  }
  __syncthreads();
  for (int i = t; i < 48 * 64; i += 256) {
    int d = i >> 6, ll = i & 63;
    int l = lt0 + ll;
    if (l < L) out[((size_t)b * C2 + h * HD + d) * L + l] = Os[d * 66 + ll];
  }
}

// ---------------- scatter attention out (weird reshape) -> xt2 upper half ----------------
__global__ void k_fill_xt2(const float* __restrict__ ao, float* __restrict__ xt2) {
  __shared__ float tile[32][33];
  int b = blockIdx.z;
  int l0 = blockIdx.x * 32, c0 = blockIdx.y * 32;
  int tx = threadIdx.x, ty = threadIdx.y;
  #pragma unroll
  for (int i = 0; i < 4; i++) {
    int l = l0 + ty + i * 8, c = c0 + tx;
    if (l < L) tile[ty + i * 8][tx] = ao[(size_t)b * ((size_t)L * C2) + (size_t)l * C2 + c];
  }
  __syncthreads();
  #pragma unroll
  for (int i = 0; i < 4; i++) {
    int c = c0 + ty + i * 8, l = l0 + tx;
    if (l < L) xt2[((size_t)b * C + C2 + c) * L + l] = tile[tx][ty + i * 8];
  }
}

// ---------------- projection dw3 + gelu -> t1, accumulate bn1 stats ----------------
__global__ __launch_bounds__(256) void k_dwproj(const float* __restrict__ xt2,
                                                const float* __restrict__ dww,
                                                const float* __restrict__ dwb,
                                                float* __restrict__ t1,
                                                float* __restrict__ sum, float* __restrict__ sq) {
  int c = blockIdx.x, b = blockIdx.y;
  const float* row = xt2 + ((size_t)b * C + c) * L;
  float w0 = dww[c * 3], w1 = dww[c * 3 + 1], w2 = dww[c * 3 + 2], bb = dwb[c];
  float* orow = t1 + ((size_t)b * C + c) * L;
  float s = 0.f, s2 = 0.f;
  for (int l = threadIdx.x; l < L; l += 256) {
    float xm1 = (l > 0) ? row[l - 1] : 0.f;
    float x0 = row[l];
    float xp1 = (l < L - 1) ? row[l + 1] : 0.f;
    float v = gelu_f(xm1 * w0 + x0 * w1 + xp1 * w2 + bb);
    orow[l] = v;
    s += v; s2 += v * v;
  }
  s = wave_sum(s); s2 = wave_sum(s2);
  __shared__ float r1[4], r2[4];
  int lane = threadIdx.x & 63, wid = threadIdx.x >> 6;
  if (lane == 0) { r1[wid] = s; r2[wid] = s2; }
  __syncthreads();
  if (threadIdx.x == 0) {
    atomicAdd(&sum[c], r1[0] + r1[1] + r1[2] + r1[3]);
    atomicAdd(&sq[c], r2[0] + r2[1] + r2[2] + r2[3]);
  }
}

// ---------------- generic per-(b,c)-row stats ----------------
__global__ __launch_bounds__(256) void k_rowstats(const float* __restrict__ Y, int Cn,
                                                  float* __restrict__ sum, float* __restrict__ sq) {
  int c = blockIdx.x, b = blockIdx.y;
  const float* row = Y + ((size_t)b * Cn + c) * L;
  float s = 0.f, s2 = 0.f;
  for (int l = threadIdx.x; l < L; l += 256) { float v = row[l]; s += v; s2 += v * v; }
  s = wave_sum(s); s2 = wave_sum(s2);
  __shared__ float r1[4], r2[4];
  int lane = threadIdx.x & 63, wid = threadIdx.x >> 6;
  if (lane == 0) { r1[wid] = s; r2[wid] = s2; }
  __syncthreads();
  if (threadIdx.x == 0) {
    atomicAdd(&sum[c], r1[0] + r1[1] + r1[2] + r1[3]);
    atomicAdd(&sq[c], r2[0] + r2[1] + r2[2] + r2[3]);
  }
}

// ---------------- finalize bn1: mean m1, scale s1, cb1 = c1b + c1w . bn1b ----------------
__global__ void k_fin1(const float* __restrict__ sum, const float* __restrict__ sq,
                       const float* __restrict__ g, const float* __restrict__ be,
                       const float* __restrict__ c1w, const float* __restrict__ c1b,
                       float* __restrict__ s1, float* __restrict__ m1, float* __restrict__ cb1) {
  int t = threadIdx.x;
  if (t < C) {
    float m = sum[t] * INV_N;
    float v = sq[t] * INV_N - m * m;
    float r = rsqrtf(v + BN_EPS);
    s1[t] = g[t] * r;
    m1[t] = m;
  }
  __syncthreads();
  if (t < 96) {
    float a = c1b[t];
    const float* wr = c1w + (size_t)t * C;
    for (int c = 0; c < C; c++) a += be[c] * wr[c];
    cb1[t] = a;
  }
}

// ---------------- finalize bn2: mean m2, scale s2, cb2 = c2b + c2w . bn2b ----------------
__global__ void k_fin2(const float* __restrict__ sum, const float* __restrict__ sq,
                       const float* __restrict__ g, const float* __restrict__ be,
                       const float* __restrict__ c2w, const float* __restrict__ c2b,
                       float* __restrict__ s2, float* __restrict__ m2, float* __restrict__ cb2) {
  int t = threadIdx.x;
  if (t < 96) {
    float m = sum[t] * INV_N;
    float v = sq[t] * INV_N - m * m;
    float r = rsqrtf(v + BN_EPS);
    s2[t] = g[t] * r;
    m2[t] = m;
  }
  __syncthreads();
  if (t < C) {
    float a = c2b[t];
    const float* wr = c2w + (size_t)t * 96;
    for (int i = 0; i < 96; i++) a += be[i] * wr[i];
    cb2[t] = a;
  }
}

// ---------------- finalize bn3 ----------------
__global__ void k_fin3(const float* __restrict__ sum, const float* __restrict__ sq,
                       const float* __restrict__ g, const float* __restrict__ be,
                       float* __restrict__ s3, float* __restrict__ d3) {
  int t = threadIdx.x;
  if (t < C) {
    float m = sum[t] * INV_N;
    float v = sq[t] * INV_N - m * m;
    float r = rsqrtf(v + BN_EPS);
    float sc = g[t] * r;
    s3[t] = sc;
    d3[t] = be[t] - m * sc;
  }
}

// ---------------- final: out[b,l,c] = bn3(y3)[b,c,l] + xt2[b,c,l] ----------------
__global__ void k_final(const float* __restrict__ y3, const float* __restrict__ xt2,
                        const float* __restrict__ s3, const float* __restrict__ d3,
                        float* __restrict__ out) {
  __shared__ float tile[32][33];
  int b = blockIdx.z;
  int l0 = blockIdx.x * 32, c0 = blockIdx.y * 32;
  int tx = threadIdx.x, ty = threadIdx.y;
  #pragma unroll
  for (int i = 0; i < 4; i++) {
    int c = c0 + ty + i * 8, l = l0 + tx;
    if (l < L) {
      size_t idx = ((size_t)b * C + c) * L + l;
      tile[ty + i * 8][tx] = y3[idx] * s3[c] + d3[c] + xt2[idx];
    }
  }
  __syncthreads();
  #pragma unroll
  for (int i = 0; i < 4; i++) {
    int l = l0 + ty + i * 8, c = c0 + tx;
    if (l < L) out[((size_t)b * L + l) * C + c] = tile[tx][ty + i * 8];
  }
}

extern "C" void kernel_launch(void* const* d_in, const int* in_sizes, int n_in,
                              void* d_out, int out_size, void* d_ws, size_t ws_size,
                              hipStream_t stream) {
  const float* x    = (const float*)d_in[0];
  const float* dcw  = (const float*)d_in[1];
  const float* dcb  = (const float*)d_in[2];
  const float* p1w  = (const float*)d_in[3];
  const float* p1b  = (const float*)d_in[4];
  const float* p2w  = (const float*)d_in[5];
  const float* p2b  = (const float*)d_in[6];
  const float* qw   = (const float*)d_in[7];
  const float* qb   = (const float*)d_in[8];
  const float* kvw  = (const float*)d_in[9];
  const float* kvb  = (const float*)d_in[10];
  const float* lcw  = (const float*)d_in[11];
  const float* lcb  = (const float*)d_in[12];
  const float* dww  = (const float*)d_in[13];
  const float* dwb  = (const float*)d_in[14];
  const float* bn1g = (const float*)d_in[15];
  const float* bn1b = (const float*)d_in[16];
  const float* c1w  = (const float*)d_in[17];
  const float* c1b  = (const float*)d_in[18];
  const float* bn2g = (const float*)d_in[19];
  const float* bn2b = (const float*)d_in[20];
  const float* c2w  = (const float*)d_in[21];
  const float* c2b  = (const float*)d_in[22];
  const float* bn3g = (const float*)d_in[23];
  const float* bn3b = (const float*)d_in[24];
  float* out = (float*)d_out;
  float* ws  = (float*)d_ws;

  float* xt      = ws + OFF_XT;     // later reused as t1
  float* xt2     = ws + OFF_XT2;
  float* kvbuf   = ws + OFF_KV;     // kv bf16, later y3 fp32
  float* kvin    = ws + OFF_KVIN;   // later reused as attnout
  float* qbuf    = ws + OFF_Q;      // q bf16, later h2 fp32
  float* sm      = ws + OFF_SM;

  float* pooled = sm + SM_POOLED;
  float* xm     = sm + SM_XM;
  float* h1     = sm + SM_H1;
  float* wdyn   = sm + SM_WDYN;
  float* bdyn   = sm + SM_BDYN;
  float* sum1 = sm + SM_SUM1; float* sq1 = sm + SM_SQ1;
  float* s1 = sm + SM_S1; float* m1 = sm + SM_M1; float* cb1 = sm + SM_CB1;
  float* sum2 = sm + SM_SUM2; float* sq2 = sm + SM_SQ2;
  float* s2 = sm + SM_S2; float* m2 = sm + SM_M2; float* cb2 = sm + SM_CB2;
  float* sum3 = sm + SM_SUM3; float* sq3 = sm + SM_SQ3;
  float* s3 = sm + SM_S3; float* d3 = sm + SM_D3;

  hipMemsetAsync((void*)(sm + SM_SUM1), 0, (SM_S3 - SM_SUM1) * sizeof(float), stream);

  dim3 tb32(32, 8);
  // 1. transpose input
  k_transpose_in<<<dim3(32, 24, B), tb32, 0, stream>>>(x, xt);
  // 2. pooled / mean
  k_pool<<<dim3(C2, B), 256, 0, stream>>>(xt, pooled, xm);
  // 3. tiny MLP
  k_mlp1<<<dim3(4, B), 128, 0, stream>>>(pooled, xm, p1w, p1b, h1);
  k_mix2<<<dim3(4, B), 384, 0, stream>>>(h1, p2w, p2b, dcw, dcb, wdyn, bdyn);
  // 4+5. fused dynamic conv (-> xt2 lower) + kv_in
  k_dwpair<<<dim3(C2, B), 256, 0, stream>>>(xt, wdyn, bdyn, lcw, lcb, xt2, kvin);
  // 6. q = (qw @ x2t + qb)*ATT_SCALE -> bf16
  k_gemm_mfma<<<dim3(16, 6, B), 256, 0, stream>>>(qw, xt + (size_t)C2 * L, (void*)qbuf,
                                                  nullptr, nullptr, qb, C2, C2,
                                                  (size_t)C * L, (size_t)C2 * L, 2, ATT_SCALE);
  // 7. kv = kvw @ kv_in + kvb -> bf16
  k_gemm_mfma<<<dim3(16, 12, B), 256, 0, stream>>>(kvw, kvin, (void*)kvbuf,
                                                   nullptr, nullptr, kvb, C, C2,
                                                   (size_t)C2 * L, (size_t)C * L, 2, 1.0f);
  // 8. MFMA flash attention -> attnout (reuses kvin buffer)
  k_attn_mfma<<<dim3(16, H, B), 256, 0, stream>>>((const short*)qbuf, (const short*)kvbuf, kvin);
  // 9. scatter (bug-compatible reshape) -> xt2 upper
  k_fill_xt2<<<dim3(32, 12, B), tb32, 0, stream>>>(kvin, xt2);
  // 10. projection dw3+gelu -> t1 (reuses xt), bn1 stats
  k_dwproj<<<dim3(C, B), 256, 0, stream>>>(xt2, dww, dwb, xt, sum1, sq1);
  k_fin1<<<1, 768, 0, stream>>>(sum1, sq1, bn1g, bn1b, c1w, c1b, s1, m1, cb1);
  // 11. c1 GEMM (centered bn1 folded) + gelu -> h2 (reuses qbuf region, fp32)
  k_gemm_mfma<<<dim3(16, 2, B), 256, 0, stream>>>(c1w, xt, (void*)qbuf,
                                                  m1, s1, cb1, 96, C,
                                                  (size_t)C * L, (size_t)96 * L, 1, 1.0f);
  k_rowstats<<<dim3(96, B), 256, 0, stream>>>(qbuf, 96, sum2, sq2);
  k_fin2<<<1, 768, 0, stream>>>(sum2, sq2, bn2g, bn2b, c2w, c2b, s2, m2, cb2);
  // 12. c2 GEMM (centered bn2 folded) -> y3 (reuses kvbuf region, fp32)
  k_gemm_mfma<<<dim3(16, 12, B), 256, 0, stream>>>(c2w, qbuf, (void*)kvbuf,
                                                   m2, s2, cb2, C, 96,
                                                   (size_t)96 * L, (size_t)C * L, 0, 1.0f);
  k_rowstats<<<dim3(C, B), 256, 0, stream>>>(kvbuf, C, sum3, sq3);
  k_fin3<<<1, 768, 0, stream>>>(sum3, sq3, bn3g, bn3b, s3, d3);
  // 13. final bn3 + residual + transpose back
  k_final<<<dim3(32, 24, B), tb32, 0, stream>>>(kvbuf, xt2, s3, d3, out);
}

// Round 8
// 581.292 us; speedup vs baseline: 3.7164x; 1.0912x over previous
//
#include <hip/hip_runtime.h>
#include <cstddef>

constexpr int B = 8, L = 999, C = 768, C2 = 384, H = 8, HD = 48;
constexpr float ATT_SCALE = 0.14433756729740644f;   // 48^-0.5
constexpr float BN_EPS = 1e-5f;
constexpr float INV_N = 1.0f / (8.0f * 999.0f);     // 1/(B*L)

constexpr size_t SZ_XT   = (size_t)B * C * L;       // 6,137,856
constexpr size_t SZ_HALF = (size_t)B * C2 * L;      // 3,068,928
constexpr size_t OFF_XT  = 0;                       // xt fp32, later t1
constexpr size_t OFF_XT2 = SZ_XT;                   // xt2 fp32
constexpr size_t OFF_KV  = 2 * SZ_XT;               // kv bf16, later y3 fp32
constexpr size_t OFF_AX  = 3 * SZ_XT;               // x2bf + kvinbf (bf16), later attnout fp32
constexpr size_t OFF_Q   = 3 * SZ_XT + SZ_HALF;     // q bf16, later h2 fp32
constexpr size_t OFF_SM  = 3 * SZ_XT + SZ_HALF + SZ_HALF / 2;

// small-region offsets (floats, relative to OFF_SM)
constexpr size_t SM_POOLED = 0;       // B*C2*3
constexpr size_t SM_XM     = 9216;    // B*C2
constexpr size_t SM_H1     = 12288;   // B*4*96
constexpr size_t SM_WDYN   = 15360;   // B*C2*3
constexpr size_t SM_BDYN   = 24576;   // B*C2
constexpr size_t SM_SUM1   = 27648;   // 768
constexpr size_t SM_SQ1    = 28416;
constexpr size_t SM_S1     = 29184;   // bn1 scale g/sigma
constexpr size_t SM_M1     = 29952;   // bn1 mean
constexpr size_t SM_CB1    = 30720;   // 96
constexpr size_t SM_SUM2   = 30816;   // 96
constexpr size_t SM_SQ2    = 30912;
constexpr size_t SM_S2     = 31008;
constexpr size_t SM_M2     = 31104;
constexpr size_t SM_CB2    = 31200;   // 768
constexpr size_t SM_SUM3   = 31968;
constexpr size_t SM_SQ3    = 32736;
constexpr size_t SM_S3     = 33504;
constexpr size_t SM_D3     = 34272;
constexpr size_t SM_END    = 35040;
// bf16 weight copies (float-slot offsets relative to OFF_SM)
constexpr size_t SM_WQ  = SM_END;                 // 147456 sh = 73728 fl
constexpr size_t SM_WKV = SM_WQ + 73728;          // 294912 sh = 147456 fl
constexpr size_t SM_WC1 = SM_WKV + 147456;        // 73728 sh = 36864 fl
constexpr size_t SM_WC2 = SM_WC1 + 36864;         // 73728 sh = 36864 fl

typedef __attribute__((ext_vector_type(8))) short bf16x8;
typedef __attribute__((ext_vector_type(4))) float floatx4;

__device__ __forceinline__ float gelu_f(float x) {
  return 0.5f * x * (1.0f + erff(x * 0.70710678118654752f));
}

__device__ __forceinline__ float wave_sum(float v) {
  #pragma unroll
  for (int off = 32; off > 0; off >>= 1) v += __shfl_down(v, off, 64);
  return v;
}

__device__ __forceinline__ short f2bf(float f) {
  union { float f; unsigned u; } x; x.f = f;
  unsigned r = x.u + 0x7FFFu + ((x.u >> 16) & 1u);
  return (short)(r >> 16);
}

// ---------------- fp32 -> bf16 bulk convert (weights) ----------------
__global__ void k_cvt_bf16(const float* __restrict__ src, short* __restrict__ dst, int n) {
  int i = (blockIdx.x * 256 + threadIdx.x) * 8;
  if (i >= n) return;
  float4 a = *reinterpret_cast<const float4*>(&src[i]);
  float4 b = *reinterpret_cast<const float4*>(&src[i + 4]);
  short tmp[8] = {f2bf(a.x), f2bf(a.y), f2bf(a.z), f2bf(a.w),
                  f2bf(b.x), f2bf(b.y), f2bf(b.z), f2bf(b.w)};
  *(bf16x8*)&dst[i] = *(bf16x8*)tmp;
}

// ---------------- transpose x (B,L,C) -> xt fp32 (B,C,L) + x2bf bf16 upper ----------------
__global__ void k_transpose_in(const float* __restrict__ x, float* __restrict__ xt,
                               short* __restrict__ x2bf) {
  __shared__ float tile[32][33];
  int b = blockIdx.z;
  int l0 = blockIdx.x * 32, c0 = blockIdx.y * 32;
  int tx = threadIdx.x, ty = threadIdx.y;
  #pragma unroll
  for (int i = 0; i < 4; i++) {
    int l = l0 + ty + i * 8, c = c0 + tx;
    if (l < L) tile[ty + i * 8][tx] = x[((size_t)b * L + l) * C + c];
  }
  __syncthreads();
  #pragma unroll
  for (int i = 0; i < 4; i++) {
    int c = c0 + ty + i * 8, l = l0 + tx;
    if (l < L) {
      float v = tile[tx][ty + i * 8];
      xt[((size_t)b * C + c) * L + l] = v;
      if (c >= C2) x2bf[((size_t)b * C2 + (c - C2)) * L + l] = f2bf(v);
    }
  }
}

// ---------------- pooled chunk means + row mean ----------------
__global__ __launch_bounds__(256) void k_pool(const float* __restrict__ xt,
                                              float* __restrict__ pooled,
                                              float* __restrict__ xm) {
  int c = blockIdx.x, b = blockIdx.y;
  const float* row = xt + ((size_t)b * C + c) * L;
  float s0 = 0.f, s1 = 0.f, s2 = 0.f;
  for (int l = threadIdx.x; l < L; l += 256) {
    float v = row[l];
    int ch = l / 333;
    if (ch == 0) s0 += v; else if (ch == 1) s1 += v; else s2 += v;
  }
  s0 = wave_sum(s0); s1 = wave_sum(s1); s2 = wave_sum(s2);
  __shared__ float r[3][4];
  int lane = threadIdx.x & 63, wid = threadIdx.x >> 6;
  if (lane == 0) { r[0][wid] = s0; r[1][wid] = s1; r[2][wid] = s2; }
  __syncthreads();
  if (threadIdx.x == 0) {
    float t0 = r[0][0] + r[0][1] + r[0][2] + r[0][3];
    float t1 = r[1][0] + r[1][1] + r[1][2] + r[1][3];
    float t2 = r[2][0] + r[2][1] + r[2][2] + r[2][3];
    size_t pb = (size_t)(b * C2 + c) * 3;
    pooled[pb + 0] = t0 / 333.f;
    pooled[pb + 1] = t1 / 333.f;
    pooled[pb + 2] = t2 / 333.f;
    xm[b * C2 + c] = (t0 + t1 + t2) / 999.f;
  }
}

// ---------------- tiny MLP layer 1 ----------------
__global__ void k_mlp1(const float* __restrict__ pooled, const float* __restrict__ xm,
                       const float* __restrict__ p1w, const float* __restrict__ p1b,
                       float* __restrict__ h1) {
  int j = blockIdx.x, b = blockIdx.y;
  __shared__ float vin[C2];
  for (int c = threadIdx.x; c < C2; c += 128)
    vin[c] = (j < 3) ? pooled[(size_t)(b * C2 + c) * 3 + j] : xm[b * C2 + c];
  __syncthreads();
  int o = threadIdx.x;
  if (o < 96) {
    float acc = p1b[o];
    const float* wr = p1w + (size_t)o * C2;
    for (int c = 0; c < C2; c++) acc += vin[c] * wr[c];
    h1[(b * 4 + j) * 96 + o] = gelu_f(acc);
  }
}

// ---------------- MLP layer 2 + softmax + mix ----------------
__global__ void k_mix2(const float* __restrict__ h1,
                       const float* __restrict__ p2w, const float* __restrict__ p2b,
                       const float* __restrict__ dcw, const float* __restrict__ dcb,
                       float* __restrict__ wdyn, float* __restrict__ bdyn) {
  int j = blockIdx.x, b = blockIdx.y;
  __shared__ float hv[96];
  for (int i = threadIdx.x; i < 96; i += 384) hv[i] = h1[(b * 4 + j) * 96 + i];
  __syncthreads();
  int c = threadIdx.x;
  float a0 = p2b[c], a1 = p2b[C2 + c];
  const float* w0r = p2w + (size_t)c * 96;
  const float* w1r = p2w + (size_t)(C2 + c) * 96;
  for (int i = 0; i < 96; i++) { float h = hv[i]; a0 += h * w0r[i]; a1 += h * w1r[i]; }
  float m = fmaxf(a0, a1);
  float e0 = __expf(a0 - m), e1 = __expf(a1 - m);
  float inv = 1.f / (e0 + e1);
  float p0 = e0 * inv, p1 = e1 * inv;
  if (j < 3)
    wdyn[(size_t)(b * C2 + c) * 3 + j] = p0 * dcw[(size_t)c * 3 + j] + p1 * dcw[(size_t)(C2 + c) * 3 + j];
  else
    bdyn[b * C2 + c] = p0 * dcb[c] + p1 * dcb[C2 + c];
}

// ---------------- fused dyn-conv (xt2 lower, fp32) + kv_in (bf16) ----------------
__global__ __launch_bounds__(256) void k_dwpair(const float* __restrict__ xt,
                                                const float* __restrict__ wdyn,
                                                const float* __restrict__ bdyn,
                                                const float* __restrict__ lcw,
                                                const float* __restrict__ lcb,
                                                float* __restrict__ xt2,
                                                short* __restrict__ kvbf) {
  int c = blockIdx.x, b = blockIdx.y;
  const float* rowA = xt + ((size_t)b * C + c) * L;
  size_t wb = (size_t)(b * C2 + c) * 3;
  float a0 = wdyn[wb], a1 = wdyn[wb + 1], a2 = wdyn[wb + 2], ab = bdyn[b * C2 + c];
  float* oA = xt2 + ((size_t)b * C + c) * L;
  const float* rowB = xt + ((size_t)b * C + C2 + c) * L;
  float w0 = lcw[c * 3], w1 = lcw[c * 3 + 1] + 1.0f, w2 = lcw[c * 3 + 2], bb = lcb[c];
  short* oB = kvbf + ((size_t)b * C2 + c) * L;
  for (int l = threadIdx.x; l < L; l += 256) {
    {
      float xm1 = (l > 0) ? rowA[l - 1] : 0.f;
      float x0 = rowA[l];
      float xp1 = (l < L - 1) ? rowA[l + 1] : 0.f;
      oA[l] = xm1 * a0 + x0 * a1 + xp1 * a2 + ab;
    }
    {
      float xm1 = (l > 0) ? rowB[l - 1] : 0.f;
      float x0 = rowB[l];
      float xp1 = (l < L - 1) ? rowB[l + 1] : 0.f;
      oB[l] = f2bf(xm1 * w0 + x0 * w1 + xp1 * w2 + bb);
    }
  }
}

// ---------------- MFMA GEMM: 64o x 128l tiles, BK=64, preconverted bf16 W ----------------
// flags: 1 gelu, 2 bf16 out, 4 X is bf16, 8 accumulate BN stats (sum/sq per o).
// fp32-X path applies (x - shift[k]) * scale[k] at staging (centered before bf16).
// X staging is scalar (R6-proven pattern); strides are unpadded L.
__global__ __launch_bounds__(256) void k_gemm2(const short* __restrict__ Wbf,
                                               const void* __restrict__ Xv,
                                               void* __restrict__ Yv,
                                               const float* __restrict__ shift,
                                               const float* __restrict__ scale,
                                               const float* __restrict__ bias,
                                               float* __restrict__ sum, float* __restrict__ sq,
                                               int O, int Kd, size_t xbs, size_t ybs,
                                               int flags, float outmul) {
  __shared__ __align__(16) short Wt[64 * 72];
  __shared__ __align__(16) short Xt[128 * 72];
  int b = blockIdx.z;
  int o0 = blockIdx.y * 64, l0 = blockIdx.x * 128;
  int t = threadIdx.x, w = t >> 6, lane = t & 63;
  int col = lane & 15, quad = lane >> 4;
  floatx4 acc[8];
  #pragma unroll
  for (int i = 0; i < 8; i++) acc[i] = floatx4{0.f, 0.f, 0.f, 0.f};

  for (int k0 = 0; k0 < Kd; k0 += 64) {
    // ---- W tile (bf16, vector loads; rows 8-short aligned since Kd%8==0) ----
    #pragma unroll
    for (int u = 0; u < 2; u++) {
      int uu = t + u * 256;
      int o = uu >> 3, ks = (uu & 7) * 8;
      int oo = o0 + o, k = k0 + ks;
      bf16x8 w8 = {0, 0, 0, 0, 0, 0, 0, 0};
      if (oo < O && k < Kd) w8 = *(const bf16x8*)&Wbf[(size_t)oo * Kd + k];
      *(bf16x8*)&Wt[o * 72 + ks] = w8;
    }
    // ---- X tile -> Xt[l][k], scalar loads, k-pairs packed (R6 pattern) ----
    if (flags & 4) {
      const short* Xb = (const short*)Xv + (size_t)b * xbs;
      #pragma unroll
      for (int rep = 0; rep < 16; rep++) {
        int u = t + rep * 256;
        int kk2 = u >> 7, ll = u & 127;
        int k = k0 + 2 * kk2, l = l0 + ll;
        unsigned s0_ = 0, s1_ = 0;
        if (l < L && k < Kd) {
          s0_ = (unsigned short)Xb[(size_t)k * L + l];
          s1_ = (unsigned short)Xb[(size_t)(k + 1) * L + l];
        }
        *(unsigned*)&Xt[ll * 72 + 2 * kk2] = s0_ | (s1_ << 16);
      }
    } else {
      const float* Xb = (const float*)Xv + (size_t)b * xbs;
      #pragma unroll
      for (int rep = 0; rep < 16; rep++) {
        int u = t + rep * 256;
        int kk2 = u >> 7, ll = u & 127;
        int k = k0 + 2 * kk2, l = l0 + ll;
        float x0 = 0.f, x1 = 0.f;
        if (l < L && k < Kd) {
          x0 = Xb[(size_t)k * L + l];
          x1 = Xb[(size_t)(k + 1) * L + l];
          if (shift) { x0 -= shift[k]; x1 -= shift[k + 1]; }
          if (scale) { x0 *= scale[k]; x1 *= scale[k + 1]; }
        }
        unsigned pk = (unsigned)(unsigned short)f2bf(x0) | ((unsigned)(unsigned short)f2bf(x1) << 16);
        *(unsigned*)&Xt[ll * 72 + 2 * kk2] = pk;
      }
    }
    __syncthreads();
    // ---- MFMA: wave w owns o-strip [w*16, w*16+16), 8 l-subtiles ----
    #pragma unroll
    for (int half = 0; half < 2; half++) {
      bf16x8 aw = *(bf16x8*)&Wt[(w * 16 + col) * 72 + half * 32 + quad * 8];
      #pragma unroll
      for (int nt = 0; nt < 8; nt++) {
        bf16x8 bx = *(bf16x8*)&Xt[(nt * 16 + col) * 72 + half * 32 + quad * 8];
        acc[nt] = __builtin_amdgcn_mfma_f32_16x16x32_bf16(aw, bx, acc[nt], 0, 0, 0);
      }
    }
    __syncthreads();
  }
  // ---- epilogue: D row=o (quad*4+r), col=l; gelu/outmul/bf16/stats ----
  int o_base = o0 + w * 16 + quad * 4;
  #pragma unroll
  for (int r = 0; r < 4; r++) {
    int o = o_base + r;
    bool ov = o < O;
    float bo = (bias && ov) ? bias[o] : 0.f;
    float ps = 0.f, pq = 0.f;
    #pragma unroll
    for (int nt = 0; nt < 8; nt++) {
      int l = l0 + nt * 16 + col;
      float v = acc[nt][r] + bo;
      if (flags & 1) v = gelu_f(v);
      v *= outmul;
      if (l >= L) v = 0.f;
      if (ov && l < L) {
        if (flags & 2) ((short*)Yv)[(size_t)b * ybs + (size_t)o * L + l] = f2bf(v);
        else           ((float*)Yv)[(size_t)b * ybs + (size_t)o * L + l] = v;
      }
      ps += v; pq += v * v;
    }
    if ((flags & 8) && ov) {
      ps += __shfl_xor(ps, 1); ps += __shfl_xor(ps, 2);
      ps += __shfl_xor(ps, 4); ps += __shfl_xor(ps, 8);
      pq += __shfl_xor(pq, 1); pq += __shfl_xor(pq, 2);
      pq += __shfl_xor(pq, 4); pq += __shfl_xor(pq, 8);
      if (col == 0) { atomicAdd(&sum[o], ps); atomicAdd(&sq[o], pq); }
    }
  }
}

// ---------------- MFMA flash attention: R6-verbatim (strides L, bf16 q/kv) ----------------
__global__ __launch_bounds__(256) void k_attn_mfma(const short* __restrict__ q,
                                                   const short* __restrict__ kv,
                                                   float* __restrict__ out) {
  __shared__ __align__(16) char smem[9216 * 3 + 6144];
  short* Qs = (short*)smem;              // [64 l][72] bf16
  short* Ks = (short*)(smem + 9216);     // [64 m][72] bf16
  short* Ps = (short*)(smem + 18432);    // [64 l][72] bf16
  short* Vf = (short*)(smem + 27648);    // [chunk2][dsub3][lane64][8] bf16
  float* Os = (float*)smem;              // epilogue overlay: [48 d][66 l] fp32

  int lt0 = blockIdx.x * 64;
  int h = blockIdx.y, b = blockIdx.z;
  int t = threadIdx.x;
  int w = t >> 6, lane = t & 63;
  int col = lane & 15, quad = lane >> 4;
  const short* qb = q  + ((size_t)b * C2 + h * HD) * L;
  const short* kb = kv + ((size_t)b * C  + h * HD) * L;
  const short* vb = kv + ((size_t)b * C + C2 + h * HD) * L;

  for (int i = t; i < 64 * 16; i += 256) {
    int row = i >> 4, d = 48 + (i & 15);
    Qs[row * 72 + d] = 0;
    Ks[row * 72 + d] = 0;
  }
  for (int i = t; i < 64 * 24; i += 256) {
    int d2 = i >> 6, ll = i & 63;
    int l = lt0 + ll;
    unsigned pk = 0;
    if (l < L) {
      unsigned s0_ = (unsigned short)qb[(size_t)(2 * d2) * L + l];
      unsigned s1_ = (unsigned short)qb[(size_t)(2 * d2 + 1) * L + l];
      pk = s0_ | (s1_ << 16);
    }
    *(unsigned*)&Qs[ll * 72 + 2 * d2] = pk;
  }

  floatx4 of[3];
  #pragma unroll
  for (int i = 0; i < 3; i++) of[i] = floatx4{0.f, 0.f, 0.f, 0.f};
  float rs[4] = {0.f, 0.f, 0.f, 0.f};
  __syncthreads();

  for (int m0 = 0; m0 < L; m0 += 64) {
    for (int i = t; i < 64 * 24; i += 256) {
      int d2 = i >> 6, mm = i & 63;
      int m = m0 + mm;
      unsigned pk = 0;
      if (m < L) {
        unsigned s0_ = (unsigned short)kb[(size_t)(2 * d2) * L + m];
        unsigned s1_ = (unsigned short)kb[(size_t)(2 * d2 + 1) * L + m];
        pk = s0_ | (s1_ << 16);
      }
      *(unsigned*)&Ks[mm * 72 + 2 * d2] = pk;
    }
    for (int a = t; a < 384; a += 256) {
      int d = (a & 7) | ((a >> 6) << 3);   // 0..47
      int o = (a >> 3) & 7;                // m-octet 0..7
      int mb = m0 + o * 8;
      const short* src = vb + (size_t)d * L + mb;
      short v8a[8];
      #pragma unroll
      for (int j = 0; j < 8; j++) v8a[j] = (mb + j < L) ? src[j] : (short)0;
      int chunk = o >> 2, dsub = d >> 4;
      int lanep = ((o & 3) << 4) | (d & 15);
      *(bf16x8*)&Vf[((chunk * 3 + dsub) * 64 + lanep) * 8] = *(bf16x8*)&v8a[0];
    }
    __syncthreads();

    bf16x8 aq0 = *(bf16x8*)&Qs[(w * 16 + col) * 72 + quad * 8];
    bf16x8 aq1 = *(bf16x8*)&Qs[(w * 16 + col) * 72 + 32 + quad * 8];
    floatx4 sf[4];
    #pragma unroll
    for (int ms = 0; ms < 4; ms++) {
      bf16x8 bk0 = *(bf16x8*)&Ks[(ms * 16 + col) * 72 + quad * 8];
      bf16x8 bk1 = *(bf16x8*)&Ks[(ms * 16 + col) * 72 + 32 + quad * 8];
      floatx4 a4 = floatx4{0.f, 0.f, 0.f, 0.f};
      a4 = __builtin_amdgcn_mfma_f32_16x16x32_bf16(aq0, bk0, a4, 0, 0, 0);
      a4 = __builtin_amdgcn_mfma_f32_16x16x32_bf16(aq1, bk1, a4, 0, 0, 0);
      sf[ms] = a4;
    }
    float rloc[4] = {0.f, 0.f, 0.f, 0.f};
    #pragma unroll
    for (int ms = 0; ms < 4; ms++) {
      int m = m0 + ms * 16 + col;
      bool ok = m < L;
      #pragma unroll
      for (int r = 0; r < 4; r++) {
        float e = ok ? __expf(sf[ms][r]) : 0.f;
        rloc[r] += e;
        Ps[(w * 16 + quad * 4 + r) * 72 + ms * 16 + col] = f2bf(e);
      }
    }
    #pragma unroll
    for (int r = 0; r < 4; r++) {
      float v = rloc[r];
      v += __shfl_xor(v, 1); v += __shfl_xor(v, 2);
      v += __shfl_xor(v, 4); v += __shfl_xor(v, 8);
      rs[r] += v;
    }
    __syncthreads();

    bf16x8 ap0 = *(bf16x8*)&Ps[(w * 16 + col) * 72 + quad * 8];
    bf16x8 ap1 = *(bf16x8*)&Ps[(w * 16 + col) * 72 + 32 + quad * 8];
    #pragma unroll
    for (int ds = 0; ds < 3; ds++) {
      bf16x8 bv0 = *(bf16x8*)&Vf[((0 * 3 + ds) * 64 + lane) * 8];
      bf16x8 bv1 = *(bf16x8*)&Vf[((1 * 3 + ds) * 64 + lane) * 8];
      of[ds] = __builtin_amdgcn_mfma_f32_16x16x32_bf16(ap0, bv0, of[ds], 0, 0, 0);
      of[ds] = __builtin_amdgcn_mfma_f32_16x16x32_bf16(ap1, bv1, of[ds], 0, 0, 0);
    }
    __syncthreads();
  }

  #pragma unroll
  for (int r = 0; r < 4; r++) {
    float inv = 1.f / rs[r];
    #pragma unroll
    for (int ds = 0; ds < 3; ds++)
      Os[(ds * 16 + col) * 66 + w * 16 + quad * 4 + r] = of[ds][r] * inv;
  }
  __syncthreads();
  for (int i = t; i < 48 * 64; i += 256) {
    int d = i >> 6, ll = i & 63;
    int l = lt0 + ll;
    if (l < L) out[((size_t)b * C2 + h * HD + d) * L + l] = Os[d * 66 + ll];
  }
}

// ---------------- scatter attention out (bug-compatible reshape) -> xt2 upper ----------------
__global__ void k_fill_xt2(const float* __restrict__ ao, float* __restrict__ xt2) {
  __shared__ float tile[32][33];
  int b = blockIdx.z;
  int l0 = blockIdx.x * 32, c0 = blockIdx.y * 32;
  int tx = threadIdx.x, ty = threadIdx.y;
  #pragma unroll
  for (int i = 0; i < 4; i++) {
    int l = l0 + ty + i * 8, c = c0 + tx;
    if (l < L) tile[ty + i * 8][tx] = ao[(size_t)b * ((size_t)L * C2) + (size_t)l * C2 + c];
  }
  __syncthreads();
  #pragma unroll
  for (int i = 0; i < 4; i++) {
    int c = c0 + ty + i * 8, l = l0 + tx;
    if (l < L) xt2[((size_t)b * C + C2 + c) * L + l] = tile[tx][ty + i * 8];
  }
}

// ---------------- projection dw3 + gelu -> t1, bn1 stats ----------------
__global__ __launch_bounds__(256) void k_dwproj(const float* __restrict__ xt2,
                                                const float* __restrict__ dww,
                                                const float* __restrict__ dwb,
                                                float* __restrict__ t1,
                                                float* __restrict__ sum, float* __restrict__ sq) {
  int c = blockIdx.x, b = blockIdx.y;
  const float* row = xt2 + ((size_t)b * C + c) * L;
  float w0 = dww[c * 3], w1 = dww[c * 3 + 1], w2 = dww[c * 3 + 2], bb = dwb[c];
  float* orow = t1 + ((size_t)b * C + c) * L;
  float s = 0.f, s2 = 0.f;
  for (int l = threadIdx.x; l < L; l += 256) {
    float xm1 = (l > 0) ? row[l - 1] : 0.f;
    float x0 = row[l];
    float xp1 = (l < L - 1) ? row[l + 1] : 0.f;
    float v = gelu_f(xm1 * w0 + x0 * w1 + xp1 * w2 + bb);
    orow[l] = v;
    s += v; s2 += v * v;
  }
  s = wave_sum(s); s2 = wave_sum(s2);
  __shared__ float r1[4], r2[4];
  int lane = threadIdx.x & 63, wid = threadIdx.x >> 6;
  if (lane == 0) { r1[wid] = s; r2[wid] = s2; }
  __syncthreads();
  if (threadIdx.x == 0) {
    atomicAdd(&sum[c], r1[0] + r1[1] + r1[2] + r1[3]);
    atomicAdd(&sq[c], r2[0] + r2[1] + r2[2] + r2[3]);
  }
}

// ---------------- finalize bn1: s1, m1, cb1 = c1b + c1w . bn1b ----------------
__global__ void k_fin1(const float* __restrict__ sum, const float* __restrict__ sq,
                       const float* __restrict__ g, const float* __restrict__ be,
                       const float* __restrict__ c1w, const float* __restrict__ c1b,
                       float* __restrict__ s1, float* __restrict__ m1, float* __restrict__ cb1) {
  int t = threadIdx.x;
  if (t < C) {
    float m = sum[t] * INV_N;
    float v = sq[t] * INV_N - m * m;
    float r = rsqrtf(v + BN_EPS);
    s1[t] = g[t] * r;
    m1[t] = m;
  }
  __syncthreads();
  if (t < 96) {
    float a = c1b[t];
    const float* wr = c1w + (size_t)t * C;
    for (int c = 0; c < C; c++) a += be[c] * wr[c];
    cb1[t] = a;
  }
}

// ---------------- finalize bn2: s2, m2, cb2 = c2b + c2w . bn2b ----------------
__global__ void k_fin2(const float* __restrict__ sum, const float* __restrict__ sq,
                       const float* __restrict__ g, const float* __restrict__ be,
                       const float* __restrict__ c2w, const float* __restrict__ c2b,
                       float* __restrict__ s2, float* __restrict__ m2, float* __restrict__ cb2) {
  int t = threadIdx.x;
  if (t < 96) {
    float m = sum[t] * INV_N;
    float v = sq[t] * INV_N - m * m;
    float r = rsqrtf(v + BN_EPS);
    s2[t] = g[t] * r;
    m2[t] = m;
  }
  __syncthreads();
  if (t < C) {
    float a = c2b[t];
    const float* wr = c2w + (size_t)t * 96;
    for (int i = 0; i < 96; i++) a += be[i] * wr[i];
    cb2[t] = a;
  }
}

// ---------------- finalize bn3 ----------------
__global__ void k_fin3(const float* __restrict__ sum, const float* __restrict__ sq,
                       const float* __restrict__ g, const float* __restrict__ be,
                       float* __restrict__ s3, float* __restrict__ d3) {
  int t = threadIdx.x;
  if (t < C) {
    float m = sum[t] * INV_N;
    float v = sq[t] * INV_N - m * m;
    float r = rsqrtf(v + BN_EPS);
    float sc = g[t] * r;
    s3[t] = sc;
    d3[t] = be[t] - m * sc;
  }
}

// ---------------- final: out[b,l,c] = bn3(y3) + xt2 (transpose back) ----------------
__global__ void k_final(const float* __restrict__ y3, const float* __restrict__ xt2,
                        const float* __restrict__ s3, const float* __restrict__ d3,
                        float* __restrict__ out) {
  __shared__ float tile[32][33];
  int b = blockIdx.z;
  int l0 = blockIdx.x * 32, c0 = blockIdx.y * 32;
  int tx = threadIdx.x, ty = threadIdx.y;
  #pragma unroll
  for (int i = 0; i < 4; i++) {
    int c = c0 + ty + i * 8, l = l0 + tx;
    if (l < L) {
      size_t idx = ((size_t)b * C + c) * L + l;
      tile[ty + i * 8][tx] = y3[idx] * s3[c] + d3[c] + xt2[idx];
    }
  }
  __syncthreads();
  #pragma unroll
  for (int i = 0; i < 4; i++) {
    int l = l0 + ty + i * 8, c = c0 + tx;
    if (l < L) out[((size_t)b * L + l) * C + c] = tile[tx][ty + i * 8];
  }
}

extern "C" void kernel_launch(void* const* d_in, const int* in_sizes, int n_in,
                              void* d_out, int out_size, void* d_ws, size_t ws_size,
                              hipStream_t stream) {
  const float* x    = (const float*)d_in[0];
  const float* dcw  = (const float*)d_in[1];
  const float* dcb  = (const float*)d_in[2];
  const float* p1w  = (const float*)d_in[3];
  const float* p1b  = (const float*)d_in[4];
  const float* p2w  = (const float*)d_in[5];
  const float* p2b  = (const float*)d_in[6];
  const float* qw   = (const float*)d_in[7];
  const float* qb   = (const float*)d_in[8];
  const float* kvw  = (const float*)d_in[9];
  const float* kvb  = (const float*)d_in[10];
  const float* lcw  = (const float*)d_in[11];
  const float* lcb  = (const float*)d_in[12];
  const float* dww  = (const float*)d_in[13];
  const float* dwb  = (const float*)d_in[14];
  const float* bn1g = (const float*)d_in[15];
  const float* bn1b = (const float*)d_in[16];
  const float* c1w  = (const float*)d_in[17];
  const float* c1b  = (const float*)d_in[18];
  const float* bn2g = (const float*)d_in[19];
  const float* bn2b = (const float*)d_in[20];
  const float* c2w  = (const float*)d_in[21];
  const float* c2b  = (const float*)d_in[22];
  const float* bn3g = (const float*)d_in[23];
  const float* bn3b = (const float*)d_in[24];
  float* out = (float*)d_out;
  float* ws  = (float*)d_ws;

  float* xt      = ws + OFF_XT;                      // fp32, later t1
  float* xt2     = ws + OFF_XT2;                     // fp32
  short* kvbuf   = (short*)(ws + OFF_KV);            // bf16 kv
  float* y3      = ws + OFF_KV;                      // fp32 (reuse)
  short* x2bf    = (short*)(ws + OFF_AX);            // bf16 x2t
  short* kvinbf  = (short*)(ws + OFF_AX + SZ_HALF / 2);  // bf16 kv_in
  float* attnout = ws + OFF_AX;                      // fp32 (reuse)
  short* qbuf    = (short*)(ws + OFF_Q);             // bf16 q
  float* h2      = ws + OFF_Q;                       // fp32 (reuse)
  float* sm      = ws + OFF_SM;

  float* pooled = sm + SM_POOLED;
  float* xm     = sm + SM_XM;
  float* h1     = sm + SM_H1;
  float* wdyn   = sm + SM_WDYN;
  float* bdyn   = sm + SM_BDYN;
  float* sum1 = sm + SM_SUM1; float* sq1 = sm + SM_SQ1;
  float* s1 = sm + SM_S1; float* m1 = sm + SM_M1; float* cb1 = sm + SM_CB1;
  float* sum2 = sm + SM_SUM2; float* sq2 = sm + SM_SQ2;
  float* s2 = sm + SM_S2; float* m2 = sm + SM_M2; float* cb2 = sm + SM_CB2;
  float* sum3 = sm + SM_SUM3; float* sq3 = sm + SM_SQ3;
  float* s3 = sm + SM_S3; float* d3 = sm + SM_D3;
  short* wqbf  = (short*)(sm + SM_WQ);
  short* wkvbf = (short*)(sm + SM_WKV);
  short* wc1bf = (short*)(sm + SM_WC1);
  short* wc2bf = (short*)(sm + SM_WC2);

  hipMemsetAsync((void*)(sm + SM_SUM1), 0, (SM_S3 - SM_SUM1) * sizeof(float), stream);

  // 0. weight conversions to bf16
  k_cvt_bf16<<<72, 256, 0, stream>>>(qw, wqbf, C2 * C2);
  k_cvt_bf16<<<144, 256, 0, stream>>>(kvw, wkvbf, 2 * C2 * C2);
  k_cvt_bf16<<<36, 256, 0, stream>>>(c1w, wc1bf, 96 * C);
  k_cvt_bf16<<<36, 256, 0, stream>>>(c2w, wc2bf, C * 96);

  dim3 tb32(32, 8);
  // 1. transpose input (+ bf16 upper half)
  k_transpose_in<<<dim3(32, 24, B), tb32, 0, stream>>>(x, xt, x2bf);
  // 2. pooled / mean
  k_pool<<<dim3(C2, B), 256, 0, stream>>>(xt, pooled, xm);
  // 3. tiny MLP
  k_mlp1<<<dim3(4, B), 128, 0, stream>>>(pooled, xm, p1w, p1b, h1);
  k_mix2<<<dim3(4, B), 384, 0, stream>>>(h1, p2w, p2b, dcw, dcb, wdyn, bdyn);
  // 4. fused dyn-conv + kv_in (bf16)
  k_dwpair<<<dim3(C2, B), 256, 0, stream>>>(xt, wdyn, bdyn, lcw, lcb, xt2, kvinbf);
  // 5. q GEMM: bf16 X, bf16 out, *ATT_SCALE
  k_gemm2<<<dim3(8, 6, B), 256, 0, stream>>>(wqbf, (const void*)x2bf, (void*)qbuf,
                                             nullptr, nullptr, qb, nullptr, nullptr,
                                             C2, C2, (size_t)C2 * L, (size_t)C2 * L,
                                             6, ATT_SCALE);
  // 6. kv GEMM: bf16 X, bf16 out
  k_gemm2<<<dim3(8, 12, B), 256, 0, stream>>>(wkvbf, (const void*)kvinbf, (void*)kvbuf,
                                              nullptr, nullptr, kvb, nullptr, nullptr,
                                              C, C2, (size_t)C2 * L, (size_t)C * L,
                                              6, 1.0f);
  // 7. MFMA flash attention -> attnout
  k_attn_mfma<<<dim3(16, H, B), 256, 0, stream>>>(qbuf, kvbuf, attnout);
  // 8. scatter reshape -> xt2 upper
  k_fill_xt2<<<dim3(32, 12, B), tb32, 0, stream>>>(attnout, xt2);
  // 9. projection dw3+gelu -> t1 (reuses xt), bn1 stats
  k_dwproj<<<dim3(C, B), 256, 0, stream>>>(xt2, dww, dwb, xt, sum1, sq1);
  k_fin1<<<1, 768, 0, stream>>>(sum1, sq1, bn1g, bn1b, c1w, c1b, s1, m1, cb1);
  // 10. c1 GEMM: fp32 X centered (m1,s1), gelu, fp32 out, stats -> sum2/sq2
  k_gemm2<<<dim3(8, 2, B), 256, 0, stream>>>(wc1bf, (const void*)xt, (void*)h2,
                                             m1, s1, cb1, sum2, sq2,
                                             96, C, (size_t)C * L, (size_t)96 * L,
                                             9, 1.0f);
  k_fin2<<<1, 768, 0, stream>>>(sum2, sq2, bn2g, bn2b, c2w, c2b, s2, m2, cb2);
  // 11. c2 GEMM: fp32 X centered (m2,s2), fp32 out, stats -> sum3/sq3
  k_gemm2<<<dim3(8, 12, B), 256, 0, stream>>>(wc2bf, (const void*)h2, (void*)y3,
                                              m2, s2, cb2, sum3, sq3,
                                              C, 96, (size_t)96 * L, (size_t)C * L,
                                              8, 1.0f);
  k_fin3<<<1, 768, 0, stream>>>(sum3, sq3, bn3g, bn3b, s3, d3);
  // 12. final bn3 + residual + transpose back
  k_final<<<dim3(32, 24, B), tb32, 0, stream>>>(y3, xt2, s3, d3, out);
}

// Round 9
// 493.048 us; speedup vs baseline: 4.3816x; 1.1790x over previous
//
#include <hip/hip_runtime.h>
#include <cstddef>

constexpr int B = 8, L = 999, C = 768, C2 = 384, H = 8, HD = 48;
constexpr float ATT_SCALE = 0.14433756729740644f;   // 48^-0.5
constexpr float BN_EPS = 1e-5f;
constexpr float INV_N = 1.0f / (8.0f * 999.0f);     // 1/(B*L)

constexpr size_t SZ_XT   = (size_t)B * C * L;       // 6,137,856
constexpr size_t SZ_HALF = (size_t)B * C2 * L;      // 3,068,928 = 4 * (B*96*L)
constexpr size_t OFF_XT  = 0;                       // xt fp32, later t1
constexpr size_t OFF_XT2 = SZ_XT;                   // xt2 fp32
constexpr size_t OFF_KV  = 2 * SZ_XT;               // kv bf16, later y3 fp32
constexpr size_t OFF_AX  = 3 * SZ_XT;               // x2bf+kvinbf (bf16) -> attnout fp32 -> c1 partials
constexpr size_t OFF_Q   = 3 * SZ_XT + SZ_HALF;     // q bf16, later h2 fp32
constexpr size_t OFF_SM  = 3 * SZ_XT + SZ_HALF + SZ_HALF / 2;

// small-region offsets (floats, relative to OFF_SM)
constexpr size_t SM_POOLED = 0;       // B*C2*3
constexpr size_t SM_XM     = 9216;    // B*C2
constexpr size_t SM_H1     = 12288;   // B*4*96
constexpr size_t SM_WDYN   = 15360;   // B*C2*3
constexpr size_t SM_BDYN   = 24576;   // B*C2
constexpr size_t SM_SUM1   = 27648;   // 768
constexpr size_t SM_SQ1    = 28416;
constexpr size_t SM_S1     = 29184;   // bn1 scale g/sigma
constexpr size_t SM_M1     = 29952;   // bn1 mean
constexpr size_t SM_CB1    = 30720;   // 96
constexpr size_t SM_SUM2   = 30816;   // 96
constexpr size_t SM_SQ2    = 30912;
constexpr size_t SM_S2     = 31008;
constexpr size_t SM_M2     = 31104;
constexpr size_t SM_CB2    = 31200;   // 768
constexpr size_t SM_SUM3   = 31968;
constexpr size_t SM_SQ3    = 32736;
constexpr size_t SM_S3     = 33504;
constexpr size_t SM_D3     = 34272;
constexpr size_t SM_END    = 35040;
// bf16 weight copies (float-slot offsets relative to OFF_SM)
constexpr size_t SM_WQ  = SM_END;                 // 147456 sh = 73728 fl
constexpr size_t SM_WKV = SM_WQ + 73728;          // 294912 sh = 147456 fl
constexpr size_t SM_WC1 = SM_WKV + 147456;        // 73728 sh = 36864 fl
constexpr size_t SM_WC2 = SM_WC1 + 36864;         // 73728 sh = 36864 fl

typedef __attribute__((ext_vector_type(8))) short bf16x8;
typedef __attribute__((ext_vector_type(4))) float floatx4;

__device__ __forceinline__ float gelu_f(float x) {
  return 0.5f * x * (1.0f + erff(x * 0.70710678118654752f));
}

__device__ __forceinline__ float wave_sum(float v) {
  #pragma unroll
  for (int off = 32; off > 0; off >>= 1) v += __shfl_down(v, off, 64);
  return v;
}

__device__ __forceinline__ short f2bf(float f) {
  union { float f; unsigned u; } x; x.f = f;
  unsigned r = x.u + 0x7FFFu + ((x.u >> 16) & 1u);
  return (short)(r >> 16);
}

// ---------------- prep: all weight bf16 conversions + cb1/cb2 matvecs ----------------
// blocks 0..71 qw, 72..215 kvw, 216..251 c1w, 252..287 c2w, 288 cb1, 289 cb2
__global__ void k_prep(const float* __restrict__ qw, short* __restrict__ wq,
                       const float* __restrict__ kvw, short* __restrict__ wkv,
                       const float* __restrict__ c1w, short* __restrict__ wc1,
                       const float* __restrict__ c2w, short* __restrict__ wc2,
                       const float* __restrict__ c1b, const float* __restrict__ bn1b,
                       const float* __restrict__ c2b, const float* __restrict__ bn2b,
                       float* __restrict__ cb1, float* __restrict__ cb2) {
  int bid = blockIdx.x;
  if (bid < 288) {
    const float* src; short* dst; int base;
    if (bid < 72)       { src = qw;  dst = wq;  base = bid; }
    else if (bid < 216) { src = kvw; dst = wkv; base = bid - 72; }
    else if (bid < 252) { src = c1w; dst = wc1; base = bid - 216; }
    else                { src = c2w; dst = wc2; base = bid - 252; }
    int i = (base * 256 + threadIdx.x) * 8;
    float4 a = *reinterpret_cast<const float4*>(&src[i]);
    float4 b = *reinterpret_cast<const float4*>(&src[i + 4]);
    short tmp[8] = {f2bf(a.x), f2bf(a.y), f2bf(a.z), f2bf(a.w),
                    f2bf(b.x), f2bf(b.y), f2bf(b.z), f2bf(b.w)};
    *(bf16x8*)&dst[i] = *(bf16x8*)tmp;
  } else if (bid == 288) {
    int o = threadIdx.x;
    if (o < 96) {
      float a = c1b[o];
      const float* wr = c1w + (size_t)o * C;
      for (int c = 0; c < C; c++) a += bn1b[c] * wr[c];
      cb1[o] = a;
    }
  } else {
    for (int o = threadIdx.x; o < C; o += 256) {
      float a = c2b[o];
      const float* wr = c2w + (size_t)o * 96;
      for (int i = 0; i < 96; i++) a += bn2b[i] * wr[i];
      cb2[o] = a;
    }
  }
}

// ---------------- transpose x (B,L,C) -> xt fp32 (B,C,L) + x2bf bf16 upper ----------------
__global__ void k_transpose_in(const float* __restrict__ x, float* __restrict__ xt,
                               short* __restrict__ x2bf) {
  __shared__ float tile[32][33];
  int b = blockIdx.z;
  int l0 = blockIdx.x * 32, c0 = blockIdx.y * 32;
  int tx = threadIdx.x, ty = threadIdx.y;
  #pragma unroll
  for (int i = 0; i < 4; i++) {
    int l = l0 + ty + i * 8, c = c0 + tx;
    if (l < L) tile[ty + i * 8][tx] = x[((size_t)b * L + l) * C + c];
  }
  __syncthreads();
  #pragma unroll
  for (int i = 0; i < 4; i++) {
    int c = c0 + ty + i * 8, l = l0 + tx;
    if (l < L) {
      float v = tile[tx][ty + i * 8];
      xt[((size_t)b * C + c) * L + l] = v;
      if (c >= C2) x2bf[((size_t)b * C2 + (c - C2)) * L + l] = f2bf(v);
    }
  }
}

// ---------------- pooled chunk means + row mean ----------------
__global__ __launch_bounds__(256) void k_pool(const float* __restrict__ xt,
                                              float* __restrict__ pooled,
                                              float* __restrict__ xm) {
  int c = blockIdx.x, b = blockIdx.y;
  const float* row = xt + ((size_t)b * C + c) * L;
  float s0 = 0.f, s1 = 0.f, s2 = 0.f;
  for (int l = threadIdx.x; l < L; l += 256) {
    float v = row[l];
    int ch = l / 333;
    if (ch == 0) s0 += v; else if (ch == 1) s1 += v; else s2 += v;
  }
  s0 = wave_sum(s0); s1 = wave_sum(s1); s2 = wave_sum(s2);
  __shared__ float r[3][4];
  int lane = threadIdx.x & 63, wid = threadIdx.x >> 6;
  if (lane == 0) { r[0][wid] = s0; r[1][wid] = s1; r[2][wid] = s2; }
  __syncthreads();
  if (threadIdx.x == 0) {
    float t0 = r[0][0] + r[0][1] + r[0][2] + r[0][3];
    float t1 = r[1][0] + r[1][1] + r[1][2] + r[1][3];
    float t2 = r[2][0] + r[2][1] + r[2][2] + r[2][3];
    size_t pb = (size_t)(b * C2 + c) * 3;
    pooled[pb + 0] = t0 / 333.f;
    pooled[pb + 1] = t1 / 333.f;
    pooled[pb + 2] = t2 / 333.f;
    xm[b * C2 + c] = (t0 + t1 + t2) / 999.f;
  }
}

// ---------------- tiny MLP layer 1 ----------------
__global__ void k_mlp1(const float* __restrict__ pooled, const float* __restrict__ xm,
                       const float* __restrict__ p1w, const float* __restrict__ p1b,
                       float* __restrict__ h1) {
  int j = blockIdx.x, b = blockIdx.y;
  __shared__ float vin[C2];
  for (int c = threadIdx.x; c < C2; c += 128)
    vin[c] = (j < 3) ? pooled[(size_t)(b * C2 + c) * 3 + j] : xm[b * C2 + c];
  __syncthreads();
  int o = threadIdx.x;
  if (o < 96) {
    float acc = p1b[o];
    const float* wr = p1w + (size_t)o * C2;
    for (int c = 0; c < C2; c++) acc += vin[c] * wr[c];
    h1[(b * 4 + j) * 96 + o] = gelu_f(acc);
  }
}

// ---------------- MLP layer 2 + softmax + mix ----------------
__global__ void k_mix2(const float* __restrict__ h1,
                       const float* __restrict__ p2w, const float* __restrict__ p2b,
                       const float* __restrict__ dcw, const float* __restrict__ dcb,
                       float* __restrict__ wdyn, float* __restrict__ bdyn) {
  int j = blockIdx.x, b = blockIdx.y;
  __shared__ float hv[96];
  for (int i = threadIdx.x; i < 96; i += 384) hv[i] = h1[(b * 4 + j) * 96 + i];
  __syncthreads();
  int c = threadIdx.x;
  float a0 = p2b[c], a1 = p2b[C2 + c];
  const float* w0r = p2w + (size_t)c * 96;
  const float* w1r = p2w + (size_t)(C2 + c) * 96;
  for (int i = 0; i < 96; i++) { float h = hv[i]; a0 += h * w0r[i]; a1 += h * w1r[i]; }
  float m = fmaxf(a0, a1);
  float e0 = __expf(a0 - m), e1 = __expf(a1 - m);
  float inv = 1.f / (e0 + e1);
  float p0 = e0 * inv, p1 = e1 * inv;
  if (j < 3)
    wdyn[(size_t)(b * C2 + c) * 3 + j] = p0 * dcw[(size_t)c * 3 + j] + p1 * dcw[(size_t)(C2 + c) * 3 + j];
  else
    bdyn[b * C2 + c] = p0 * dcb[c] + p1 * dcb[C2 + c];
}

// ---------------- fused dyn-conv (xt2 lower, fp32) + kv_in (bf16) ----------------
__global__ __launch_bounds__(256) void k_dwpair(const float* __restrict__ xt,
                                                const float* __restrict__ wdyn,
                                                const float* __restrict__ bdyn,
                                                const float* __restrict__ lcw,
                                                const float* __restrict__ lcb,
                                                float* __restrict__ xt2,
                                                short* __restrict__ kvbf) {
  int c = blockIdx.x, b = blockIdx.y;
  const float* rowA = xt + ((size_t)b * C + c) * L;
  size_t wb = (size_t)(b * C2 + c) * 3;
  float a0 = wdyn[wb], a1 = wdyn[wb + 1], a2 = wdyn[wb + 2], ab = bdyn[b * C2 + c];
  float* oA = xt2 + ((size_t)b * C + c) * L;
  const float* rowB = xt + ((size_t)b * C + C2 + c) * L;
  float w0 = lcw[c * 3], w1 = lcw[c * 3 + 1] + 1.0f, w2 = lcw[c * 3 + 2], bb = lcb[c];
  short* oB = kvbf + ((size_t)b * C2 + c) * L;
  for (int l = threadIdx.x; l < L; l += 256) {
    {
      float xm1 = (l > 0) ? rowA[l - 1] : 0.f;
      float x0 = rowA[l];
      float xp1 = (l < L - 1) ? rowA[l + 1] : 0.f;
      oA[l] = xm1 * a0 + x0 * a1 + xp1 * a2 + ab;
    }
    {
      float xm1 = (l > 0) ? rowB[l - 1] : 0.f;
      float x0 = rowB[l];
      float xp1 = (l < L - 1) ? rowB[l + 1] : 0.f;
      oB[l] = f2bf(xm1 * w0 + x0 * w1 + xp1 * w2 + bb);
    }
  }
}

// ---------------- MFMA GEMM: 64o x LT-l tiles, BK=64, bf16 W, optional K-split ----------------
// flags: 1 gelu, 2 bf16 out, 4 X is bf16, 8 BN stats.
// ksplit>1: blockIdx.y = (o-tile)*ksplit + kc; chunk kc covers K range [kc*Kd, (kc+1)*Kd)
// of a matrix with row stride Kstride; output goes to slice kc (slice elems apart, fp32).
__global__ __launch_bounds__(256) void k_gemm2_t64(const short*, const void*, void*,
                                                   const float*, const float*, const float*,
                                                   float*, float*, int, int, int,
                                                   size_t, size_t, int, float, int, size_t);

template<int LT>
__global__ __launch_bounds__(256) void k_gemm2(const short* __restrict__ Wbf,
                                               const void* __restrict__ Xv,
                                               void* __restrict__ Yv,
                                               const float* __restrict__ shift,
                                               const float* __restrict__ scale,
                                               const float* __restrict__ bias,
                                               float* __restrict__ sum, float* __restrict__ sq,
                                               int O, int Kd, int Kstride,
                                               size_t xbs, size_t ybs,
                                               int flags, float outmul,
                                               int ksplit, size_t slice) {
  __shared__ __align__(16) short Wt[64 * 72];
  __shared__ __align__(16) short Xt[LT * 72];
  int b = blockIdx.z;
  int kc = (int)blockIdx.y % ksplit;
  int o0 = ((int)blockIdx.y / ksplit) * 64;
  int l0 = blockIdx.x * LT;
  int kbeg = kc * Kd;
  int t = threadIdx.x, w = t >> 6, lane = t & 63;
  int col = lane & 15, quad = lane >> 4;
  const short* Wp = Wbf + kbeg;
  floatx4 acc[LT / 16];
  #pragma unroll
  for (int i = 0; i < LT / 16; i++) acc[i] = floatx4{0.f, 0.f, 0.f, 0.f};

  for (int k0 = 0; k0 < Kd; k0 += 64) {
    // ---- W tile (bf16, vector loads) ----
    #pragma unroll
    for (int u = 0; u < 2; u++) {
      int uu = t + u * 256;
      int o = uu >> 3, ks = (uu & 7) * 8;
      int oo = o0 + o, k = k0 + ks;
      bf16x8 w8 = {0, 0, 0, 0, 0, 0, 0, 0};
      if (oo < O && k < Kd) w8 = *(const bf16x8*)&Wp[(size_t)oo * Kstride + k];
      *(bf16x8*)&Wt[o * 72 + ks] = w8;
    }
    // ---- X tile -> Xt[l][k], scalar loads, k-pairs packed ----
    if (flags & 4) {
      const short* Xb = (const short*)Xv + (size_t)b * xbs + (size_t)kbeg * L;
      #pragma unroll
      for (int rep = 0; rep < LT / 8; rep++) {
        int u = t + rep * 256;
        int kk2 = u / LT, ll = u % LT;
        int k = k0 + 2 * kk2, l = l0 + ll;
        unsigned s0_ = 0, s1_ = 0;
        if (l < L && k < Kd) {
          s0_ = (unsigned short)Xb[(size_t)k * L + l];
          s1_ = (unsigned short)Xb[(size_t)(k + 1) * L + l];
        }
        *(unsigned*)&Xt[ll * 72 + 2 * kk2] = s0_ | (s1_ << 16);
      }
    } else {
      const float* Xb = (const float*)Xv + (size_t)b * xbs + (size_t)kbeg * L;
      #pragma unroll
      for (int rep = 0; rep < LT / 8; rep++) {
        int u = t + rep * 256;
        int kk2 = u / LT, ll = u % LT;
        int k = k0 + 2 * kk2, l = l0 + ll;
        float x0 = 0.f, x1 = 0.f;
        if (l < L && k < Kd) {
          x0 = Xb[(size_t)k * L + l];
          x1 = Xb[(size_t)(k + 1) * L + l];
          if (shift) { x0 -= shift[kbeg + k]; x1 -= shift[kbeg + k + 1]; }
          if (scale) { x0 *= scale[kbeg + k]; x1 *= scale[kbeg + k + 1]; }
        }
        unsigned pk = (unsigned)(unsigned short)f2bf(x0) | ((unsigned)(unsigned short)f2bf(x1) << 16);
        *(unsigned*)&Xt[ll * 72 + 2 * kk2] = pk;
      }
    }
    __syncthreads();
    // ---- MFMA: wave w owns o-strip [w*16, w*16+16) ----
    #pragma unroll
    for (int half = 0; half < 2; half++) {
      bf16x8 aw = *(bf16x8*)&Wt[(w * 16 + col) * 72 + half * 32 + quad * 8];
      #pragma unroll
      for (int nt = 0; nt < LT / 16; nt++) {
        bf16x8 bx = *(bf16x8*)&Xt[(nt * 16 + col) * 72 + half * 32 + quad * 8];
        acc[nt] = __builtin_amdgcn_mfma_f32_16x16x32_bf16(aw, bx, acc[nt], 0, 0, 0);
      }
    }
    __syncthreads();
  }
  // ---- epilogue ----
  int o_base = o0 + w * 16 + quad * 4;
  #pragma unroll
  for (int r = 0; r < 4; r++) {
    int o = o_base + r;
    bool ov = o < O;
    float bo = (bias && ov) ? bias[o] : 0.f;
    float ps = 0.f, pq = 0.f;
    #pragma unroll
    for (int nt = 0; nt < LT / 16; nt++) {
      int l = l0 + nt * 16 + col;
      float v = acc[nt][r] + bo;
      if (flags & 1) v = gelu_f(v);
      v *= outmul;
      if (l >= L) v = 0.f;
      if (ov && l < L) {
        if (flags & 2) ((short*)Yv)[(size_t)b * ybs + (size_t)o * L + l] = f2bf(v);
        else           ((float*)Yv)[kc * slice + (size_t)b * ybs + (size_t)o * L + l] = v;
      }
      ps += v; pq += v * v;
    }
    if ((flags & 8) && ov) {
      ps += __shfl_xor(ps, 1); ps += __shfl_xor(ps, 2);
      ps += __shfl_xor(ps, 4); ps += __shfl_xor(ps, 8);
      pq += __shfl_xor(pq, 1); pq += __shfl_xor(pq, 2);
      pq += __shfl_xor(pq, 4); pq += __shfl_xor(pq, 8);
      if (col == 0) { atomicAdd(&sum[o], ps); atomicAdd(&sq[o], pq); }
    }
  }
}

// ---------------- h2 finalize: sum 4 c1 partials + cb1, gelu, bn2 stats ----------------
__global__ __launch_bounds__(256) void k_h2fin(const float* __restrict__ part,
                                               const float* __restrict__ cb1,
                                               float* __restrict__ h2,
                                               float* __restrict__ sum, float* __restrict__ sq) {
  int o = blockIdx.x, b = blockIdx.y;
  constexpr size_t SL = (size_t)B * 96 * L;
  const float* p0 = part + ((size_t)b * 96 + o) * L;
  float bo = cb1[o];
  float* orow = h2 + ((size_t)b * 96 + o) * L;
  float s = 0.f, s2 = 0.f;
  for (int l = threadIdx.x; l < L; l += 256) {
    float v = p0[l] + p0[SL + l] + p0[2 * SL + l] + p0[3 * SL + l] + bo;
    v = gelu_f(v);
    orow[l] = v;
    s += v; s2 += v * v;
  }
  s = wave_sum(s); s2 = wave_sum(s2);
  __shared__ float r1[4], r2[4];
  int lane = threadIdx.x & 63, wid = threadIdx.x >> 6;
  if (lane == 0) { r1[wid] = s; r2[wid] = s2; }
  __syncthreads();
  if (threadIdx.x == 0) {
    atomicAdd(&sum[o], r1[0] + r1[1] + r1[2] + r1[3]);
    atomicAdd(&sq[o], r2[0] + r2[1] + r2[2] + r2[3]);
  }
}

// ---------------- MFMA flash attention (R6-verbatim) ----------------
__global__ __launch_bounds__(256) void k_attn_mfma(const short* __restrict__ q,
                                                   const short* __restrict__ kv,
                                                   float* __restrict__ out) {
  __shared__ __align__(16) char smem[9216 * 3 + 6144];
  short* Qs = (short*)smem;
  short* Ks = (short*)(smem + 9216);
  short* Ps = (short*)(smem + 18432);
  short* Vf = (short*)(smem + 27648);
  float* Os = (float*)smem;

  int lt0 = blockIdx.x * 64;
  int h = blockIdx.y, b = blockIdx.z;
  int t = threadIdx.x;
  int w = t >> 6, lane = t & 63;
  int col = lane & 15, quad = lane >> 4;
  const short* qb = q  + ((size_t)b * C2 + h * HD) * L;
  const short* kb = kv + ((size_t)b * C  + h * HD) * L;
  const short* vb = kv + ((size_t)b * C + C2 + h * HD) * L;

  for (int i = t; i < 64 * 16; i += 256) {
    int row = i >> 4, d = 48 + (i & 15);
    Qs[row * 72 + d] = 0;
    Ks[row * 72 + d] = 0;
  }
  for (int i = t; i < 64 * 24; i += 256) {
    int d2 = i >> 6, ll = i & 63;
    int l = lt0 + ll;
    unsigned pk = 0;
    if (l < L) {
      unsigned s0_ = (unsigned short)qb[(size_t)(2 * d2) * L + l];
      unsigned s1_ = (unsigned short)qb[(size_t)(2 * d2 + 1) * L + l];
      pk = s0_ | (s1_ << 16);
    }
    *(unsigned*)&Qs[ll * 72 + 2 * d2] = pk;
  }

  floatx4 of[3];
  #pragma unroll
  for (int i = 0; i < 3; i++) of[i] = floatx4{0.f, 0.f, 0.f, 0.f};
  float rs[4] = {0.f, 0.f, 0.f, 0.f};
  __syncthreads();

  for (int m0 = 0; m0 < L; m0 += 64) {
    for (int i = t; i < 64 * 24; i += 256) {
      int d2 = i >> 6, mm = i & 63;
      int m = m0 + mm;
      unsigned pk = 0;
      if (m < L) {
        unsigned s0_ = (unsigned short)kb[(size_t)(2 * d2) * L + m];
        unsigned s1_ = (unsigned short)kb[(size_t)(2 * d2 + 1) * L + m];
        pk = s0_ | (s1_ << 16);
      }
      *(unsigned*)&Ks[mm * 72 + 2 * d2] = pk;
    }
    for (int a = t; a < 384; a += 256) {
      int d = (a & 7) | ((a >> 6) << 3);
      int o = (a >> 3) & 7;
      int mb = m0 + o * 8;
      const short* src = vb + (size_t)d * L + mb;
      short v8a[8];
      #pragma unroll
      for (int j = 0; j < 8; j++) v8a[j] = (mb + j < L) ? src[j] : (short)0;
      int chunk = o >> 2, dsub = d >> 4;
      int lanep = ((o & 3) << 4) | (d & 15);
      *(bf16x8*)&Vf[((chunk * 3 + dsub) * 64 + lanep) * 8] = *(bf16x8*)&v8a[0];
    }
    __syncthreads();

    bf16x8 aq0 = *(bf16x8*)&Qs[(w * 16 + col) * 72 + quad * 8];
    bf16x8 aq1 = *(bf16x8*)&Qs[(w * 16 + col) * 72 + 32 + quad * 8];
    floatx4 sf[4];
    #pragma unroll
    for (int ms = 0; ms < 4; ms++) {
      bf16x8 bk0 = *(bf16x8*)&Ks[(ms * 16 + col) * 72 + quad * 8];
      bf16x8 bk1 = *(bf16x8*)&Ks[(ms * 16 + col) * 72 + 32 + quad * 8];
      floatx4 a4 = floatx4{0.f, 0.f, 0.f, 0.f};
      a4 = __builtin_amdgcn_mfma_f32_16x16x32_bf16(aq0, bk0, a4, 0, 0, 0);
      a4 = __builtin_amdgcn_mfma_f32_16x16x32_bf16(aq1, bk1, a4, 0, 0, 0);
      sf[ms] = a4;
    }
    float rloc[4] = {0.f, 0.f, 0.f, 0.f};
    #pragma unroll
    for (int ms = 0; ms < 4; ms++) {
      int m = m0 + ms * 16 + col;
      bool ok = m < L;
      #pragma unroll
      for (int r = 0; r < 4; r++) {
        float e = ok ? __expf(sf[ms][r]) : 0.f;
        rloc[r] += e;
        Ps[(w * 16 + quad * 4 + r) * 72 + ms * 16 + col] = f2bf(e);
      }
    }
    #pragma unroll
    for (int r = 0; r < 4; r++) {
      float v = rloc[r];
      v += __shfl_xor(v, 1); v += __shfl_xor(v, 2);
      v += __shfl_xor(v, 4); v += __shfl_xor(v, 8);
      rs[r] += v;
    }
    __syncthreads();

    bf16x8 ap0 = *(bf16x8*)&Ps[(w * 16 + col) * 72 + quad * 8];
    bf16x8 ap1 = *(bf16x8*)&Ps[(w * 16 + col) * 72 + 32 + quad * 8];
    #pragma unroll
    for (int ds = 0; ds < 3; ds++) {
      bf16x8 bv0 = *(bf16x8*)&Vf[((0 * 3 + ds) * 64 + lane) * 8];
      bf16x8 bv1 = *(bf16x8*)&Vf[((1 * 3 + ds) * 64 + lane) * 8];
      of[ds] = __builtin_amdgcn_mfma_f32_16x16x32_bf16(ap0, bv0, of[ds], 0, 0, 0);
      of[ds] = __builtin_amdgcn_mfma_f32_16x16x32_bf16(ap1, bv1, of[ds], 0, 0, 0);
    }
    __syncthreads();
  }

  #pragma unroll
  for (int r = 0; r < 4; r++) {
    float inv = 1.f / rs[r];
    #pragma unroll
    for (int ds = 0; ds < 3; ds++)
      Os[(ds * 16 + col) * 66 + w * 16 + quad * 4 + r] = of[ds][r] * inv;
  }
  __syncthreads();
  for (int i = t; i < 48 * 64; i += 256) {
    int d = i >> 6, ll = i & 63;
    int l = lt0 + ll;
    if (l < L) out[((size_t)b * C2 + h * HD + d) * L + l] = Os[d * 66 + ll];
  }
}

// ---------------- scatter attention out (bug-compatible reshape) -> xt2 upper ----------------
__global__ void k_fill_xt2(const float* __restrict__ ao, float* __restrict__ xt2) {
  __shared__ float tile[32][33];
  int b = blockIdx.z;
  int l0 = blockIdx.x * 32, c0 = blockIdx.y * 32;
  int tx = threadIdx.x, ty = threadIdx.y;
  #pragma unroll
  for (int i = 0; i < 4; i++) {
    int l = l0 + ty + i * 8, c = c0 + tx;
    if (l < L) tile[ty + i * 8][tx] = ao[(size_t)b * ((size_t)L * C2) + (size_t)l * C2 + c];
  }
  __syncthreads();
  #pragma unroll
  for (int i = 0; i < 4; i++) {
    int c = c0 + ty + i * 8, l = l0 + tx;
    if (l < L) xt2[((size_t)b * C + C2 + c) * L + l] = tile[tx][ty + i * 8];
  }
}

// ---------------- projection dw3 + gelu -> t1, bn1 stats ----------------
__global__ __launch_bounds__(256) void k_dwproj(const float* __restrict__ xt2,
                                                const float* __restrict__ dww,
                                                const float* __restrict__ dwb,
                                                float* __restrict__ t1,
                                                float* __restrict__ sum, float* __restrict__ sq) {
  int c = blockIdx.x, b = blockIdx.y;
  const float* row = xt2 + ((size_t)b * C + c) * L;
  float w0 = dww[c * 3], w1 = dww[c * 3 + 1], w2 = dww[c * 3 + 2], bb = dwb[c];
  float* orow = t1 + ((size_t)b * C + c) * L;
  float s = 0.f, s2 = 0.f;
  for (int l = threadIdx.x; l < L; l += 256) {
    float xm1 = (l > 0) ? row[l - 1] : 0.f;
    float x0 = row[l];
    float xp1 = (l < L - 1) ? row[l + 1] : 0.f;
    float v = gelu_f(xm1 * w0 + x0 * w1 + xp1 * w2 + bb);
    orow[l] = v;
    s += v; s2 += v * v;
  }
  s = wave_sum(s); s2 = wave_sum(s2);
  __shared__ float r1[4], r2[4];
  int lane = threadIdx.x & 63, wid = threadIdx.x >> 6;
  if (lane == 0) { r1[wid] = s; r2[wid] = s2; }
  __syncthreads();
  if (threadIdx.x == 0) {
    atomicAdd(&sum[c], r1[0] + r1[1] + r1[2] + r1[3]);
    atomicAdd(&sq[c], r2[0] + r2[1] + r2[2] + r2[3]);
  }
}

// ---------------- bn finalize (s = g*rsqrt(var), m = mean), for n channels ----------------
__global__ void k_bnfin(const float* __restrict__ sum, const float* __restrict__ sq,
                        const float* __restrict__ g, int n,
                        float* __restrict__ s_, float* __restrict__ m_) {
  int t = threadIdx.x;
  if (t < n) {
    float m = sum[t] * INV_N;
    float v = sq[t] * INV_N - m * m;
    float r = rsqrtf(v + BN_EPS);
    s_[t] = g[t] * r;
    m_[t] = m;
  }
}

// ---------------- finalize bn3 (scale + delta form) ----------------
__global__ void k_fin3(const float* __restrict__ sum, const float* __restrict__ sq,
                       const float* __restrict__ g, const float* __restrict__ be,
                       float* __restrict__ s3, float* __restrict__ d3) {
  int t = threadIdx.x;
  if (t < C) {
    float m = sum[t] * INV_N;
    float v = sq[t] * INV_N - m * m;
    float r = rsqrtf(v + BN_EPS);
    float sc = g[t] * r;
    s3[t] = sc;
    d3[t] = be[t] - m * sc;
  }
}

// ---------------- final: out[b,l,c] = bn3(y3) + xt2 (transpose back) ----------------
__global__ void k_final(const float* __restrict__ y3, const float* __restrict__ xt2,
                        const float* __restrict__ s3, const float* __restrict__ d3,
                        float* __restrict__ out) {
  __shared__ float tile[32][33];
  int b = blockIdx.z;
  int l0 = blockIdx.x * 32, c0 = blockIdx.y * 32;
  int tx = threadIdx.x, ty = threadIdx.y;
  #pragma unroll
  for (int i = 0; i < 4; i++) {
    int c = c0 + ty + i * 8, l = l0 + tx;
    if (l < L) {
      size_t idx = ((size_t)b * C + c) * L + l;
      tile[ty + i * 8][tx] = y3[idx] * s3[c] + d3[c] + xt2[idx];
    }
  }
  __syncthreads();
  #pragma unroll
  for (int i = 0; i < 4; i++) {
    int l = l0 + ty + i * 8, c = c0 + tx;
    if (l < L) out[((size_t)b * L + l) * C + c] = tile[tx][ty + i * 8];
  }
}

extern "C" void kernel_launch(void* const* d_in, const int* in_sizes, int n_in,
                              void* d_out, int out_size, void* d_ws, size_t ws_size,
                              hipStream_t stream) {
  const float* x    = (const float*)d_in[0];
  const float* dcw  = (const float*)d_in[1];
  const float* dcb  = (const float*)d_in[2];
  const float* p1w  = (const float*)d_in[3];
  const float* p1b  = (const float*)d_in[4];
  const float* p2w  = (const float*)d_in[5];
  const float* p2b  = (const float*)d_in[6];
  const float* qw   = (const float*)d_in[7];
  const float* qb   = (const float*)d_in[8];
  const float* kvw  = (const float*)d_in[9];
  const float* kvb  = (const float*)d_in[10];
  const float* lcw  = (const float*)d_in[11];
  const float* lcb  = (const float*)d_in[12];
  const float* dww  = (const float*)d_in[13];
  const float* dwb  = (const float*)d_in[14];
  const float* bn1g = (const float*)d_in[15];
  const float* bn1b = (const float*)d_in[16];
  const float* c1w  = (const float*)d_in[17];
  const float* c1b  = (const float*)d_in[18];
  const float* bn2g = (const float*)d_in[19];
  const float* bn2b = (const float*)d_in[20];
  const float* c2w  = (const float*)d_in[21];
  const float* c2b  = (const float*)d_in[22];
  const float* bn3g = (const float*)d_in[23];
  const float* bn3b = (const float*)d_in[24];
  float* out = (float*)d_out;
  float* ws  = (float*)d_ws;

  float* xt      = ws + OFF_XT;                      // fp32, later t1
  float* xt2     = ws + OFF_XT2;                     // fp32
  short* kvbuf   = (short*)(ws + OFF_KV);            // bf16 kv
  float* y3      = ws + OFF_KV;                      // fp32 (reuse)
  short* x2bf    = (short*)(ws + OFF_AX);            // bf16 x2t
  short* kvinbf  = (short*)(ws + OFF_AX + SZ_HALF / 2);  // bf16 kv_in
  float* attnout = ws + OFF_AX;                      // fp32 (reuse)
  float* c1part  = ws + OFF_AX;                      // fp32, 4 slices of B*96*L (reuse)
  short* qbuf    = (short*)(ws + OFF_Q);             // bf16 q
  float* h2      = ws + OFF_Q;                       // fp32 (reuse)
  float* sm      = ws + OFF_SM;

  float* pooled = sm + SM_POOLED;
  float* xm     = sm + SM_XM;
  float* h1     = sm + SM_H1;
  float* wdyn   = sm + SM_WDYN;
  float* bdyn   = sm + SM_BDYN;
  float* sum1 = sm + SM_SUM1; float* sq1 = sm + SM_SQ1;
  float* s1 = sm + SM_S1; float* m1 = sm + SM_M1; float* cb1 = sm + SM_CB1;
  float* sum2 = sm + SM_SUM2; float* sq2 = sm + SM_SQ2;
  float* s2 = sm + SM_S2; float* m2 = sm + SM_M2; float* cb2 = sm + SM_CB2;
  float* sum3 = sm + SM_SUM3; float* sq3 = sm + SM_SQ3;
  float* s3 = sm + SM_S3; float* d3 = sm + SM_D3;
  short* wqbf  = (short*)(sm + SM_WQ);
  short* wkvbf = (short*)(sm + SM_WKV);
  short* wc1bf = (short*)(sm + SM_WC1);
  short* wc2bf = (short*)(sm + SM_WC2);

  hipMemsetAsync((void*)(sm + SM_SUM1), 0, (SM_S3 - SM_SUM1) * sizeof(float), stream);

  // 0. weight bf16 conversions + cb1/cb2 matvecs (one launch)
  k_prep<<<290, 256, 0, stream>>>(qw, wqbf, kvw, wkvbf, c1w, wc1bf, c2w, wc2bf,
                                  c1b, bn1b, c2b, bn2b, cb1, cb2);

  dim3 tb32(32, 8);
  // 1. transpose input (+ bf16 upper half)
  k_transpose_in<<<dim3(32, 24, B), tb32, 0, stream>>>(x, xt, x2bf);
  // 2. pooled / mean
  k_pool<<<dim3(C2, B), 256, 0, stream>>>(xt, pooled, xm);
  // 3. tiny MLP
  k_mlp1<<<dim3(4, B), 128, 0, stream>>>(pooled, xm, p1w, p1b, h1);
  k_mix2<<<dim3(4, B), 384, 0, stream>>>(h1, p2w, p2b, dcw, dcb, wdyn, bdyn);
  // 4. fused dyn-conv + kv_in (bf16)
  k_dwpair<<<dim3(C2, B), 256, 0, stream>>>(xt, wdyn, bdyn, lcw, lcb, xt2, kvinbf);
  // 5. q GEMM: 64-l tiles (768 blocks), bf16 X/out, *ATT_SCALE
  k_gemm2<64><<<dim3(16, 6, B), 256, 0, stream>>>(wqbf, (const void*)x2bf, (void*)qbuf,
                                                  nullptr, nullptr, qb, nullptr, nullptr,
                                                  C2, C2, C2, (size_t)C2 * L, (size_t)C2 * L,
                                                  6, ATT_SCALE, 1, 0);
  // 6. kv GEMM: 128-l tiles (768 blocks), bf16 X/out
  k_gemm2<128><<<dim3(8, 12, B), 256, 0, stream>>>(wkvbf, (const void*)kvinbf, (void*)kvbuf,
                                                   nullptr, nullptr, kvb, nullptr, nullptr,
                                                   C, C2, C2, (size_t)C2 * L, (size_t)C * L,
                                                   6, 1.0f, 1, 0);
  // 7. MFMA flash attention -> attnout
  k_attn_mfma<<<dim3(16, H, B), 256, 0, stream>>>(qbuf, kvbuf, attnout);
  // 8. scatter reshape -> xt2 upper
  k_fill_xt2<<<dim3(32, 12, B), tb32, 0, stream>>>(attnout, xt2);
  // 9. projection dw3+gelu -> t1 (reuses xt), bn1 stats
  k_dwproj<<<dim3(C, B), 256, 0, stream>>>(xt2, dww, dwb, xt, sum1, sq1);
  k_bnfin<<<1, 768, 0, stream>>>(sum1, sq1, bn1g, C, s1, m1);
  // 10. c1 GEMM, K-split x4 (512 blocks): partials, no bias/act
  k_gemm2<128><<<dim3(8, 8, B), 256, 0, stream>>>(wc1bf, (const void*)xt, (void*)c1part,
                                                  m1, s1, nullptr, nullptr, nullptr,
                                                  96, 192, C, (size_t)C * L, (size_t)96 * L,
                                                  0, 1.0f, 4, (size_t)B * 96 * L);
  // 10b. h2 = gelu(sum partials + cb1), bn2 stats
  k_h2fin<<<dim3(96, B), 256, 0, stream>>>(c1part, cb1, h2, sum2, sq2);
  k_bnfin<<<1, 768, 0, stream>>>(sum2, sq2, bn2g, 96, s2, m2);
  // 11. c2 GEMM: fp32 X centered (m2,s2), fp32 out, bn3 stats
  k_gemm2<128><<<dim3(8, 12, B), 256, 0, stream>>>(wc2bf, (const void*)h2, (void*)y3,
                                                   m2, s2, cb2, sum3, sq3,
                                                   C, 96, 96, (size_t)96 * L, (size_t)C * L,
                                                   8, 1.0f, 1, 0);
  k_fin3<<<1, 768, 0, stream>>>(sum3, sq3, bn3g, bn3b, s3, d3);
  // 12. final bn3 + residual + transpose back
  k_final<<<dim3(32, 24, B), tb32, 0, stream>>>(y3, xt2, s3, d3, out);
}